// Round 6
// baseline (2227.521 us; speedup 1.0000x reference)
//
#include <hip/hip_runtime.h>
#include <math.h>

// ---------------- problem constants ----------------
#define NB   128
#define DC   256
#define SP   256
#define NROW 32768
#define KCB  1024
#define BETA_F 0.1f
#define EPSQ 1e-10f

typedef __attribute__((ext_vector_type(8))) short s16x8;
typedef __attribute__((ext_vector_type(4))) short s16x4;
typedef __attribute__((ext_vector_type(4))) float f32x4;

__device__ __forceinline__ short f2bf(float f) {
  unsigned u = __builtin_bit_cast(unsigned, f);
  unsigned r = (u + 0x7FFFu + ((u >> 16) & 1u)) >> 16;
  return (short)r;
}
__device__ __forceinline__ float bf2f(short s) {
  unsigned u = ((unsigned)(unsigned short)s) << 16;
  return __builtin_bit_cast(float, u);
}
__device__ __forceinline__ unsigned pack2(float a, float b) {
  return (unsigned)(unsigned short)f2bf(a) | ((unsigned)(unsigned short)f2bf(b) << 16);
}

// ========================= init: zero the zero-source buffer ===============
__global__ void init0_kernel(short* __restrict__ zerob)
{
  if (threadIdx.x < 8) zerob[threadIdx.x] = 0;
}

// ========================= weight transposes (fp32 -> bf16) =================
__global__ void w3t_kernel(const float* __restrict__ w, short* __restrict__ o)
{
  const int i = blockIdx.x * 256 + threadIdx.x;  // 589824
  const int ci = i & 255, co = (i >> 8) & 255, j = i >> 16;
  o[i] = f2bf(w[((size_t)(co * 256 + ci)) * 9 + j]);
}
__global__ void w2t_kernel(const float* __restrict__ w, short* __restrict__ o)
{
  const int i = blockIdx.x * 256 + threadIdx.x;  // 524288
  const int ci = i & 127, co = (i >> 7) & 255, j = i >> 15;
  o[i] = f2bf(w[((size_t)(co * 128 + ci)) * 16 + j]);
}
__global__ void wtt2_kernel(const float* __restrict__ w, short* __restrict__ o)
{
  const int i = blockIdx.x * 256 + threadIdx.x;  // 524288
  const int ci = i & 255, co = (i >> 8) & 127, j = (i >> 15) & 3, p = i >> 17;
  const int po = p >> 1, pq = p & 1, a = j >> 1, b2 = j & 1;
  const int kh = (1 - po) + 2 * a, kw = (1 - pq) + 2 * b2;
  o[i] = f2bf(w[((size_t)(ci * 128 + co)) * 16 + kh * 4 + kw]);
}
__global__ void cbbf_kernel(const float* __restrict__ cb, short* __restrict__ o)
{
  const int i = blockIdx.x * 256 + threadIdx.x;  // 262144
  o[i] = f2bf(cb[i]);
}
__global__ void cbt_kernel(const float* __restrict__ cb, short* __restrict__ o)
{
  const int i = blockIdx.x * 256 + threadIdx.x;  // 262144
  const int d = i >> 10, k = i & 1023;
  o[i] = f2bf(cb[(size_t)k * 256 + d]);
}

// ========================= conv1: 3->128, 4x4 s2, 64->32, out NHWC bf16 =====
// wave-per-pixel, lane-per-2-cout. Coalesced 256B/wave output stores.
__global__ __launch_bounds__(256) void conv1_kernel(
    const float* __restrict__ x, const float* __restrict__ w,
    const float* __restrict__ bias, short* __restrict__ out)
{
  __shared__ float li[3][34][34];
  const int tid = threadIdx.x;
  const int tile = blockIdx.x;          // 0..3 quadrant of 32x32 output
  const int b = blockIdx.y;
  const int qy = tile >> 1, qx = tile & 1;
  const int ihlo = qy * 32 - 1, iwlo = qx * 32 - 1;
  for (int ci = 0; ci < 3; ++ci)
    for (int s = tid; s < 1156; s += 256) {
      const int r = s / 34, c = s - r * 34;
      const int ih = ihlo + r, iw = iwlo + c;
      float v = 0.f;
      if ((unsigned)ih < 64u && (unsigned)iw < 64u)
        v = x[((size_t)(b * 3 + ci) * 64 + ih) * 64 + iw];
      li[ci][r][c] = v;
    }
  __syncthreads();

  const int wv = tid >> 6, l = tid & 63;
  const int co0 = 2 * l, co1 = 2 * l + 1;
  float w0[48], w1[48];
#pragma unroll
  for (int j = 0; j < 48; ++j) {
    w0[j] = w[(size_t)co0 * 48 + j];
    w1[j] = w[(size_t)co1 * 48 + j];
  }
  const float b0 = bias[co0], b1 = bias[co1];

  for (int pass = 0; pass < 64; ++pass) {
    const int pix = pass * 4 + wv;            // 0..255
    const int py = pix >> 4, px = pix & 15;
    float s0 = b0, s1 = b1;
#pragma unroll
    for (int ci = 0; ci < 3; ++ci)
#pragma unroll
      for (int kh = 0; kh < 4; ++kh)
#pragma unroll
        for (int kw = 0; kw < 4; ++kw) {
          const int j = ci * 16 + kh * 4 + kw;
          const float v = li[ci][2 * py + kh][2 * px + kw];  // wave-broadcast
          s0 = fmaf(v, w0[j], s0);
          s1 = fmaf(v, w1[j], s1);
        }
    s0 = fmaxf(s0, 0.f);
    s1 = fmaxf(s1, 0.f);
    const int oh = qy * 16 + py, ow = qx * 16 + px;
    ((unsigned*)(out + ((size_t)b * 1024 + oh * 32 + ow) * 128))[l] = pack2(s0, s1);
  }
}

// ========================= MFMA implicit GEMM ===============================
// MODE 0: conv3x3 (A [32768][256], N=256, K=9*256), optional res, optional f32 dup
// MODE 2: conv4x4 s2 (A [131072][128], N=256, K=16*128)
// MODE 3: convT2 per-parity (A [32768][256], N=128, K=4*256), scatter out
// MODE 4: distance variant (out DV bf16 = cn[n] - 2*acc)
template<int MODE, int NSUB, int KIT, int AK, int KPN>
__global__ __launch_bounds__(256) void igemm_kernel(
    const short* __restrict__ Abuf, const short* __restrict__ Bw,
    const float* __restrict__ bias, const short* __restrict__ res,
    short* __restrict__ outb, float* __restrict__ outf32,
    const short* __restrict__ zerob, int po, int pq)
{
  __shared__ __align__(16) short Alds[2][2048];    // 2 x [64 rows][32 ci] bf16
  const int tid = threadIdx.x;
  const int wv = tid >> 6, l = tid & 63;
  const int lcol = l & 15, lk = l >> 4;
  const int m0 = blockIdx.x * 64;

  const int srow = tid >> 2;
  const int sm = m0 + srow;
  const int cchunk = (tid & 3) ^ (srow & 3);
  const int s_img = sm & ~255;
  const int s_h = (sm >> 4) & 15, s_w = sm & 15;
  const int s_b1024 = (sm >> 8) * 1024;
  short* stage_dst = &Alds[0][wv * 512];

  const short* Bp = Bw;
  if constexpr (MODE == 4) Bp += (size_t)blockIdx.y * 65536;

  f32x4 acc[4][NSUB];
#pragma unroll
  for (int i = 0; i < 4; ++i)
#pragma unroll
    for (int j = 0; j < NSUB; ++j) acc[i][j] = (f32x4){0.f, 0.f, 0.f, 0.f};

  int boff[NSUB];
#pragma unroll
  for (int ns = 0; ns < NSUB; ++ns)
    boff[ns] = (wv * (NSUB * 16) + ns * 16 + lcol) * KPN + lk * 8;

  const int aoff_base = lcol * 32 + ((lk ^ (lcol & 3)) * 8);

  auto STAGE = [&](int it, int bufc) {
    int kk, ih, iw, srcrow; bool v;
    if constexpr (MODE == 0) {
      const int jj = it >> 3; kk = it & 7;
      const int q3 = jj / 3;
      ih = s_h + q3 - 1; iw = s_w + (jj - q3 * 3) - 1;
      v = ((unsigned)ih < 16u) & ((unsigned)iw < 16u);
      srcrow = s_img + ih * 16 + iw;
    } else if constexpr (MODE == 2) {
      const int jj = it >> 2; kk = it & 3;
      ih = 2 * s_h + (jj >> 2) - 1; iw = 2 * s_w + (jj & 3) - 1;
      v = ((unsigned)ih < 32u) & ((unsigned)iw < 32u);
      srcrow = s_b1024 + ih * 32 + iw;
    } else if constexpr (MODE == 4) {
      kk = it; v = true; srcrow = sm;
    } else {
      const int jj = it >> 3; kk = it & 7;
      ih = s_h + po - (jj >> 1); iw = s_w + pq - (jj & 1);
      v = ((unsigned)ih < 16u) & ((unsigned)iw < 16u);
      srcrow = s_img + ih * 16 + iw;
    }
    const short* src = v ? (Abuf + (size_t)srcrow * AK + kk * 32 + cchunk * 8) : zerob;
    __builtin_amdgcn_global_load_lds(
        (const __attribute__((address_space(1))) void*)src,
        (__attribute__((address_space(3))) void*)(stage_dst + bufc * 2048),
        16, 0, 0);
  };

  auto COMPUTE = [&](int it, int bufc) {
    int uoff;
    if constexpr (MODE == 0)      uoff = (it >> 3) * 65536 + (it & 7) * 32;
    else if constexpr (MODE == 2) uoff = (it >> 2) * 32768 + (it & 3) * 32;
    else if constexpr (MODE == 4) uoff = it * 32;
    else                          uoff = (it >> 3) * 32768 + (it & 7) * 32;
    s16x8 a[4], b[NSUB];
#pragma unroll
    for (int ms = 0; ms < 4; ++ms)
      a[ms] = *(const s16x8*)&Alds[bufc][aoff_base + ms * 512];
#pragma unroll
    for (int ns = 0; ns < NSUB; ++ns)
      b[ns] = *(const s16x8*)(Bp + uoff + boff[ns]);
#pragma unroll
    for (int ms = 0; ms < 4; ++ms)
#pragma unroll
      for (int ns = 0; ns < NSUB; ++ns)
        acc[ms][ns] = __builtin_amdgcn_mfma_f32_16x16x32_bf16(a[ms], b[ns], acc[ms][ns], 0, 0, 0);
  };

  STAGE(0, 0);
  for (int it = 0; it < KIT; it += 2) {
    __syncthreads();
    if (it + 1 < KIT) STAGE(it + 1, 1);
    COMPUTE(it, 0);
    __syncthreads();
    if (it + 2 < KIT) STAGE(it + 2, 0);
    COMPUTE(it + 1, 1);
  }

  const int r4 = lk * 4;
#pragma unroll
  for (int ms = 0; ms < 4; ++ms) {
#pragma unroll
    for (int ns = 0; ns < NSUB; ++ns) {
      const int n_l = wv * (NSUB * 16) + ns * 16 + lcol;
#pragma unroll
      for (int e = 0; e < 4; ++e) {
        const int m = m0 + ms * 16 + r4 + e;
        if constexpr (MODE == 4) {
          const int n_g = blockIdx.y * 256 + n_l;
          const float val = bias[n_g] - 2.f * acc[ms][ns][e];
          outb[(size_t)m * 1024 + n_g] = f2bf(val);
        } else {
          float val = acc[ms][ns][e] + bias[n_l];
          if constexpr (MODE == 3) {
            val = fmaxf(val, 0.f);
            const int orow = (m & ~255) * 4 + (2 * ((m >> 4) & 15) + po) * 32 + (2 * (m & 15) + pq);
            outb[(size_t)orow * 128 + n_l] = f2bf(val);
          } else {
            if (res) val += bf2f(res[(size_t)m * 256 + n_l]);
            val = fmaxf(val, 0.f);
            outb[(size_t)m * 256 + n_l] = f2bf(val);
            if (outf32) outf32[(size_t)m * 256 + n_l] = val;
          }
        }
      }
    }
  }
}

// ========================= VQ block =========================================
__global__ __launch_bounds__(256) void rownorm_kernel(
    const float* __restrict__ a, float* __restrict__ nrm, int rows)
{
  const int wv = threadIdx.x >> 6, lane = threadIdx.x & 63;
  const int r = blockIdx.x * 4 + wv;
  if (r >= rows) return;
  const float* p = a + (size_t)r * DC;
  float s = 0.f;
#pragma unroll
  for (int i = 0; i < 4; ++i) { float v = p[lane + 64 * i]; s = fmaf(v, v, s); }
#pragma unroll
  for (int o = 32; o > 0; o >>= 1) s += __shfl_xor(s, o);
  if (lane == 0) nrm[r] = s;
}

__global__ void initq_kernel(const float* __restrict__ pi, float* __restrict__ logq,
                             float* __restrict__ Sacc)
{
  const int k = blockIdx.x * 256 + threadIdx.x;
  logq[k] = logf(fmaxf(pi[k], EPSQ));
  if (k == 0) *Sacc = 0.f;
}

// one BA iteration over bf16 DV; per-block Q-partials to PART (no atomics).
__global__ __launch_bounds__(256) void ba2_kernel(
    unsigned* __restrict__ DV, const float* __restrict__ logq,
    float* __restrict__ part, int* __restrict__ idxout, int storeP)
{
  __shared__ float qp[4][1024];
  const int tid = threadIdx.x;
  const int wv = tid >> 6, lane = tid & 63;
  for (int i = tid; i < 4096; i += 256) ((float*)qp)[i] = 0.f;
  __syncthreads();

  float2 lq[8];
#pragma unroll
  for (int it = 0; it < 8; ++it) lq[it] = *(const float2*)&logq[it * 128 + lane * 2];

  const int n0 = blockIdx.x * 16;
  for (int rr = 0; rr < 4; ++rr) {
    const int n = n0 + wv * 4 + rr;
    unsigned* rowp = DV + (size_t)n * 512;
    float l0[8], l1[8];
    float mx = -1e30f;
#pragma unroll
    for (int it = 0; it < 8; ++it) {
      const unsigned w = rowp[it * 64 + lane];
      l0[it] = lq[it].x - BETA_F * bf2f((short)(w & 0xFFFFu));
      l1[it] = lq[it].y - BETA_F * bf2f((short)(w >> 16));
      mx = fmaxf(mx, fmaxf(l0[it], l1[it]));
    }
#pragma unroll
    for (int o = 32; o > 0; o >>= 1) mx = fmaxf(mx, __shfl_xor(mx, o));
    float e0[8], e1[8];
    float s = 0.f;
#pragma unroll
    for (int it = 0; it < 8; ++it) {
      e0[it] = __expf(l0[it] - mx);
      e1[it] = __expf(l1[it] - mx);
      s += e0[it] + e1[it];
    }
#pragma unroll
    for (int o = 32; o > 0; o >>= 1) s += __shfl_xor(s, o);
    const float inv = 1.f / s;
#pragma unroll
    for (int it = 0; it < 8; ++it) {
      qp[wv][it * 128 + lane * 2]     += e0[it] * inv;
      qp[wv][it * 128 + lane * 2 + 1] += e1[it] * inv;
    }

    if (storeP) {
#pragma unroll
      for (int it = 0; it < 8; ++it)
        rowp[it * 64 + lane] = pack2(e0[it] * inv, e1[it] * inv);
      float bv = l0[0]; int bi = lane * 2;
      if (l1[0] > bv) { bv = l1[0]; bi = lane * 2 + 1; }
#pragma unroll
      for (int it = 1; it < 8; ++it) {
        const int k = it * 128 + lane * 2;
        if (l0[it] > bv) { bv = l0[it]; bi = k; }
        if (l1[it] > bv) { bv = l1[it]; bi = k + 1; }
      }
#pragma unroll
      for (int o = 32; o > 0; o >>= 1) {
        const float ov = __shfl_xor(bv, o);
        const int oi = __shfl_xor(bi, o);
        if (ov > bv || (ov == bv && oi < bi)) { bv = ov; bi = oi; }
      }
      if (lane == 0) idxout[n] = bi;
    }
  }
  __syncthreads();
  for (int k = tid; k < 1024; k += 256) {
    part[(size_t)blockIdx.x * 1024 + k] = qp[0][k] + qp[1][k] + qp[2][k] + qp[3][k];
  }
}

// reduce PART[2048][1024] -> qsum, logq.  grid 4 x 256.
__global__ __launch_bounds__(256) void qred_kernel(
    const float* __restrict__ part, float* __restrict__ qsum, float* __restrict__ logq)
{
  const int k = blockIdx.x * 256 + threadIdx.x;
  float s0 = 0.f, s1 = 0.f, s2 = 0.f, s3 = 0.f;
  for (int r = 0; r < 2048; r += 4) {
    s0 += part[(size_t)r * 1024 + k];
    s1 += part[(size_t)(r + 1) * 1024 + k];
    s2 += part[(size_t)(r + 2) * 1024 + k];
    s3 += part[(size_t)(r + 3) * 1024 + k];
  }
  const float s = (s0 + s1) + (s2 + s3);
  qsum[k] = s;
  logq[k] = logf(fmaxf(s * (1.f / 32768.f), EPSQ));
}

__global__ __launch_bounds__(1024) void ent_kernel(
    const float* __restrict__ qsum, float* __restrict__ out_ent)
{
  const int k = threadIdx.x;
  const float q = fmaxf(qsum[k] * (1.f / 32768.f), EPSQ);
  float v = q * logf(q);
#pragma unroll
  for (int o = 32; o > 0; o >>= 1) v += __shfl_xor(v, o);
  __shared__ float red[16];
  const int wv = k >> 6, lane = k & 63;
  if (lane == 0) red[wv] = v;
  __syncthreads();
  if (k == 0) {
    float s = 0.f;
    for (int i = 0; i < 16; ++i) s += red[i];
    *out_ent = 0.01f * s;
  }
}

// zq_soft = P @ cbT via MFMA; fused sum((zq_soft - zf)^2) into Sacc.
__global__ __launch_bounds__(256) void pvq_kernel(
    const short* __restrict__ P, const short* __restrict__ CBT,
    const float* __restrict__ zf32, float* __restrict__ Sacc)
{
  __shared__ __align__(16) short Alds[2][2048];
  __shared__ float red[4];
  const int tid = threadIdx.x;
  const int wv = tid >> 6, l = tid & 63;
  const int lcol = l & 15, lk = l >> 4;
  const int m0 = blockIdx.x * 64;

  const int srow = tid >> 2;
  const int cchunk = (tid & 3) ^ (srow & 3);
  short* stage_dst = &Alds[0][wv * 512];

  f32x4 acc[4][4];
#pragma unroll
  for (int i = 0; i < 4; ++i)
#pragma unroll
    for (int j = 0; j < 4; ++j) acc[i][j] = (f32x4){0.f, 0.f, 0.f, 0.f};

  int boff[4];
#pragma unroll
  for (int ns = 0; ns < 4; ++ns)
    boff[ns] = (wv * 64 + ns * 16 + lcol) * 1024 + lk * 8;

  const int aoff_base = lcol * 32 + ((lk ^ (lcol & 3)) * 8);

  auto STAGE = [&](int it, int bufc) {
    const short* src = P + (size_t)(m0 + srow) * 1024 + it * 32 + cchunk * 8;
    __builtin_amdgcn_global_load_lds(
        (const __attribute__((address_space(1))) void*)src,
        (__attribute__((address_space(3))) void*)(stage_dst + bufc * 2048),
        16, 0, 0);
  };
  auto COMPUTE = [&](int it, int bufc) {
    s16x8 a[4], b[4];
#pragma unroll
    for (int ms = 0; ms < 4; ++ms)
      a[ms] = *(const s16x8*)&Alds[bufc][aoff_base + ms * 512];
#pragma unroll
    for (int ns = 0; ns < 4; ++ns)
      b[ns] = *(const s16x8*)(CBT + it * 32 + boff[ns]);
#pragma unroll
    for (int ms = 0; ms < 4; ++ms)
#pragma unroll
      for (int ns = 0; ns < 4; ++ns)
        acc[ms][ns] = __builtin_amdgcn_mfma_f32_16x16x32_bf16(a[ms], b[ns], acc[ms][ns], 0, 0, 0);
  };

  STAGE(0, 0);
  for (int it = 0; it < 32; it += 2) {
    __syncthreads();
    if (it + 1 < 32) STAGE(it + 1, 1);
    COMPUTE(it, 0);
    __syncthreads();
    if (it + 2 < 32) STAGE(it + 2, 0);
    COMPUTE(it + 1, 1);
  }

  float ls = 0.f;
  const int r4 = lk * 4;
#pragma unroll
  for (int ms = 0; ms < 4; ++ms) {
#pragma unroll
    for (int ns = 0; ns < 4; ++ns) {
      const int n_l = wv * 64 + ns * 16 + lcol;
#pragma unroll
      for (int e = 0; e < 4; ++e) {
        const int m = m0 + ms * 16 + r4 + e;
        const float d = acc[ms][ns][e] - zf32[(size_t)m * 256 + n_l];
        ls = fmaf(d, d, ls);
      }
    }
  }
#pragma unroll
  for (int o = 32; o > 0; o >>= 1) ls += __shfl_xor(ls, o);
  if (l == 0) red[wv] = ls;
  __syncthreads();
  if (tid == 0) atomicAdd(Sacc, red[0] + red[1] + red[2] + red[3]);
}

__global__ void scalars_kernel(const float* __restrict__ S, float* __restrict__ out2)
{
  const float s = *S;
  out2[0] = 0.25f * s / 8388608.f;
  out2[1] = s / 8388608.f;
}

__global__ void gather16_kernel(const int* __restrict__ idx, const short* __restrict__ cbb,
                                short* __restrict__ out)
{
  const int t = blockIdx.x * 256 + threadIdx.x;
  const int m = t >> 6, d4 = (t & 63) * 4;
  *(s16x4*)(out + (size_t)m * 256 + d4) = *(const s16x4*)(cbb + (size_t)idx[m] * 256 + d4);
}

// ========================= convT3: 128->3, 32->64, direct ==================
__global__ __launch_bounds__(256) void convt3_kernel(
    const short* __restrict__ in, const float* __restrict__ w,
    const float* __restrict__ bias, float* __restrict__ out)
{
  __shared__ __align__(16) short li[100 * 136];
  __shared__ float lw[6144];
  const int tid = threadIdx.x;
  const int tile = blockIdx.x;          // 0..15
  const int b = blockIdx.y;
  const int ty0 = (tile >> 2) * 16, tx0 = (tile & 3) * 16;
  const int iy0 = (tile >> 2) * 8 - 1, ix0 = (tile & 3) * 8 - 1;
  for (int s = tid; s < 1600; s += 256) {
    const int pix = s >> 4, ch = s & 15;
    const int r = pix / 10, c = pix - r * 10;
    const int ih = iy0 + r, iw = ix0 + c;
    s16x8 v = {0, 0, 0, 0, 0, 0, 0, 0};
    if ((unsigned)ih < 32u && (unsigned)iw < 32u)
      v = *(const s16x8*)(in + ((size_t)b * 1024 + ih * 32 + iw) * 128 + ch * 8);
    *(s16x8*)&li[pix * 136 + ch * 8] = v;
  }
  for (int s = tid; s < 6144; s += 256) lw[s] = w[s];
  __syncthreads();
  const int ty = tid >> 4, tx = tid & 15;
  const int oh2 = ty0 + ty, ow2 = tx0 + tx;
  const int kh0 = (oh2 + 1) & 1, kw0 = (ow2 + 1) & 1;
  const int ih0 = (oh2 + 1 - kh0) >> 1, iw0 = (ow2 + 1 - kw0) >> 1;
  const int rl0 = ih0 - iy0, cl0 = iw0 - ix0;
  const int p00 = rl0 * 10 + cl0, p01 = p00 - 1, p10 = p00 - 10, p11 = p00 - 11;
  const int wi00 = kh0 * 4 + kw0, wi01 = wi00 + 2, wi10 = wi00 + 8, wi11 = wi00 + 10;
  float acc0 = 0.f, acc1 = 0.f, acc2 = 0.f;
  for (int ch = 0; ch < 16; ++ch) {
    const s16x8 v00 = *(const s16x8*)&li[p00 * 136 + ch * 8];
    const s16x8 v01 = *(const s16x8*)&li[p01 * 136 + ch * 8];
    const s16x8 v10 = *(const s16x8*)&li[p10 * 136 + ch * 8];
    const s16x8 v11 = *(const s16x8*)&li[p11 * 136 + ch * 8];
#pragma unroll
    for (int e = 0; e < 8; ++e) {
      const int ci = ch * 8 + e;
      const float* wr = &lw[ci * 48];
      const float f00 = bf2f(v00[e]), f01 = bf2f(v01[e]);
      const float f10 = bf2f(v10[e]), f11 = bf2f(v11[e]);
      acc0 = fmaf(wr[wi00], f00, fmaf(wr[wi01], f01, fmaf(wr[wi10], f10, fmaf(wr[wi11], f11, acc0))));
      acc1 = fmaf(wr[16 + wi00], f00, fmaf(wr[16 + wi01], f01, fmaf(wr[16 + wi10], f10, fmaf(wr[16 + wi11], f11, acc1))));
      acc2 = fmaf(wr[32 + wi00], f00, fmaf(wr[32 + wi01], f01, fmaf(wr[32 + wi10], f10, fmaf(wr[32 + wi11], f11, acc2))));
    }
  }
  const size_t ob = ((size_t)(b * 3) * 64 + oh2) * 64 + ow2;
  out[ob] = acc0 + bias[0];
  out[ob + 4096] = acc1 + bias[1];
  out[ob + 8192] = acc2 + bias[2];
}

// =====================================================================
extern "C" void kernel_launch(void* const* d_in, const int* in_sizes, int n_in,
                              void* d_out, int out_size, void* d_ws, size_t ws_size,
                              hipStream_t stream)
{
  const float* x     = (const float*)d_in[0];
  const float* ew1   = (const float*)d_in[1];
  const float* eb1   = (const float*)d_in[2];
  const float* ew2   = (const float*)d_in[3];
  const float* eb2   = (const float*)d_in[4];
  const float* ew3   = (const float*)d_in[5];
  const float* eb3   = (const float*)d_in[6];
  const float* er1aw = (const float*)d_in[7];
  const float* er1ab = (const float*)d_in[8];
  const float* er1bw = (const float*)d_in[9];
  const float* er1bb = (const float*)d_in[10];
  const float* er2aw = (const float*)d_in[11];
  const float* er2ab = (const float*)d_in[12];
  const float* er2bw = (const float*)d_in[13];
  const float* er2bb = (const float*)d_in[14];
  const float* cb    = (const float*)d_in[15];
  const float* pi    = (const float*)d_in[16];
  const float* dr1aw = (const float*)d_in[17];
  const float* dr1ab = (const float*)d_in[18];
  const float* dr1bw = (const float*)d_in[19];
  const float* dr1bb = (const float*)d_in[20];
  const float* dr2aw = (const float*)d_in[21];
  const float* dr2ab = (const float*)d_in[22];
  const float* dr2bw = (const float*)d_in[23];
  const float* dr2bb = (const float*)d_in[24];
  const float* dw1   = (const float*)d_in[25];
  const float* db1   = (const float*)d_in[26];
  const float* dwt2  = (const float*)d_in[27];
  const float* dbt2  = (const float*)d_in[28];
  const float* dwt3  = (const float*)d_in[29];
  const float* dbt3  = (const float*)d_in[30];

  float* outf = (float*)d_out;

  // workspace layout (bytes), ~168 MB of 256 MiB
  char* W = (char*)d_ws;
  short* BIGA  = (short*)W;                    // 33.5MB: conv1-out -> ZF32 -> convt2-out
  float* ZF32  = (float*)W;
  short* DV    = (short*)(W + 33554432);       // 67MB bf16 [32768][1024]: dv -> P
  short* X0    = (short*)(W + 100663296);      // 16.7MB each
  short* X1    = (short*)(W + 117440512);
  short* X2    = (short*)(W + 134217728);
  short* WT3   = (short*)(W + 150994944);      // 1,179,648 B
  short* WT2   = (short*)(W + 152174592);      // 1,048,576 B
  short* WTT2  = (short*)(W + 153223168);      // 1,048,576 B
  short* CBB   = (short*)(W + 154271744);      //   524,288 B
  short* CBT   = (short*)(W + 154796032);      //   524,288 B
  float* cn    = (float*)(W + 155320320);      //     4,096 B
  float* qsum  = (float*)(W + 155324416);
  float* logq  = (float*)(W + 155328512);
  int*   idx   = (int*)(W + 155332608);        //   131,072 B
  float* Sacc  = (float*)(W + 155463680);
  short* zerob = (short*)(W + 155463696);
  float* PART  = (float*)(W + 160000000);      // 8,388,608 B [2048][1024]

  const dim3 blk(256);
  #define IG3(A_, W_, B_, R_, O_, F_) \
    igemm_kernel<0,4,72,256,256><<<dim3(512), blk, 0, stream>>>(A_, W_, B_, R_, O_, F_, zerob, 0, 0)

  init0_kernel<<<dim3(1), dim3(64), 0, stream>>>(zerob);

  // -------- encoder --------
  conv1_kernel<<<dim3(4, NB), blk, 0, stream>>>(x, ew1, eb1, BIGA);
  w2t_kernel<<<dim3(2048), blk, 0, stream>>>(ew2, WT2);
  igemm_kernel<2,4,64,128,128><<<dim3(512), blk, 0, stream>>>(
      BIGA, WT2, eb2, nullptr, X0, nullptr, zerob, 0, 0);
  w3t_kernel<<<dim3(2304), blk, 0, stream>>>(ew3, WT3);
  IG3(X0, WT3, eb3, nullptr, X1, nullptr);                 // h3
  w3t_kernel<<<dim3(2304), blk, 0, stream>>>(er1aw, WT3);
  IG3(X1, WT3, er1ab, nullptr, X2, nullptr);
  w3t_kernel<<<dim3(2304), blk, 0, stream>>>(er1bw, WT3);
  IG3(X2, WT3, er1bb, X1, X0, nullptr);                    // h4
  w3t_kernel<<<dim3(2304), blk, 0, stream>>>(er2aw, WT3);
  IG3(X0, WT3, er2ab, nullptr, X1, nullptr);
  w3t_kernel<<<dim3(2304), blk, 0, stream>>>(er2bw, WT3);
  IG3(X1, WT3, er2bb, X0, X2, ZF32);                       // z (bf16 + fp32 dup)

  // -------- VQ / Blahut-Arimoto --------
  rownorm_kernel<<<dim3(KCB / 4), blk, 0, stream>>>(cb, cn, KCB);
  cbbf_kernel<<<dim3(1024), blk, 0, stream>>>(cb, CBB);
  cbt_kernel<<<dim3(1024), blk, 0, stream>>>(cb, CBT);
  initq_kernel<<<dim3(4), blk, 0, stream>>>(pi, logq, Sacc);
  igemm_kernel<4,4,8,256,256><<<dim3(512, 4), blk, 0, stream>>>(
      X2, CBB, cn, nullptr, DV, nullptr, zerob, 0, 0);
  for (int i = 0; i < 5; ++i) {
    ba2_kernel<<<dim3(NROW / 16), blk, 0, stream>>>(
        (unsigned*)DV, logq, PART, idx, (i == 4) ? 1 : 0);
    qred_kernel<<<dim3(4), blk, 0, stream>>>(PART, qsum, logq);
  }
  ent_kernel<<<dim3(1), dim3(1024), 0, stream>>>(qsum, outf + 1572866);
  pvq_kernel<<<dim3(512), blk, 0, stream>>>(DV, CBT, ZF32, Sacc);
  scalars_kernel<<<dim3(1), dim3(1), 0, stream>>>(Sacc, outf + 1572864);
  gather16_kernel<<<dim3(8192), blk, 0, stream>>>(idx, CBB, X0);  // zq_hard NHWC bf16

  // -------- decoder --------
  w3t_kernel<<<dim3(2304), blk, 0, stream>>>(dr1aw, WT3);
  IG3(X0, WT3, dr1ab, nullptr, X1, nullptr);
  w3t_kernel<<<dim3(2304), blk, 0, stream>>>(dr1bw, WT3);
  IG3(X1, WT3, dr1bb, X0, X2, nullptr);                    // y1
  w3t_kernel<<<dim3(2304), blk, 0, stream>>>(dr2aw, WT3);
  IG3(X2, WT3, dr2ab, nullptr, X0, nullptr);
  w3t_kernel<<<dim3(2304), blk, 0, stream>>>(dr2bw, WT3);
  IG3(X0, WT3, dr2bb, X2, X1, nullptr);                    // y2
  w3t_kernel<<<dim3(2304), blk, 0, stream>>>(dw1, WT3);
  IG3(X1, WT3, db1, nullptr, X0, nullptr);                 // y3
  wtt2_kernel<<<dim3(2048), blk, 0, stream>>>(dwt2, WTT2);
  for (int p = 0; p < 4; ++p)
    igemm_kernel<3,2,32,256,256><<<dim3(512), blk, 0, stream>>>(
        X0, WTT2 + p * 131072, dbt2, nullptr, BIGA, nullptr, zerob, p >> 1, p & 1);
  convt3_kernel<<<dim3(16, NB), blk, 0, stream>>>(BIGA, dwt3, dbt3, outf);
  #undef IG3
}

// Round 7
// 1538.537 us; speedup vs baseline: 1.4478x; 1.4478x over previous
//
#include <hip/hip_runtime.h>
#include <math.h>

// ---------------- problem constants ----------------
#define NB   128
#define DC   256
#define SP   256
#define NROW 32768
#define KCB  1024
#define BETA_F 0.1f
#define EPSQ 1e-10f

typedef __attribute__((ext_vector_type(8))) short s16x8;
typedef __attribute__((ext_vector_type(4))) short s16x4;
typedef __attribute__((ext_vector_type(4))) float f32x4;

__device__ __forceinline__ short f2bf(float f) {
  unsigned u = __builtin_bit_cast(unsigned, f);
  unsigned r = (u + 0x7FFFu + ((u >> 16) & 1u)) >> 16;
  return (short)r;
}
__device__ __forceinline__ float bf2f(short s) {
  unsigned u = ((unsigned)(unsigned short)s) << 16;
  return __builtin_bit_cast(float, u);
}
__device__ __forceinline__ unsigned pack2(float a, float b) {
  return (unsigned)(unsigned short)f2bf(a) | ((unsigned)(unsigned short)f2bf(b) << 16);
}

// ========================= init: zero the zero-source buffer ===============
__global__ void init0_kernel(short* __restrict__ zerob)
{
  if (threadIdx.x < 8) zerob[threadIdx.x] = 0;
}

// ========================= weight transposes (fp32 -> bf16) =================
__global__ void w3t_kernel(const float* __restrict__ w, short* __restrict__ o)
{
  const int i = blockIdx.x * 256 + threadIdx.x;  // 589824
  const int ci = i & 255, co = (i >> 8) & 255, j = i >> 16;
  o[i] = f2bf(w[((size_t)(co * 256 + ci)) * 9 + j]);
}
__global__ void w2t_kernel(const float* __restrict__ w, short* __restrict__ o)
{
  const int i = blockIdx.x * 256 + threadIdx.x;  // 524288
  const int ci = i & 127, co = (i >> 7) & 255, j = i >> 15;
  o[i] = f2bf(w[((size_t)(co * 128 + ci)) * 16 + j]);
}
__global__ void wtt2_kernel(const float* __restrict__ w, short* __restrict__ o)
{
  const int i = blockIdx.x * 256 + threadIdx.x;  // 524288
  const int ci = i & 255, co = (i >> 8) & 127, j = (i >> 15) & 3, p = i >> 17;
  const int po = p >> 1, pq = p & 1, a = j >> 1, b2 = j & 1;
  const int kh = (1 - po) + 2 * a, kw = (1 - pq) + 2 * b2;
  o[i] = f2bf(w[((size_t)(ci * 128 + co)) * 16 + kh * 4 + kw]);
}
__global__ void cbbf_kernel(const float* __restrict__ cb, short* __restrict__ o)
{
  const int i = blockIdx.x * 256 + threadIdx.x;  // 262144
  o[i] = f2bf(cb[i]);
}
__global__ void cbt_kernel(const float* __restrict__ cb, short* __restrict__ o)
{
  const int i = blockIdx.x * 256 + threadIdx.x;  // 262144
  const int d = i >> 10, k = i & 1023;
  o[i] = f2bf(cb[(size_t)k * 256 + d]);
}

// ========================= conv1: 3->128, 4x4 s2, 64->32, out NHWC bf16 =====
// wave-per-pixel, lane-per-2-cout. Coalesced 256B/wave output stores.
__global__ __launch_bounds__(256) void conv1_kernel(
    const float* __restrict__ x, const float* __restrict__ w,
    const float* __restrict__ bias, short* __restrict__ out)
{
  __shared__ float li[3][34][34];
  const int tid = threadIdx.x;
  const int tile = blockIdx.x;          // 0..3 quadrant of 32x32 output
  const int b = blockIdx.y;
  const int qy = tile >> 1, qx = tile & 1;
  const int ihlo = qy * 32 - 1, iwlo = qx * 32 - 1;
  for (int ci = 0; ci < 3; ++ci)
    for (int s = tid; s < 1156; s += 256) {
      const int r = s / 34, c = s - r * 34;
      const int ih = ihlo + r, iw = iwlo + c;
      float v = 0.f;
      if ((unsigned)ih < 64u && (unsigned)iw < 64u)
        v = x[((size_t)(b * 3 + ci) * 64 + ih) * 64 + iw];
      li[ci][r][c] = v;
    }
  __syncthreads();

  const int wv = tid >> 6, l = tid & 63;
  const int co0 = 2 * l, co1 = 2 * l + 1;
  float w0[48], w1[48];
#pragma unroll
  for (int j = 0; j < 48; ++j) {
    w0[j] = w[(size_t)co0 * 48 + j];
    w1[j] = w[(size_t)co1 * 48 + j];
  }
  const float b0 = bias[co0], b1 = bias[co1];

  for (int pass = 0; pass < 64; ++pass) {
    const int pix = pass * 4 + wv;            // 0..255
    const int py = pix >> 4, px = pix & 15;
    float s0 = b0, s1 = b1;
#pragma unroll
    for (int ci = 0; ci < 3; ++ci)
#pragma unroll
      for (int kh = 0; kh < 4; ++kh)
#pragma unroll
        for (int kw = 0; kw < 4; ++kw) {
          const int j = ci * 16 + kh * 4 + kw;
          const float v = li[ci][2 * py + kh][2 * px + kw];  // wave-broadcast
          s0 = fmaf(v, w0[j], s0);
          s1 = fmaf(v, w1[j], s1);
        }
    s0 = fmaxf(s0, 0.f);
    s1 = fmaxf(s1, 0.f);
    const int oh = qy * 16 + py, ow = qx * 16 + px;
    ((unsigned*)(out + ((size_t)b * 1024 + oh * 32 + ow) * 128))[l] = pack2(s0, s1);
  }
}

// ========================= MFMA implicit GEMM ===============================
// MODE 0: conv3x3 (A [32768][256], N=256, K=9*256), optional res, optional f32 dup
// MODE 2: conv4x4 s2 (A [131072][128], N=256, K=16*128)
// MODE 3: convT2 per-parity (A [32768][256], N=128, K=4*256), scatter out
// MODE 4: distance variant (out DV bf16 = cn[n] - 2*acc)
template<int MODE, int NSUB, int KIT, int AK, int KPN>
__global__ __launch_bounds__(256) void igemm_kernel(
    const short* __restrict__ Abuf, const short* __restrict__ Bw,
    const float* __restrict__ bias, const short* __restrict__ res,
    short* __restrict__ outb, float* __restrict__ outf32,
    const short* __restrict__ zerob, int po, int pq)
{
  __shared__ __align__(16) short Alds[2][2048];    // 2 x [64 rows][32 ci] bf16
  const int tid = threadIdx.x;
  const int wv = tid >> 6, l = tid & 63;
  const int lcol = l & 15, lk = l >> 4;
  const int m0 = blockIdx.x * 64;

  const int srow = tid >> 2;
  const int sm = m0 + srow;
  const int cchunk = (tid & 3) ^ (srow & 3);
  const int s_img = sm & ~255;
  const int s_h = (sm >> 4) & 15, s_w = sm & 15;
  const int s_b1024 = (sm >> 8) * 1024;
  short* stage_dst = &Alds[0][wv * 512];

  const short* Bp = Bw;
  if constexpr (MODE == 4) Bp += (size_t)blockIdx.y * 65536;

  f32x4 acc[4][NSUB];
#pragma unroll
  for (int i = 0; i < 4; ++i)
#pragma unroll
    for (int j = 0; j < NSUB; ++j) acc[i][j] = (f32x4){0.f, 0.f, 0.f, 0.f};

  int boff[NSUB];
#pragma unroll
  for (int ns = 0; ns < NSUB; ++ns)
    boff[ns] = (wv * (NSUB * 16) + ns * 16 + lcol) * KPN + lk * 8;

  const int aoff_base = lcol * 32 + ((lk ^ (lcol & 3)) * 8);

  auto STAGE = [&](int it, int bufc) {
    int kk, ih, iw, srcrow; bool v;
    if constexpr (MODE == 0) {
      const int jj = it >> 3; kk = it & 7;
      const int q3 = jj / 3;
      ih = s_h + q3 - 1; iw = s_w + (jj - q3 * 3) - 1;
      v = ((unsigned)ih < 16u) & ((unsigned)iw < 16u);
      srcrow = s_img + ih * 16 + iw;
    } else if constexpr (MODE == 2) {
      const int jj = it >> 2; kk = it & 3;
      ih = 2 * s_h + (jj >> 2) - 1; iw = 2 * s_w + (jj & 3) - 1;
      v = ((unsigned)ih < 32u) & ((unsigned)iw < 32u);
      srcrow = s_b1024 + ih * 32 + iw;
    } else if constexpr (MODE == 4) {
      kk = it; v = true; srcrow = sm;
    } else {
      const int jj = it >> 3; kk = it & 7;
      ih = s_h + po - (jj >> 1); iw = s_w + pq - (jj & 1);
      v = ((unsigned)ih < 16u) & ((unsigned)iw < 16u);
      srcrow = s_img + ih * 16 + iw;
    }
    const short* src = v ? (Abuf + (size_t)srcrow * AK + kk * 32 + cchunk * 8) : zerob;
    __builtin_amdgcn_global_load_lds(
        (const __attribute__((address_space(1))) void*)src,
        (__attribute__((address_space(3))) void*)(stage_dst + bufc * 2048),
        16, 0, 0);
  };

  auto COMPUTE = [&](int it, int bufc) {
    int uoff;
    if constexpr (MODE == 0)      uoff = (it >> 3) * 65536 + (it & 7) * 32;
    else if constexpr (MODE == 2) uoff = (it >> 2) * 32768 + (it & 3) * 32;
    else if constexpr (MODE == 4) uoff = it * 32;
    else                          uoff = (it >> 3) * 32768 + (it & 7) * 32;
    s16x8 a[4], b[NSUB];
#pragma unroll
    for (int ms = 0; ms < 4; ++ms)
      a[ms] = *(const s16x8*)&Alds[bufc][aoff_base + ms * 512];
#pragma unroll
    for (int ns = 0; ns < NSUB; ++ns)
      b[ns] = *(const s16x8*)(Bp + uoff + boff[ns]);
#pragma unroll
    for (int ms = 0; ms < 4; ++ms)
#pragma unroll
      for (int ns = 0; ns < NSUB; ++ns)
        acc[ms][ns] = __builtin_amdgcn_mfma_f32_16x16x32_bf16(a[ms], b[ns], acc[ms][ns], 0, 0, 0);
  };

  STAGE(0, 0);
  for (int it = 0; it < KIT; it += 2) {
    __syncthreads();
    if (it + 1 < KIT) STAGE(it + 1, 1);
    COMPUTE(it, 0);
    __syncthreads();
    if (it + 2 < KIT) STAGE(it + 2, 0);
    COMPUTE(it + 1, 1);
  }

  const int r4 = lk * 4;
#pragma unroll
  for (int ms = 0; ms < 4; ++ms) {
#pragma unroll
    for (int ns = 0; ns < NSUB; ++ns) {
      const int n_l = wv * (NSUB * 16) + ns * 16 + lcol;
#pragma unroll
      for (int e = 0; e < 4; ++e) {
        const int m = m0 + ms * 16 + r4 + e;
        if constexpr (MODE == 4) {
          const int n_g = blockIdx.y * 256 + n_l;
          const float val = bias[n_g] - 2.f * acc[ms][ns][e];
          outb[(size_t)m * 1024 + n_g] = f2bf(val);
        } else {
          float val = acc[ms][ns][e] + bias[n_l];
          if constexpr (MODE == 3) {
            val = fmaxf(val, 0.f);
            const int orow = (m & ~255) * 4 + (2 * ((m >> 4) & 15) + po) * 32 + (2 * (m & 15) + pq);
            outb[(size_t)orow * 128 + n_l] = f2bf(val);
          } else {
            if (res) val += bf2f(res[(size_t)m * 256 + n_l]);
            val = fmaxf(val, 0.f);
            outb[(size_t)m * 256 + n_l] = f2bf(val);
            if (outf32) outf32[(size_t)m * 256 + n_l] = val;
          }
        }
      }
    }
  }
}

// ========================= VQ block =========================================
__global__ __launch_bounds__(256) void rownorm_kernel(
    const float* __restrict__ a, float* __restrict__ nrm, int rows)
{
  const int wv = threadIdx.x >> 6, lane = threadIdx.x & 63;
  const int r = blockIdx.x * 4 + wv;
  if (r >= rows) return;
  const float* p = a + (size_t)r * DC;
  float s = 0.f;
#pragma unroll
  for (int i = 0; i < 4; ++i) { float v = p[lane + 64 * i]; s = fmaf(v, v, s); }
#pragma unroll
  for (int o = 32; o > 0; o >>= 1) s += __shfl_xor(s, o);
  if (lane == 0) nrm[r] = s;
}

__global__ void initq_kernel(const float* __restrict__ pi, float* __restrict__ logq,
                             float* __restrict__ Sacc)
{
  const int k = blockIdx.x * 256 + threadIdx.x;
  logq[k] = logf(fmaxf(pi[k], EPSQ));
  if (k == 0) *Sacc = 0.f;
}

// one BA iteration over bf16 DV; per-block Q-partials to PART (no atomics).
__global__ __launch_bounds__(256) void ba2_kernel(
    unsigned* __restrict__ DV, const float* __restrict__ logq,
    float* __restrict__ part, int* __restrict__ idxout, int storeP)
{
  __shared__ float qp[4][1024];
  const int tid = threadIdx.x;
  const int wv = tid >> 6, lane = tid & 63;
  for (int i = tid; i < 4096; i += 256) ((float*)qp)[i] = 0.f;
  __syncthreads();

  float2 lq[8];
#pragma unroll
  for (int it = 0; it < 8; ++it) lq[it] = *(const float2*)&logq[it * 128 + lane * 2];

  const int n0 = blockIdx.x * 16;
  for (int rr = 0; rr < 4; ++rr) {
    const int n = n0 + wv * 4 + rr;
    unsigned* rowp = DV + (size_t)n * 512;
    float l0[8], l1[8];
    float mx = -1e30f;
#pragma unroll
    for (int it = 0; it < 8; ++it) {
      const unsigned w = rowp[it * 64 + lane];
      l0[it] = lq[it].x - BETA_F * bf2f((short)(w & 0xFFFFu));
      l1[it] = lq[it].y - BETA_F * bf2f((short)(w >> 16));
      mx = fmaxf(mx, fmaxf(l0[it], l1[it]));
    }
#pragma unroll
    for (int o = 32; o > 0; o >>= 1) mx = fmaxf(mx, __shfl_xor(mx, o));
    float e0[8], e1[8];
    float s = 0.f;
#pragma unroll
    for (int it = 0; it < 8; ++it) {
      e0[it] = __expf(l0[it] - mx);
      e1[it] = __expf(l1[it] - mx);
      s += e0[it] + e1[it];
    }
#pragma unroll
    for (int o = 32; o > 0; o >>= 1) s += __shfl_xor(s, o);
    const float inv = 1.f / s;
#pragma unroll
    for (int it = 0; it < 8; ++it) {
      qp[wv][it * 128 + lane * 2]     += e0[it] * inv;
      qp[wv][it * 128 + lane * 2 + 1] += e1[it] * inv;
    }

    if (storeP) {
#pragma unroll
      for (int it = 0; it < 8; ++it)
        rowp[it * 64 + lane] = pack2(e0[it] * inv, e1[it] * inv);
      float bv = l0[0]; int bi = lane * 2;
      if (l1[0] > bv) { bv = l1[0]; bi = lane * 2 + 1; }
#pragma unroll
      for (int it = 1; it < 8; ++it) {
        const int k = it * 128 + lane * 2;
        if (l0[it] > bv) { bv = l0[it]; bi = k; }
        if (l1[it] > bv) { bv = l1[it]; bi = k + 1; }
      }
#pragma unroll
      for (int o = 32; o > 0; o >>= 1) {
        const float ov = __shfl_xor(bv, o);
        const int oi = __shfl_xor(bi, o);
        if (ov > bv || (ov == bv && oi < bi)) { bv = ov; bi = oi; }
      }
      if (lane == 0) idxout[n] = bi;
    }
  }
  __syncthreads();
  for (int k = tid; k < 1024; k += 256) {
    part[(size_t)blockIdx.x * 1024 + k] = qp[0][k] + qp[1][k] + qp[2][k] + qp[3][k];
  }
}

// reduce stage 1: 64 blocks; block b sums PART rows [32b,32b+32) -> PART2[b][1024]
__global__ __launch_bounds__(256) void qred1_kernel(
    const float* __restrict__ part, float* __restrict__ part2)
{
  const int b = blockIdx.x;
  const int tid = threadIdx.x;
  const float* p = part + (size_t)b * 32 * 1024;
#pragma unroll
  for (int j = 0; j < 4; ++j) {
    const int k = tid + j * 256;
    float s = 0.f;
#pragma unroll
    for (int r = 0; r < 32; ++r) s += p[(size_t)r * 1024 + k];
    part2[(size_t)b * 1024 + k] = s;
  }
}

// reduce stage 2: 4 blocks x 256; sum 64 entries/column -> qsum, logq
__global__ __launch_bounds__(256) void qred2_kernel(
    const float* __restrict__ part2, float* __restrict__ qsum, float* __restrict__ logq)
{
  const int k = blockIdx.x * 256 + threadIdx.x;
  float s = 0.f;
#pragma unroll
  for (int r = 0; r < 64; ++r) s += part2[(size_t)r * 1024 + k];
  qsum[k] = s;
  logq[k] = logf(fmaxf(s * (1.f / 32768.f), EPSQ));
}

__global__ __launch_bounds__(1024) void ent_kernel(
    const float* __restrict__ qsum, float* __restrict__ out_ent)
{
  const int k = threadIdx.x;
  const float q = fmaxf(qsum[k] * (1.f / 32768.f), EPSQ);
  float v = q * logf(q);
#pragma unroll
  for (int o = 32; o > 0; o >>= 1) v += __shfl_xor(v, o);
  __shared__ float red[16];
  const int wv = k >> 6, lane = k & 63;
  if (lane == 0) red[wv] = v;
  __syncthreads();
  if (k == 0) {
    float s = 0.f;
    for (int i = 0; i < 16; ++i) s += red[i];
    *out_ent = 0.01f * s;
  }
}

// zq_soft = P @ cbT via MFMA; fused sum((zq_soft - zf)^2) into Sacc.
__global__ __launch_bounds__(256) void pvq_kernel(
    const short* __restrict__ P, const short* __restrict__ CBT,
    const float* __restrict__ zf32, float* __restrict__ Sacc)
{
  __shared__ __align__(16) short Alds[2][2048];
  __shared__ float red[4];
  const int tid = threadIdx.x;
  const int wv = tid >> 6, l = tid & 63;
  const int lcol = l & 15, lk = l >> 4;
  const int m0 = blockIdx.x * 64;

  const int srow = tid >> 2;
  const int cchunk = (tid & 3) ^ (srow & 3);
  short* stage_dst = &Alds[0][wv * 512];

  f32x4 acc[4][4];
#pragma unroll
  for (int i = 0; i < 4; ++i)
#pragma unroll
    for (int j = 0; j < 4; ++j) acc[i][j] = (f32x4){0.f, 0.f, 0.f, 0.f};

  int boff[4];
#pragma unroll
  for (int ns = 0; ns < 4; ++ns)
    boff[ns] = (wv * 64 + ns * 16 + lcol) * 1024 + lk * 8;

  const int aoff_base = lcol * 32 + ((lk ^ (lcol & 3)) * 8);

  auto STAGE = [&](int it, int bufc) {
    const short* src = P + (size_t)(m0 + srow) * 1024 + it * 32 + cchunk * 8;
    __builtin_amdgcn_global_load_lds(
        (const __attribute__((address_space(1))) void*)src,
        (__attribute__((address_space(3))) void*)(stage_dst + bufc * 2048),
        16, 0, 0);
  };
  auto COMPUTE = [&](int it, int bufc) {
    s16x8 a[4], b[4];
#pragma unroll
    for (int ms = 0; ms < 4; ++ms)
      a[ms] = *(const s16x8*)&Alds[bufc][aoff_base + ms * 512];
#pragma unroll
    for (int ns = 0; ns < 4; ++ns)
      b[ns] = *(const s16x8*)(CBT + it * 32 + boff[ns]);
#pragma unroll
    for (int ms = 0; ms < 4; ++ms)
#pragma unroll
      for (int ns = 0; ns < 4; ++ns)
        acc[ms][ns] = __builtin_amdgcn_mfma_f32_16x16x32_bf16(a[ms], b[ns], acc[ms][ns], 0, 0, 0);
  };

  STAGE(0, 0);
  for (int it = 0; it < 32; it += 2) {
    __syncthreads();
    if (it + 1 < 32) STAGE(it + 1, 1);
    COMPUTE(it, 0);
    __syncthreads();
    if (it + 2 < 32) STAGE(it + 2, 0);
    COMPUTE(it + 1, 1);
  }

  float ls = 0.f;
  const int r4 = lk * 4;
#pragma unroll
  for (int ms = 0; ms < 4; ++ms) {
#pragma unroll
    for (int ns = 0; ns < 4; ++ns) {
      const int n_l = wv * 64 + ns * 16 + lcol;
#pragma unroll
      for (int e = 0; e < 4; ++e) {
        const int m = m0 + ms * 16 + r4 + e;
        const float d = acc[ms][ns][e] - zf32[(size_t)m * 256 + n_l];
        ls = fmaf(d, d, ls);
      }
    }
  }
#pragma unroll
  for (int o = 32; o > 0; o >>= 1) ls += __shfl_xor(ls, o);
  if (l == 0) red[wv] = ls;
  __syncthreads();
  if (tid == 0) atomicAdd(Sacc, red[0] + red[1] + red[2] + red[3]);
}

__global__ void scalars_kernel(const float* __restrict__ S, float* __restrict__ out2)
{
  const float s = *S;
  out2[0] = 0.25f * s / 8388608.f;
  out2[1] = s / 8388608.f;
}

__global__ void gather16_kernel(const int* __restrict__ idx, const short* __restrict__ cbb,
                                short* __restrict__ out)
{
  const int t = blockIdx.x * 256 + threadIdx.x;
  const int m = t >> 6, d4 = (t & 63) * 4;
  *(s16x4*)(out + (size_t)m * 256 + d4) = *(const s16x4*)(cbb + (size_t)idx[m] * 256 + d4);
}

// ========================= convT3: 128->3, 32->64, direct ==================
__global__ __launch_bounds__(256) void convt3_kernel(
    const short* __restrict__ in, const float* __restrict__ w,
    const float* __restrict__ bias, float* __restrict__ out)
{
  __shared__ __align__(16) short li[100 * 136];
  __shared__ float lw[6144];
  const int tid = threadIdx.x;
  const int tile = blockIdx.x;          // 0..15
  const int b = blockIdx.y;
  const int ty0 = (tile >> 2) * 16, tx0 = (tile & 3) * 16;
  const int iy0 = (tile >> 2) * 8 - 1, ix0 = (tile & 3) * 8 - 1;
  for (int s = tid; s < 1600; s += 256) {
    const int pix = s >> 4, ch = s & 15;
    const int r = pix / 10, c = pix - r * 10;
    const int ih = iy0 + r, iw = ix0 + c;
    s16x8 v = {0, 0, 0, 0, 0, 0, 0, 0};
    if ((unsigned)ih < 32u && (unsigned)iw < 32u)
      v = *(const s16x8*)(in + ((size_t)b * 1024 + ih * 32 + iw) * 128 + ch * 8);
    *(s16x8*)&li[pix * 136 + ch * 8] = v;
  }
  for (int s = tid; s < 6144; s += 256) lw[s] = w[s];
  __syncthreads();
  const int ty = tid >> 4, tx = tid & 15;
  const int oh2 = ty0 + ty, ow2 = tx0 + tx;
  const int kh0 = (oh2 + 1) & 1, kw0 = (ow2 + 1) & 1;
  const int ih0 = (oh2 + 1 - kh0) >> 1, iw0 = (ow2 + 1 - kw0) >> 1;
  const int rl0 = ih0 - iy0, cl0 = iw0 - ix0;
  const int p00 = rl0 * 10 + cl0, p01 = p00 - 1, p10 = p00 - 10, p11 = p00 - 11;
  const int wi00 = kh0 * 4 + kw0, wi01 = wi00 + 2, wi10 = wi00 + 8, wi11 = wi00 + 10;
  float acc0 = 0.f, acc1 = 0.f, acc2 = 0.f;
  for (int ch = 0; ch < 16; ++ch) {
    const s16x8 v00 = *(const s16x8*)&li[p00 * 136 + ch * 8];
    const s16x8 v01 = *(const s16x8*)&li[p01 * 136 + ch * 8];
    const s16x8 v10 = *(const s16x8*)&li[p10 * 136 + ch * 8];
    const s16x8 v11 = *(const s16x8*)&li[p11 * 136 + ch * 8];
#pragma unroll
    for (int e = 0; e < 8; ++e) {
      const int ci = ch * 8 + e;
      const float* wr = &lw[ci * 48];
      const float f00 = bf2f(v00[e]), f01 = bf2f(v01[e]);
      const float f10 = bf2f(v10[e]), f11 = bf2f(v11[e]);
      acc0 = fmaf(wr[wi00], f00, fmaf(wr[wi01], f01, fmaf(wr[wi10], f10, fmaf(wr[wi11], f11, acc0))));
      acc1 = fmaf(wr[16 + wi00], f00, fmaf(wr[16 + wi01], f01, fmaf(wr[16 + wi10], f10, fmaf(wr[16 + wi11], f11, acc1))));
      acc2 = fmaf(wr[32 + wi00], f00, fmaf(wr[32 + wi01], f01, fmaf(wr[32 + wi10], f10, fmaf(wr[32 + wi11], f11, acc2))));
    }
  }
  const size_t ob = ((size_t)(b * 3) * 64 + oh2) * 64 + ow2;
  out[ob] = acc0 + bias[0];
  out[ob + 4096] = acc1 + bias[1];
  out[ob + 8192] = acc2 + bias[2];
}

// =====================================================================
extern "C" void kernel_launch(void* const* d_in, const int* in_sizes, int n_in,
                              void* d_out, int out_size, void* d_ws, size_t ws_size,
                              hipStream_t stream)
{
  const float* x     = (const float*)d_in[0];
  const float* ew1   = (const float*)d_in[1];
  const float* eb1   = (const float*)d_in[2];
  const float* ew2   = (const float*)d_in[3];
  const float* eb2   = (const float*)d_in[4];
  const float* ew3   = (const float*)d_in[5];
  const float* eb3   = (const float*)d_in[6];
  const float* er1aw = (const float*)d_in[7];
  const float* er1ab = (const float*)d_in[8];
  const float* er1bw = (const float*)d_in[9];
  const float* er1bb = (const float*)d_in[10];
  const float* er2aw = (const float*)d_in[11];
  const float* er2ab = (const float*)d_in[12];
  const float* er2bw = (const float*)d_in[13];
  const float* er2bb = (const float*)d_in[14];
  const float* cb    = (const float*)d_in[15];
  const float* pi    = (const float*)d_in[16];
  const float* dr1aw = (const float*)d_in[17];
  const float* dr1ab = (const float*)d_in[18];
  const float* dr1bw = (const float*)d_in[19];
  const float* dr1bb = (const float*)d_in[20];
  const float* dr2aw = (const float*)d_in[21];
  const float* dr2ab = (const float*)d_in[22];
  const float* dr2bw = (const float*)d_in[23];
  const float* dr2bb = (const float*)d_in[24];
  const float* dw1   = (const float*)d_in[25];
  const float* db1   = (const float*)d_in[26];
  const float* dwt2  = (const float*)d_in[27];
  const float* dbt2  = (const float*)d_in[28];
  const float* dwt3  = (const float*)d_in[29];
  const float* dbt3  = (const float*)d_in[30];

  float* outf = (float*)d_out;

  // workspace layout (bytes), ~169 MB of 256 MiB
  char* W = (char*)d_ws;
  short* BIGA  = (short*)W;                    // 33.5MB: conv1-out -> ZF32 -> convt2-out
  float* ZF32  = (float*)W;
  short* DV    = (short*)(W + 33554432);       // 67MB bf16 [32768][1024]: dv -> P
  short* X0    = (short*)(W + 100663296);      // 16.7MB each
  short* X1    = (short*)(W + 117440512);
  short* X2    = (short*)(W + 134217728);
  short* WT3   = (short*)(W + 150994944);      // 1,179,648 B
  short* WT2   = (short*)(W + 152174592);      // 1,048,576 B
  short* WTT2  = (short*)(W + 153223168);      // 1,048,576 B
  short* CBB   = (short*)(W + 154271744);      //   524,288 B
  short* CBT   = (short*)(W + 154796032);      //   524,288 B
  float* cn    = (float*)(W + 155320320);      //     4,096 B
  float* qsum  = (float*)(W + 155324416);
  float* logq  = (float*)(W + 155328512);
  int*   idx   = (int*)(W + 155332608);        //   131,072 B
  float* Sacc  = (float*)(W + 155463680);
  short* zerob = (short*)(W + 155463696);
  float* PART  = (float*)(W + 160000000);      // 8,388,608 B [2048][1024]
  float* PART2 = (float*)(W + 168388608);      //   262,144 B [64][1024]

  const dim3 blk(256);
  #define IG3(A_, W_, B_, R_, O_, F_) \
    igemm_kernel<0,4,72,256,256><<<dim3(512), blk, 0, stream>>>(A_, W_, B_, R_, O_, F_, zerob, 0, 0)

  init0_kernel<<<dim3(1), dim3(64), 0, stream>>>(zerob);

  // -------- encoder --------
  conv1_kernel<<<dim3(4, NB), blk, 0, stream>>>(x, ew1, eb1, BIGA);
  w2t_kernel<<<dim3(2048), blk, 0, stream>>>(ew2, WT2);
  igemm_kernel<2,4,64,128,128><<<dim3(512), blk, 0, stream>>>(
      BIGA, WT2, eb2, nullptr, X0, nullptr, zerob, 0, 0);
  w3t_kernel<<<dim3(2304), blk, 0, stream>>>(ew3, WT3);
  IG3(X0, WT3, eb3, nullptr, X1, nullptr);                 // h3
  w3t_kernel<<<dim3(2304), blk, 0, stream>>>(er1aw, WT3);
  IG3(X1, WT3, er1ab, nullptr, X2, nullptr);
  w3t_kernel<<<dim3(2304), blk, 0, stream>>>(er1bw, WT3);
  IG3(X2, WT3, er1bb, X1, X0, nullptr);                    // h4
  w3t_kernel<<<dim3(2304), blk, 0, stream>>>(er2aw, WT3);
  IG3(X0, WT3, er2ab, nullptr, X1, nullptr);
  w3t_kernel<<<dim3(2304), blk, 0, stream>>>(er2bw, WT3);
  IG3(X1, WT3, er2bb, X0, X2, ZF32);                       // z (bf16 + fp32 dup)

  // -------- VQ / Blahut-Arimoto --------
  rownorm_kernel<<<dim3(KCB / 4), blk, 0, stream>>>(cb, cn, KCB);
  cbbf_kernel<<<dim3(1024), blk, 0, stream>>>(cb, CBB);
  cbt_kernel<<<dim3(1024), blk, 0, stream>>>(cb, CBT);
  initq_kernel<<<dim3(4), blk, 0, stream>>>(pi, logq, Sacc);
  igemm_kernel<4,4,8,256,256><<<dim3(512, 4), blk, 0, stream>>>(
      X2, CBB, cn, nullptr, DV, nullptr, zerob, 0, 0);
  for (int i = 0; i < 5; ++i) {
    ba2_kernel<<<dim3(NROW / 16), blk, 0, stream>>>(
        (unsigned*)DV, logq, PART, idx, (i == 4) ? 1 : 0);
    qred1_kernel<<<dim3(64), blk, 0, stream>>>(PART, PART2);
    qred2_kernel<<<dim3(4), blk, 0, stream>>>(PART2, qsum, logq);
  }
  ent_kernel<<<dim3(1), dim3(1024), 0, stream>>>(qsum, outf + 1572866);
  pvq_kernel<<<dim3(512), blk, 0, stream>>>(DV, CBT, ZF32, Sacc);
  scalars_kernel<<<dim3(1), dim3(1), 0, stream>>>(Sacc, outf + 1572864);
  gather16_kernel<<<dim3(8192), blk, 0, stream>>>(idx, CBB, X0);  // zq_hard NHWC bf16

  // -------- decoder --------
  w3t_kernel<<<dim3(2304), blk, 0, stream>>>(dr1aw, WT3);
  IG3(X0, WT3, dr1ab, nullptr, X1, nullptr);
  w3t_kernel<<<dim3(2304), blk, 0, stream>>>(dr1bw, WT3);
  IG3(X1, WT3, dr1bb, X0, X2, nullptr);                    // y1
  w3t_kernel<<<dim3(2304), blk, 0, stream>>>(dr2aw, WT3);
  IG3(X2, WT3, dr2ab, nullptr, X0, nullptr);
  w3t_kernel<<<dim3(2304), blk, 0, stream>>>(dr2bw, WT3);
  IG3(X0, WT3, dr2bb, X2, X1, nullptr);                    // y2
  w3t_kernel<<<dim3(2304), blk, 0, stream>>>(dw1, WT3);
  IG3(X1, WT3, db1, nullptr, X0, nullptr);                 // y3
  wtt2_kernel<<<dim3(2048), blk, 0, stream>>>(dwt2, WTT2);
  for (int p = 0; p < 4; ++p)
    igemm_kernel<3,2,32,256,256><<<dim3(512), blk, 0, stream>>>(
        X0, WTT2 + p * 131072, dbt2, nullptr, BIGA, nullptr, zerob, p >> 1, p & 1);
  convt3_kernel<<<dim3(16, NB), blk, 0, stream>>>(BIGA, dwt3, dbt3, outf);
  #undef IG3
}

// Round 8
// 1472.953 us; speedup vs baseline: 1.5123x; 1.0445x over previous
//
#include <hip/hip_runtime.h>
#include <math.h>

// ---------------- problem constants ----------------
#define NB   128
#define DC   256
#define SP   256
#define NROW 32768
#define KCB  1024
#define BETA_F 0.1f
#define EPSQ 1e-10f

typedef __attribute__((ext_vector_type(8))) short s16x8;
typedef __attribute__((ext_vector_type(4))) short s16x4;
typedef __attribute__((ext_vector_type(4))) float f32x4;

__device__ __forceinline__ short f2bf(float f) {
  unsigned u = __builtin_bit_cast(unsigned, f);
  unsigned r = (u + 0x7FFFu + ((u >> 16) & 1u)) >> 16;
  return (short)r;
}
__device__ __forceinline__ float bf2f(short s) {
  unsigned u = ((unsigned)(unsigned short)s) << 16;
  return __builtin_bit_cast(float, u);
}
__device__ __forceinline__ unsigned pack2(float a, float b) {
  return (unsigned)(unsigned short)f2bf(a) | ((unsigned)(unsigned short)f2bf(b) << 16);
}

// ========================= init: zero the zero-source buffer ===============
__global__ void init0_kernel(short* __restrict__ zerob)
{
  if (threadIdx.x < 8) zerob[threadIdx.x] = 0;
}

// ========================= weight transposes (fp32 -> bf16) =================
__global__ void w3t_kernel(const float* __restrict__ w, short* __restrict__ o)
{
  const int i = blockIdx.x * 256 + threadIdx.x;  // 589824
  const int ci = i & 255, co = (i >> 8) & 255, j = i >> 16;
  o[i] = f2bf(w[((size_t)(co * 256 + ci)) * 9 + j]);
}
__global__ void w2t_kernel(const float* __restrict__ w, short* __restrict__ o)
{
  const int i = blockIdx.x * 256 + threadIdx.x;  // 524288
  const int ci = i & 127, co = (i >> 7) & 255, j = i >> 15;
  o[i] = f2bf(w[((size_t)(co * 128 + ci)) * 16 + j]);
}
__global__ void wtt2_kernel(const float* __restrict__ w, short* __restrict__ o)
{
  const int i = blockIdx.x * 256 + threadIdx.x;  // 524288
  const int ci = i & 255, co = (i >> 8) & 127, j = (i >> 15) & 3, p = i >> 17;
  const int po = p >> 1, pq = p & 1, a = j >> 1, b2 = j & 1;
  const int kh = (1 - po) + 2 * a, kw = (1 - pq) + 2 * b2;
  o[i] = f2bf(w[((size_t)(ci * 128 + co)) * 16 + kh * 4 + kw]);
}
__global__ void cbbf_kernel(const float* __restrict__ cb, short* __restrict__ o)
{
  const int i = blockIdx.x * 256 + threadIdx.x;  // 262144
  o[i] = f2bf(cb[i]);
}
__global__ void cbt_kernel(const float* __restrict__ cb, short* __restrict__ o)
{
  const int i = blockIdx.x * 256 + threadIdx.x;  // 262144
  const int d = i >> 10, k = i & 1023;
  o[i] = f2bf(cb[(size_t)k * 256 + d]);
}

// ========================= conv1: 3->128, 4x4 s2, 64->32, out NHWC bf16 =====
__global__ __launch_bounds__(256) void conv1_kernel(
    const float* __restrict__ x, const float* __restrict__ w,
    const float* __restrict__ bias, short* __restrict__ out)
{
  __shared__ float li[3][34][34];
  const int tid = threadIdx.x;
  const int tile = blockIdx.x;          // 0..3 quadrant of 32x32 output
  const int b = blockIdx.y;
  const int qy = tile >> 1, qx = tile & 1;
  const int ihlo = qy * 32 - 1, iwlo = qx * 32 - 1;
  for (int ci = 0; ci < 3; ++ci)
    for (int s = tid; s < 1156; s += 256) {
      const int r = s / 34, c = s - r * 34;
      const int ih = ihlo + r, iw = iwlo + c;
      float v = 0.f;
      if ((unsigned)ih < 64u && (unsigned)iw < 64u)
        v = x[((size_t)(b * 3 + ci) * 64 + ih) * 64 + iw];
      li[ci][r][c] = v;
    }
  __syncthreads();

  const int wv = tid >> 6, l = tid & 63;
  const int co0 = 2 * l, co1 = 2 * l + 1;
  float w0[48], w1[48];
#pragma unroll
  for (int j = 0; j < 48; ++j) {
    w0[j] = w[(size_t)co0 * 48 + j];
    w1[j] = w[(size_t)co1 * 48 + j];
  }
  const float b0 = bias[co0], b1 = bias[co1];

  for (int pass = 0; pass < 64; ++pass) {
    const int pix = pass * 4 + wv;            // 0..255
    const int py = pix >> 4, px = pix & 15;
    float s0 = b0, s1 = b1;
#pragma unroll
    for (int ci = 0; ci < 3; ++ci)
#pragma unroll
      for (int kh = 0; kh < 4; ++kh)
#pragma unroll
        for (int kw = 0; kw < 4; ++kw) {
          const int j = ci * 16 + kh * 4 + kw;
          const float v = li[ci][2 * py + kh][2 * px + kw];  // wave-broadcast
          s0 = fmaf(v, w0[j], s0);
          s1 = fmaf(v, w1[j], s1);
        }
    s0 = fmaxf(s0, 0.f);
    s1 = fmaxf(s1, 0.f);
    const int oh = qy * 16 + py, ow = qx * 16 + px;
    ((unsigned*)(out + ((size_t)b * 1024 + oh * 32 + ow) * 128))[l] = pack2(s0, s1);
  }
}

// ========================= MFMA implicit GEMM ===============================
// MODE 0: conv3x3 (A [32768][256], N=256, K=9*256); blockIdx.y = N-split
// MODE 2: conv4x4 s2 (A [131072][128], N=256, K=16*128); blockIdx.y = N-split
// MODE 3: convT2 per-parity (N=128, K=4*256); blockIdx.y = parity, scatter out
// MODE 4: distance (out DV bf16 = cn[n] - 2*acc); blockIdx.y = N-split
template<int MODE, int NSUB, int KIT, int AK, int KPN>
__global__ __launch_bounds__(256) void igemm_kernel(
    const short* __restrict__ Abuf, const short* __restrict__ Bw,
    const float* __restrict__ bias, const short* __restrict__ res,
    short* __restrict__ outb, float* __restrict__ outf32,
    const short* __restrict__ zerob)
{
  __shared__ __align__(16) short Alds[2][2048];    // 2 x [64 rows][32 ci] bf16
  const int tid = threadIdx.x;
  const int wv = tid >> 6, l = tid & 63;
  const int lcol = l & 15, lk = l >> 4;
  const int m0 = blockIdx.x * 64;

  const int srow = tid >> 2;
  const int sm = m0 + srow;
  const int cchunk = (tid & 3) ^ ((srow >> 1) & 3);   // bank-bijective swizzle
  const int s_img = sm & ~255;
  const int s_h = (sm >> 4) & 15, s_w = sm & 15;
  const int s_b1024 = (sm >> 8) * 1024;
  short* stage_dst = &Alds[0][wv * 512];

  // column base / parity from blockIdx.y
  int ncol0 = 0, po = 0, pq = 0;
  const short* Bp = Bw;
  if constexpr (MODE == 3) {
    po = blockIdx.y >> 1; pq = blockIdx.y & 1;
    Bp += (size_t)blockIdx.y * 131072;                // per-parity B slab
  } else {
    ncol0 = blockIdx.y * (NSUB * 64);
    Bp += (size_t)ncol0 * KPN;
  }

  f32x4 acc[4][NSUB];
#pragma unroll
  for (int i = 0; i < 4; ++i)
#pragma unroll
    for (int j = 0; j < NSUB; ++j) acc[i][j] = (f32x4){0.f, 0.f, 0.f, 0.f};

  int boff[NSUB];
#pragma unroll
  for (int ns = 0; ns < NSUB; ++ns)
    boff[ns] = (wv * (NSUB * 16) + ns * 16 + lcol) * KPN + lk * 8;

  const int aoff_base = lcol * 32 + ((lk ^ ((lcol >> 1) & 3)) * 8);

  auto STAGE = [&](int it, int bufc) {
    int kk, ih, iw, srcrow; bool v;
    if constexpr (MODE == 0) {
      const int jj = it >> 3; kk = it & 7;
      const int q3 = jj / 3;
      ih = s_h + q3 - 1; iw = s_w + (jj - q3 * 3) - 1;
      v = ((unsigned)ih < 16u) & ((unsigned)iw < 16u);
      srcrow = s_img + ih * 16 + iw;
    } else if constexpr (MODE == 2) {
      const int jj = it >> 2; kk = it & 3;
      ih = 2 * s_h + (jj >> 2) - 1; iw = 2 * s_w + (jj & 3) - 1;
      v = ((unsigned)ih < 32u) & ((unsigned)iw < 32u);
      srcrow = s_b1024 + ih * 32 + iw;
    } else if constexpr (MODE == 4) {
      kk = it; v = true; srcrow = sm;
    } else {
      const int jj = it >> 3; kk = it & 7;
      ih = s_h + po - (jj >> 1); iw = s_w + pq - (jj & 1);
      v = ((unsigned)ih < 16u) & ((unsigned)iw < 16u);
      srcrow = s_img + ih * 16 + iw;
    }
    const short* src = v ? (Abuf + (size_t)srcrow * AK + kk * 32 + cchunk * 8) : zerob;
    __builtin_amdgcn_global_load_lds(
        (const __attribute__((address_space(1))) void*)src,
        (__attribute__((address_space(3))) void*)(stage_dst + bufc * 2048),
        16, 0, 0);
  };

  auto COMPUTE = [&](int it, int bufc) {
    int uoff;
    if constexpr (MODE == 0)      uoff = (it >> 3) * 65536 + (it & 7) * 32;
    else if constexpr (MODE == 2) uoff = (it >> 2) * 32768 + (it & 3) * 32;
    else if constexpr (MODE == 4) uoff = it * 32;
    else                          uoff = (it >> 3) * 32768 + (it & 7) * 32;
    s16x8 a[4], b[NSUB];
#pragma unroll
    for (int ms = 0; ms < 4; ++ms)
      a[ms] = *(const s16x8*)&Alds[bufc][aoff_base + ms * 512];
#pragma unroll
    for (int ns = 0; ns < NSUB; ++ns)
      b[ns] = *(const s16x8*)(Bp + uoff + boff[ns]);
#pragma unroll
    for (int ms = 0; ms < 4; ++ms)
#pragma unroll
      for (int ns = 0; ns < NSUB; ++ns)
        acc[ms][ns] = __builtin_amdgcn_mfma_f32_16x16x32_bf16(a[ms], b[ns], acc[ms][ns], 0, 0, 0);
  };

  STAGE(0, 0);
  for (int it = 0; it < KIT; it += 2) {
    __syncthreads();
    if (it + 1 < KIT) STAGE(it + 1, 1);
    COMPUTE(it, 0);
    __syncthreads();
    if (it + 2 < KIT) STAGE(it + 2, 0);
    COMPUTE(it + 1, 1);
  }

  const int r4 = lk * 4;
#pragma unroll
  for (int ms = 0; ms < 4; ++ms) {
#pragma unroll
    for (int ns = 0; ns < NSUB; ++ns) {
      const int n_l = wv * (NSUB * 16) + ns * 16 + lcol;
      const int n_g = ncol0 + n_l;
#pragma unroll
      for (int e = 0; e < 4; ++e) {
        const int m = m0 + ms * 16 + r4 + e;
        if constexpr (MODE == 4) {
          const float val = bias[n_g] - 2.f * acc[ms][ns][e];
          outb[(size_t)m * 1024 + n_g] = f2bf(val);
        } else if constexpr (MODE == 3) {
          float val = fmaxf(acc[ms][ns][e] + bias[n_l], 0.f);
          const int orow = (m & ~255) * 4 + (2 * ((m >> 4) & 15) + po) * 32 + (2 * (m & 15) + pq);
          outb[(size_t)orow * 128 + n_l] = f2bf(val);
        } else {
          float val = acc[ms][ns][e] + bias[n_g];
          if (res) val += bf2f(res[(size_t)m * 256 + n_g]);
          val = fmaxf(val, 0.f);
          outb[(size_t)m * 256 + n_g] = f2bf(val);
          if (outf32) outf32[(size_t)m * 256 + n_g] = val;
        }
      }
    }
  }
}

// ========================= VQ block =========================================
__global__ __launch_bounds__(256) void rownorm_kernel(
    const float* __restrict__ a, float* __restrict__ nrm, int rows)
{
  const int wv = threadIdx.x >> 6, lane = threadIdx.x & 63;
  const int r = blockIdx.x * 4 + wv;
  if (r >= rows) return;
  const float* p = a + (size_t)r * DC;
  float s = 0.f;
#pragma unroll
  for (int i = 0; i < 4; ++i) { float v = p[lane + 64 * i]; s = fmaf(v, v, s); }
#pragma unroll
  for (int o = 32; o > 0; o >>= 1) s += __shfl_xor(s, o);
  if (lane == 0) nrm[r] = s;
}

__global__ void initq_kernel(const float* __restrict__ pi, float* __restrict__ logq,
                             float* __restrict__ Sacc)
{
  const int k = blockIdx.x * 256 + threadIdx.x;
  logq[k] = logf(fmaxf(pi[k], EPSQ));
  if (k == 0) *Sacc = 0.f;
}

// one BA iteration over bf16 DV; per-block Q-partials to PART (no atomics).
__global__ __launch_bounds__(256) void ba2_kernel(
    unsigned* __restrict__ DV, const float* __restrict__ logq,
    float* __restrict__ part, int* __restrict__ idxout, int storeP)
{
  __shared__ float qp[4][1024];
  const int tid = threadIdx.x;
  const int wv = tid >> 6, lane = tid & 63;
  for (int i = tid; i < 4096; i += 256) ((float*)qp)[i] = 0.f;
  __syncthreads();

  float2 lq[8];
#pragma unroll
  for (int it = 0; it < 8; ++it) lq[it] = *(const float2*)&logq[it * 128 + lane * 2];

  const int n0 = blockIdx.x * 16;
  for (int rr = 0; rr < 4; ++rr) {
    const int n = n0 + wv * 4 + rr;
    unsigned* rowp = DV + (size_t)n * 512;
    float l0[8], l1[8];
    float mx = -1e30f;
#pragma unroll
    for (int it = 0; it < 8; ++it) {
      const unsigned w = rowp[it * 64 + lane];
      l0[it] = lq[it].x - BETA_F * bf2f((short)(w & 0xFFFFu));
      l1[it] = lq[it].y - BETA_F * bf2f((short)(w >> 16));
      mx = fmaxf(mx, fmaxf(l0[it], l1[it]));
    }
#pragma unroll
    for (int o = 32; o > 0; o >>= 1) mx = fmaxf(mx, __shfl_xor(mx, o));
    float e0[8], e1[8];
    float s = 0.f;
#pragma unroll
    for (int it = 0; it < 8; ++it) {
      e0[it] = __expf(l0[it] - mx);
      e1[it] = __expf(l1[it] - mx);
      s += e0[it] + e1[it];
    }
#pragma unroll
    for (int o = 32; o > 0; o >>= 1) s += __shfl_xor(s, o);
    const float inv = 1.f / s;
#pragma unroll
    for (int it = 0; it < 8; ++it) {
      qp[wv][it * 128 + lane * 2]     += e0[it] * inv;
      qp[wv][it * 128 + lane * 2 + 1] += e1[it] * inv;
    }

    if (storeP) {
#pragma unroll
      for (int it = 0; it < 8; ++it)
        rowp[it * 64 + lane] = pack2(e0[it] * inv, e1[it] * inv);
      float bv = l0[0]; int bi = lane * 2;
      if (l1[0] > bv) { bv = l1[0]; bi = lane * 2 + 1; }
#pragma unroll
      for (int it = 1; it < 8; ++it) {
        const int k = it * 128 + lane * 2;
        if (l0[it] > bv) { bv = l0[it]; bi = k; }
        if (l1[it] > bv) { bv = l1[it]; bi = k + 1; }
      }
#pragma unroll
      for (int o = 32; o > 0; o >>= 1) {
        const float ov = __shfl_xor(bv, o);
        const int oi = __shfl_xor(bi, o);
        if (ov > bv || (ov == bv && oi < bi)) { bv = ov; bi = oi; }
      }
      if (lane == 0) idxout[n] = bi;
    }
  }
  __syncthreads();
  for (int k = tid; k < 1024; k += 256) {
    part[(size_t)blockIdx.x * 1024 + k] = qp[0][k] + qp[1][k] + qp[2][k] + qp[3][k];
  }
}

// reduce stage 1: 64 blocks; block b sums PART rows [32b,32b+32) -> PART2[b][1024]
__global__ __launch_bounds__(256) void qred1_kernel(
    const float* __restrict__ part, float* __restrict__ part2)
{
  const int b = blockIdx.x;
  const int tid = threadIdx.x;
  const float* p = part + (size_t)b * 32 * 1024;
#pragma unroll
  for (int j = 0; j < 4; ++j) {
    const int k = tid + j * 256;
    float s = 0.f;
#pragma unroll
    for (int r = 0; r < 32; ++r) s += p[(size_t)r * 1024 + k];
    part2[(size_t)b * 1024 + k] = s;
  }
}

// reduce stage 2: 4 blocks x 256; sum 64 entries/column -> qsum, logq
__global__ __launch_bounds__(256) void qred2_kernel(
    const float* __restrict__ part2, float* __restrict__ qsum, float* __restrict__ logq)
{
  const int k = blockIdx.x * 256 + threadIdx.x;
  float s = 0.f;
#pragma unroll
  for (int r = 0; r < 64; ++r) s += part2[(size_t)r * 1024 + k];
  qsum[k] = s;
  logq[k] = logf(fmaxf(s * (1.f / 32768.f), EPSQ));
}

__global__ __launch_bounds__(1024) void ent_kernel(
    const float* __restrict__ qsum, float* __restrict__ out_ent)
{
  const int k = threadIdx.x;
  const float q = fmaxf(qsum[k] * (1.f / 32768.f), EPSQ);
  float v = q * logf(q);
#pragma unroll
  for (int o = 32; o > 0; o >>= 1) v += __shfl_xor(v, o);
  __shared__ float red[16];
  const int wv = k >> 6, lane = k & 63;
  if (lane == 0) red[wv] = v;
  __syncthreads();
  if (k == 0) {
    float s = 0.f;
    for (int i = 0; i < 16; ++i) s += red[i];
    *out_ent = 0.01f * s;
  }
}

// zq_soft = P @ cbT via MFMA; fused sum((zq_soft - zf)^2) into Sacc.
// grid (512, 2): blockIdx.y = 128-col half.
__global__ __launch_bounds__(256) void pvq_kernel(
    const short* __restrict__ P, const short* __restrict__ CBT,
    const float* __restrict__ zf32, float* __restrict__ Sacc)
{
  __shared__ __align__(16) short Alds[2][2048];
  __shared__ float red[4];
  const int tid = threadIdx.x;
  const int wv = tid >> 6, l = tid & 63;
  const int lcol = l & 15, lk = l >> 4;
  const int m0 = blockIdx.x * 64;
  const int ncol0 = blockIdx.y * 128;

  const int srow = tid >> 2;
  const int cchunk = (tid & 3) ^ ((srow >> 1) & 3);
  short* stage_dst = &Alds[0][wv * 512];

  f32x4 acc[4][2];
#pragma unroll
  for (int i = 0; i < 4; ++i)
#pragma unroll
    for (int j = 0; j < 2; ++j) acc[i][j] = (f32x4){0.f, 0.f, 0.f, 0.f};

  int boff[2];
#pragma unroll
  for (int ns = 0; ns < 2; ++ns)
    boff[ns] = (ncol0 + wv * 32 + ns * 16 + lcol) * 1024 + lk * 8;

  const int aoff_base = lcol * 32 + ((lk ^ ((lcol >> 1) & 3)) * 8);

  auto STAGE = [&](int it, int bufc) {
    const short* src = P + (size_t)(m0 + srow) * 1024 + it * 32 + cchunk * 8;
    __builtin_amdgcn_global_load_lds(
        (const __attribute__((address_space(1))) void*)src,
        (__attribute__((address_space(3))) void*)(stage_dst + bufc * 2048),
        16, 0, 0);
  };
  auto COMPUTE = [&](int it, int bufc) {
    s16x8 a[4], b[2];
#pragma unroll
    for (int ms = 0; ms < 4; ++ms)
      a[ms] = *(const s16x8*)&Alds[bufc][aoff_base + ms * 512];
#pragma unroll
    for (int ns = 0; ns < 2; ++ns)
      b[ns] = *(const s16x8*)(CBT + it * 32 + boff[ns]);
#pragma unroll
    for (int ms = 0; ms < 4; ++ms)
#pragma unroll
      for (int ns = 0; ns < 2; ++ns)
        acc[ms][ns] = __builtin_amdgcn_mfma_f32_16x16x32_bf16(a[ms], b[ns], acc[ms][ns], 0, 0, 0);
  };

  STAGE(0, 0);
  for (int it = 0; it < 32; it += 2) {
    __syncthreads();
    if (it + 1 < 32) STAGE(it + 1, 1);
    COMPUTE(it, 0);
    __syncthreads();
    if (it + 2 < 32) STAGE(it + 2, 0);
    COMPUTE(it + 1, 1);
  }

  float ls = 0.f;
  const int r4 = lk * 4;
#pragma unroll
  for (int ms = 0; ms < 4; ++ms) {
#pragma unroll
    for (int ns = 0; ns < 2; ++ns) {
      const int n_g = ncol0 + wv * 32 + ns * 16 + lcol;
#pragma unroll
      for (int e = 0; e < 4; ++e) {
        const int m = m0 + ms * 16 + r4 + e;
        const float d = acc[ms][ns][e] - zf32[(size_t)m * 256 + n_g];
        ls = fmaf(d, d, ls);
      }
    }
  }
#pragma unroll
  for (int o = 32; o > 0; o >>= 1) ls += __shfl_xor(ls, o);
  if (l == 0) red[wv] = ls;
  __syncthreads();
  if (tid == 0) atomicAdd(Sacc, red[0] + red[1] + red[2] + red[3]);
}

__global__ void scalars_kernel(const float* __restrict__ S, float* __restrict__ out2)
{
  const float s = *S;
  out2[0] = 0.25f * s / 8388608.f;
  out2[1] = s / 8388608.f;
}

__global__ void gather16_kernel(const int* __restrict__ idx, const short* __restrict__ cbb,
                                short* __restrict__ out)
{
  const int t = blockIdx.x * 256 + threadIdx.x;
  const int m = t >> 6, d4 = (t & 63) * 4;
  *(s16x4*)(out + (size_t)m * 256 + d4) = *(const s16x4*)(cbb + (size_t)idx[m] * 256 + d4);
}

// ========================= convT3: 128->3, 32->64, direct ==================
__global__ __launch_bounds__(256) void convt3_kernel(
    const short* __restrict__ in, const float* __restrict__ w,
    const float* __restrict__ bias, float* __restrict__ out)
{
  __shared__ __align__(16) short li[100 * 136];
  __shared__ float lw[6144];
  const int tid = threadIdx.x;
  const int tile = blockIdx.x;          // 0..15
  const int b = blockIdx.y;
  const int ty0 = (tile >> 2) * 16, tx0 = (tile & 3) * 16;
  const int iy0 = (tile >> 2) * 8 - 1, ix0 = (tile & 3) * 8 - 1;
  for (int s = tid; s < 1600; s += 256) {
    const int pix = s >> 4, ch = s & 15;
    const int r = pix / 10, c = pix - r * 10;
    const int ih = iy0 + r, iw = ix0 + c;
    s16x8 v = {0, 0, 0, 0, 0, 0, 0, 0};
    if ((unsigned)ih < 32u && (unsigned)iw < 32u)
      v = *(const s16x8*)(in + ((size_t)b * 1024 + ih * 32 + iw) * 128 + ch * 8);
    *(s16x8*)&li[pix * 136 + ch * 8] = v;
  }
  for (int s = tid; s < 6144; s += 256) lw[s] = w[s];
  __syncthreads();
  const int ty = tid >> 4, tx = tid & 15;
  const int oh2 = ty0 + ty, ow2 = tx0 + tx;
  const int kh0 = (oh2 + 1) & 1, kw0 = (ow2 + 1) & 1;
  const int ih0 = (oh2 + 1 - kh0) >> 1, iw0 = (ow2 + 1 - kw0) >> 1;
  const int rl0 = ih0 - iy0, cl0 = iw0 - ix0;
  const int p00 = rl0 * 10 + cl0, p01 = p00 - 1, p10 = p00 - 10, p11 = p00 - 11;
  const int wi00 = kh0 * 4 + kw0, wi01 = wi00 + 2, wi10 = wi00 + 8, wi11 = wi00 + 10;
  float acc0 = 0.f, acc1 = 0.f, acc2 = 0.f;
  for (int ch = 0; ch < 16; ++ch) {
    const s16x8 v00 = *(const s16x8*)&li[p00 * 136 + ch * 8];
    const s16x8 v01 = *(const s16x8*)&li[p01 * 136 + ch * 8];
    const s16x8 v10 = *(const s16x8*)&li[p10 * 136 + ch * 8];
    const s16x8 v11 = *(const s16x8*)&li[p11 * 136 + ch * 8];
#pragma unroll
    for (int e = 0; e < 8; ++e) {
      const int ci = ch * 8 + e;
      const float* wr = &lw[ci * 48];
      const float f00 = bf2f(v00[e]), f01 = bf2f(v01[e]);
      const float f10 = bf2f(v10[e]), f11 = bf2f(v11[e]);
      acc0 = fmaf(wr[wi00], f00, fmaf(wr[wi01], f01, fmaf(wr[wi10], f10, fmaf(wr[wi11], f11, acc0))));
      acc1 = fmaf(wr[16 + wi00], f00, fmaf(wr[16 + wi01], f01, fmaf(wr[16 + wi10], f10, fmaf(wr[16 + wi11], f11, acc1))));
      acc2 = fmaf(wr[32 + wi00], f00, fmaf(wr[32 + wi01], f01, fmaf(wr[32 + wi10], f10, fmaf(wr[32 + wi11], f11, acc2))));
    }
  }
  const size_t ob = ((size_t)(b * 3) * 64 + oh2) * 64 + ow2;
  out[ob] = acc0 + bias[0];
  out[ob + 4096] = acc1 + bias[1];
  out[ob + 8192] = acc2 + bias[2];
}

// =====================================================================
extern "C" void kernel_launch(void* const* d_in, const int* in_sizes, int n_in,
                              void* d_out, int out_size, void* d_ws, size_t ws_size,
                              hipStream_t stream)
{
  const float* x     = (const float*)d_in[0];
  const float* ew1   = (const float*)d_in[1];
  const float* eb1   = (const float*)d_in[2];
  const float* ew2   = (const float*)d_in[3];
  const float* eb2   = (const float*)d_in[4];
  const float* ew3   = (const float*)d_in[5];
  const float* eb3   = (const float*)d_in[6];
  const float* er1aw = (const float*)d_in[7];
  const float* er1ab = (const float*)d_in[8];
  const float* er1bw = (const float*)d_in[9];
  const float* er1bb = (const float*)d_in[10];
  const float* er2aw = (const float*)d_in[11];
  const float* er2ab = (const float*)d_in[12];
  const float* er2bw = (const float*)d_in[13];
  const float* er2bb = (const float*)d_in[14];
  const float* cb    = (const float*)d_in[15];
  const float* pi    = (const float*)d_in[16];
  const float* dr1aw = (const float*)d_in[17];
  const float* dr1ab = (const float*)d_in[18];
  const float* dr1bw = (const float*)d_in[19];
  const float* dr1bb = (const float*)d_in[20];
  const float* dr2aw = (const float*)d_in[21];
  const float* dr2ab = (const float*)d_in[22];
  const float* dr2bw = (const float*)d_in[23];
  const float* dr2bb = (const float*)d_in[24];
  const float* dw1   = (const float*)d_in[25];
  const float* db1   = (const float*)d_in[26];
  const float* dwt2  = (const float*)d_in[27];
  const float* dbt2  = (const float*)d_in[28];
  const float* dwt3  = (const float*)d_in[29];
  const float* dbt3  = (const float*)d_in[30];

  float* outf = (float*)d_out;

  // workspace layout (bytes), ~169 MB of 256 MiB
  char* W = (char*)d_ws;
  short* BIGA  = (short*)W;                    // 33.5MB: conv1-out -> ZF32 -> convt2-out
  float* ZF32  = (float*)W;
  short* DV    = (short*)(W + 33554432);       // 67MB bf16 [32768][1024]: dv -> P
  short* X0    = (short*)(W + 100663296);      // 16.7MB each
  short* X1    = (short*)(W + 117440512);
  short* X2    = (short*)(W + 134217728);
  short* WT3   = (short*)(W + 150994944);      // 1,179,648 B
  short* WT2   = (short*)(W + 152174592);      // 1,048,576 B
  short* WTT2  = (short*)(W + 153223168);      // 1,048,576 B
  short* CBB   = (short*)(W + 154271744);      //   524,288 B
  short* CBT   = (short*)(W + 154796032);      //   524,288 B
  float* cn    = (float*)(W + 155320320);      //     4,096 B
  float* qsum  = (float*)(W + 155324416);
  float* logq  = (float*)(W + 155328512);
  int*   idx   = (int*)(W + 155332608);        //   131,072 B
  float* Sacc  = (float*)(W + 155463680);
  short* zerob = (short*)(W + 155463696);
  float* PART  = (float*)(W + 160000000);      // 8,388,608 B [2048][1024]
  float* PART2 = (float*)(W + 168388608);      //   262,144 B [64][1024]

  const dim3 blk(256);
  #define IG3(A_, W_, B_, R_, O_, F_) \
    igemm_kernel<0,2,72,256,256><<<dim3(512, 2), blk, 0, stream>>>(A_, W_, B_, R_, O_, F_, zerob)

  init0_kernel<<<dim3(1), dim3(64), 0, stream>>>(zerob);

  // -------- encoder --------
  conv1_kernel<<<dim3(4, NB), blk, 0, stream>>>(x, ew1, eb1, BIGA);
  w2t_kernel<<<dim3(2048), blk, 0, stream>>>(ew2, WT2);
  igemm_kernel<2,2,64,128,128><<<dim3(512, 2), blk, 0, stream>>>(
      BIGA, WT2, eb2, nullptr, X0, nullptr, zerob);
  w3t_kernel<<<dim3(2304), blk, 0, stream>>>(ew3, WT3);
  IG3(X0, WT3, eb3, nullptr, X1, nullptr);                 // h3
  w3t_kernel<<<dim3(2304), blk, 0, stream>>>(er1aw, WT3);
  IG3(X1, WT3, er1ab, nullptr, X2, nullptr);
  w3t_kernel<<<dim3(2304), blk, 0, stream>>>(er1bw, WT3);
  IG3(X2, WT3, er1bb, X1, X0, nullptr);                    // h4
  w3t_kernel<<<dim3(2304), blk, 0, stream>>>(er2aw, WT3);
  IG3(X0, WT3, er2ab, nullptr, X1, nullptr);
  w3t_kernel<<<dim3(2304), blk, 0, stream>>>(er2bw, WT3);
  IG3(X1, WT3, er2bb, X0, X2, ZF32);                       // z (bf16 + fp32 dup)

  // -------- VQ / Blahut-Arimoto --------
  rownorm_kernel<<<dim3(KCB / 4), blk, 0, stream>>>(cb, cn, KCB);
  cbbf_kernel<<<dim3(1024), blk, 0, stream>>>(cb, CBB);
  cbt_kernel<<<dim3(1024), blk, 0, stream>>>(cb, CBT);
  initq_kernel<<<dim3(4), blk, 0, stream>>>(pi, logq, Sacc);
  igemm_kernel<4,4,8,256,256><<<dim3(512, 4), blk, 0, stream>>>(
      X2, CBB, cn, nullptr, DV, nullptr, zerob);
  for (int i = 0; i < 5; ++i) {
    ba2_kernel<<<dim3(NROW / 16), blk, 0, stream>>>(
        (unsigned*)DV, logq, PART, idx, (i == 4) ? 1 : 0);
    qred1_kernel<<<dim3(64), blk, 0, stream>>>(PART, PART2);
    qred2_kernel<<<dim3(4), blk, 0, stream>>>(PART2, qsum, logq);
  }
  ent_kernel<<<dim3(1), dim3(1024), 0, stream>>>(qsum, outf + 1572866);
  pvq_kernel<<<dim3(512, 2), blk, 0, stream>>>(DV, CBT, ZF32, Sacc);
  scalars_kernel<<<dim3(1), dim3(1), 0, stream>>>(Sacc, outf + 1572864);
  gather16_kernel<<<dim3(8192), blk, 0, stream>>>(idx, CBB, X0);  // zq_hard NHWC bf16

  // -------- decoder --------
  w3t_kernel<<<dim3(2304), blk, 0, stream>>>(dr1aw, WT3);
  IG3(X0, WT3, dr1ab, nullptr, X1, nullptr);
  w3t_kernel<<<dim3(2304), blk, 0, stream>>>(dr1bw, WT3);
  IG3(X1, WT3, dr1bb, X0, X2, nullptr);                    // y1
  w3t_kernel<<<dim3(2304), blk, 0, stream>>>(dr2aw, WT3);
  IG3(X2, WT3, dr2ab, nullptr, X0, nullptr);
  w3t_kernel<<<dim3(2304), blk, 0, stream>>>(dr2bw, WT3);
  IG3(X0, WT3, dr2bb, X2, X1, nullptr);                    // y2
  w3t_kernel<<<dim3(2304), blk, 0, stream>>>(dw1, WT3);
  IG3(X1, WT3, db1, nullptr, X0, nullptr);                 // y3
  wtt2_kernel<<<dim3(2048), blk, 0, stream>>>(dwt2, WTT2);
  igemm_kernel<3,2,32,256,256><<<dim3(512, 4), blk, 0, stream>>>(
      X0, WTT2, dbt2, nullptr, BIGA, nullptr, zerob);
  convt3_kernel<<<dim3(16, NB), blk, 0, stream>>>(BIGA, dwt3, dbt3, outf);
  #undef IG3
}

// Round 9
// 1030.995 us; speedup vs baseline: 2.1606x; 1.4287x over previous
//
#include <hip/hip_runtime.h>
#include <math.h>

// ---------------- problem constants ----------------
#define NB   128
#define DC   256
#define SP   256
#define NROW 32768
#define KCB  1024
#define BETA_F 0.1f
#define EPSQ 1e-10f

typedef __attribute__((ext_vector_type(8))) short s16x8;
typedef __attribute__((ext_vector_type(4))) short s16x4;
typedef __attribute__((ext_vector_type(4))) float f32x4;

__device__ __forceinline__ short f2bf(float f) {
  unsigned u = __builtin_bit_cast(unsigned, f);
  unsigned r = (u + 0x7FFFu + ((u >> 16) & 1u)) >> 16;
  return (short)r;
}
__device__ __forceinline__ float bf2f(short s) {
  unsigned u = ((unsigned)(unsigned short)s) << 16;
  return __builtin_bit_cast(float, u);
}
__device__ __forceinline__ unsigned pack2(float a, float b) {
  return (unsigned)(unsigned short)f2bf(a) | ((unsigned)(unsigned short)f2bf(b) << 16);
}

// ========================= init: zero the zero-source buffer ===============
__global__ void init0_kernel(short* __restrict__ zerob)
{
  if (threadIdx.x < 8) zerob[threadIdx.x] = 0;
}

// ========================= weight transposes (fp32 -> bf16) =================
__global__ void w3t_kernel(const float* __restrict__ w, short* __restrict__ o)
{
  const int i = blockIdx.x * 256 + threadIdx.x;  // 589824
  const int ci = i & 255, co = (i >> 8) & 255, j = i >> 16;
  o[i] = f2bf(w[((size_t)(co * 256 + ci)) * 9 + j]);
}
__global__ void w2t_kernel(const float* __restrict__ w, short* __restrict__ o)
{
  const int i = blockIdx.x * 256 + threadIdx.x;  // 524288
  const int ci = i & 127, co = (i >> 7) & 255, j = i >> 15;
  o[i] = f2bf(w[((size_t)(co * 128 + ci)) * 16 + j]);
}
__global__ void wtt2_kernel(const float* __restrict__ w, short* __restrict__ o)
{
  const int i = blockIdx.x * 256 + threadIdx.x;  // 524288
  const int ci = i & 255, co = (i >> 8) & 127, j = (i >> 15) & 3, p = i >> 17;
  const int po = p >> 1, pq = p & 1, a = j >> 1, b2 = j & 1;
  const int kh = (1 - po) + 2 * a, kw = (1 - pq) + 2 * b2;
  o[i] = f2bf(w[((size_t)(ci * 128 + co)) * 16 + kh * 4 + kw]);
}
__global__ void cbbf_kernel(const float* __restrict__ cb, short* __restrict__ o)
{
  const int i = blockIdx.x * 256 + threadIdx.x;  // 262144
  o[i] = f2bf(cb[i]);
}
__global__ void cbt_kernel(const float* __restrict__ cb, short* __restrict__ o)
{
  const int i = blockIdx.x * 256 + threadIdx.x;  // 262144
  const int d = i >> 10, k = i & 1023;
  o[i] = f2bf(cb[(size_t)k * 256 + d]);
}

// ========================= conv1: 3->128, 4x4 s2, 64->32, out NHWC bf16 =====
__global__ __launch_bounds__(256) void conv1_kernel(
    const float* __restrict__ x, const float* __restrict__ w,
    const float* __restrict__ bias, short* __restrict__ out)
{
  __shared__ float li[3][34][34];
  const int tid = threadIdx.x;
  const int tile = blockIdx.x;          // 0..3 quadrant of 32x32 output
  const int b = blockIdx.y;
  const int qy = tile >> 1, qx = tile & 1;
  const int ihlo = qy * 32 - 1, iwlo = qx * 32 - 1;
  for (int ci = 0; ci < 3; ++ci)
    for (int s = tid; s < 1156; s += 256) {
      const int r = s / 34, c = s - r * 34;
      const int ih = ihlo + r, iw = iwlo + c;
      float v = 0.f;
      if ((unsigned)ih < 64u && (unsigned)iw < 64u)
        v = x[((size_t)(b * 3 + ci) * 64 + ih) * 64 + iw];
      li[ci][r][c] = v;
    }
  __syncthreads();

  const int wv = tid >> 6, l = tid & 63;
  const int co0 = 2 * l, co1 = 2 * l + 1;
  float w0[48], w1[48];
#pragma unroll
  for (int j = 0; j < 48; ++j) {
    w0[j] = w[(size_t)co0 * 48 + j];
    w1[j] = w[(size_t)co1 * 48 + j];
  }
  const float b0 = bias[co0], b1 = bias[co1];

  for (int pass = 0; pass < 64; ++pass) {
    const int pix = pass * 4 + wv;            // 0..255
    const int py = pix >> 4, px = pix & 15;
    float s0 = b0, s1 = b1;
#pragma unroll
    for (int ci = 0; ci < 3; ++ci)
#pragma unroll
      for (int kh = 0; kh < 4; ++kh)
#pragma unroll
        for (int kw = 0; kw < 4; ++kw) {
          const int j = ci * 16 + kh * 4 + kw;
          const float v = li[ci][2 * py + kh][2 * px + kw];  // wave-broadcast
          s0 = fmaf(v, w0[j], s0);
          s1 = fmaf(v, w1[j], s1);
        }
    s0 = fmaxf(s0, 0.f);
    s1 = fmaxf(s1, 0.f);
    const int oh = qy * 16 + py, ow = qx * 16 + px;
    ((unsigned*)(out + ((size_t)b * 1024 + oh * 32 + ow) * 128))[l] = pack2(s0, s1);
  }
}

// ========================= MFMA implicit GEMM (m97-style 128x128 tile) ======
// 4 waves as 2x2; wave tile 64x64 = acc[4][4]; A and B both staged in LDS.
// MODE 0: conv3x3 (A [32768][256], N=256, K=9*256); grid (256, 2)
// MODE 2: conv4x4 s2 (A NHWC 128ch on 32x32, out 32768x256); grid (256, 2)
// MODE 3: convT2 (N=128, K=4*256); grid (256, 4=parity), scatter out
// MODE 4: distance (DV = cn[n] - 2*acc); grid (256, 8)
// MODE 5: pvq (zq_soft = P@cbT, fused loss vs zf32); grid (256, 2)
// TS = B tap stride; KPN = B per-col K stride; AK = A row stride
template<int MODE, int KIT, int AK, int KPN, int TS>
__global__ __launch_bounds__(256) void igemm_kernel(
    const short* __restrict__ Abuf, const short* __restrict__ Bw,
    const float* __restrict__ bias, const short* __restrict__ res,
    short* __restrict__ outb, float* __restrict__ outf32,
    float* __restrict__ sacc, const short* __restrict__ zerob)
{
  __shared__ __align__(16) short Alds[2][8192];   // per buf: [A 4096 | B 4096]
  __shared__ float red[4];
  const int tid = threadIdx.x;
  const int wv = tid >> 6, l = tid & 63;
  const int wm = wv >> 1, wn = wv & 1;
  const int lcol = l & 15, lk = l >> 4;
  const int m0 = blockIdx.x * 128;

  int ncol0 = 0, po = 0, pq = 0;
  const short* Bp = Bw;
  if constexpr (MODE == 3) {
    po = blockIdx.y >> 1; pq = blockIdx.y & 1;
    Bp += (size_t)blockIdx.y * 131072;            // per-parity slab
  } else {
    ncol0 = blockIdx.y * 128;
    Bp += (size_t)ncol0 * KPN;
  }

  // staging lane geometry: issue q covers rows/cols (wv*2+q)*16 + (l>>2)
  const int cpos = l & 3;
  const int rl_[2] = { (wv * 2) * 16 + (l >> 2), (wv * 2 + 1) * 16 + (l >> 2) };
  const int cc_[2] = { cpos ^ ((rl_[0] >> 1) & 3), cpos ^ ((rl_[1] >> 1) & 3) };

  f32x4 acc[4][4];
#pragma unroll
  for (int i = 0; i < 4; ++i)
#pragma unroll
    for (int j = 0; j < 4; ++j) acc[i][j] = (f32x4){0.f, 0.f, 0.f, 0.f};

  const int aoff_base = lcol * 32 + ((lk ^ ((lcol >> 1) & 3)) * 8);

  auto STAGE = [&](int it, int bufc) {
    int jj, kk;
    if constexpr (MODE == 0 || MODE == 3) { jj = it >> 3; kk = it & 7; }
    else if constexpr (MODE == 2)         { jj = it >> 2; kk = it & 3; }
    else                                  { jj = 0; kk = it; }
    const int choff = kk * 32;
    (void)jj;
#pragma unroll
    for (int q = 0; q < 2; ++q) {
      const int rl = rl_[q], cc = cc_[q];
      // ---- A ----
      const int m = m0 + rl;
      const short* srcA;
      if constexpr (MODE == 0) {
        const int q3 = jj / 3;
        const int ih = ((m >> 4) & 15) + q3 - 1, iw = (m & 15) + (jj - q3 * 3) - 1;
        const bool v = ((unsigned)ih < 16u) & ((unsigned)iw < 16u);
        srcA = v ? Abuf + (size_t)((m & ~255) + ih * 16 + iw) * AK + choff + cc * 8 : zerob;
      } else if constexpr (MODE == 2) {
        const int ih = 2 * ((m >> 4) & 15) + (jj >> 2) - 1, iw = 2 * (m & 15) + (jj & 3) - 1;
        const bool v = ((unsigned)ih < 32u) & ((unsigned)iw < 32u);
        srcA = v ? Abuf + (size_t)((m >> 8) * 1024 + ih * 32 + iw) * AK + choff + cc * 8 : zerob;
      } else if constexpr (MODE == 3) {
        const int ih = ((m >> 4) & 15) + po - (jj >> 1), iw = (m & 15) + pq - (jj & 1);
        const bool v = ((unsigned)ih < 16u) & ((unsigned)iw < 16u);
        srcA = v ? Abuf + (size_t)((m & ~255) + ih * 16 + iw) * AK + choff + cc * 8 : zerob;
      } else {
        srcA = Abuf + (size_t)m * AK + choff + cc * 8;
      }
      __builtin_amdgcn_global_load_lds(
          (const __attribute__((address_space(1))) void*)srcA,
          (__attribute__((address_space(3))) void*)(&Alds[bufc][(wv * 2 + q) * 512]),
          16, 0, 0);
      // ---- B ----
      const short* srcB = Bp + (size_t)jj * TS + (size_t)rl * KPN + choff + cc * 8;
      __builtin_amdgcn_global_load_lds(
          (const __attribute__((address_space(1))) void*)srcB,
          (__attribute__((address_space(3))) void*)(&Alds[bufc][4096 + (wv * 2 + q) * 512]),
          16, 0, 0);
    }
  };

  auto COMPUTE = [&](int it, int bufc) {
    (void)it;
    s16x8 a[4], b[4];
#pragma unroll
    for (int ms = 0; ms < 4; ++ms)
      a[ms] = *(const s16x8*)&Alds[bufc][wm * 2048 + ms * 512 + aoff_base];
#pragma unroll
    for (int ns = 0; ns < 4; ++ns)
      b[ns] = *(const s16x8*)&Alds[bufc][4096 + wn * 2048 + ns * 512 + aoff_base];
#pragma unroll
    for (int ms = 0; ms < 4; ++ms)
#pragma unroll
      for (int ns = 0; ns < 4; ++ns)
        acc[ms][ns] = __builtin_amdgcn_mfma_f32_16x16x32_bf16(a[ms], b[ns], acc[ms][ns], 0, 0, 0);
  };

  STAGE(0, 0);
  for (int it = 0; it < KIT; it += 2) {
    __syncthreads();
    if (it + 1 < KIT) STAGE(it + 1, 1);
    COMPUTE(it, 0);
    __syncthreads();
    if (it + 2 < KIT) STAGE(it + 2, 0);
    COMPUTE(it + 1, 1);
  }

  // ---------------- epilogue ----------------
  const int r4 = lk * 4;
  float ls = 0.f;
#pragma unroll
  for (int ms = 0; ms < 4; ++ms) {
#pragma unroll
    for (int ns = 0; ns < 4; ++ns) {
      const int n_l = wn * 64 + ns * 16 + lcol;
      const int n_g = ncol0 + n_l;
#pragma unroll
      for (int e = 0; e < 4; ++e) {
        const int m = m0 + wm * 64 + ms * 16 + r4 + e;
        if constexpr (MODE == 4) {
          const float val = bias[n_g] - 2.f * acc[ms][ns][e];
          outb[(size_t)m * 1024 + n_g] = f2bf(val);
        } else if constexpr (MODE == 5) {
          const float d = acc[ms][ns][e] - outf32[(size_t)m * 256 + n_g];
          ls = fmaf(d, d, ls);
        } else if constexpr (MODE == 3) {
          const float val = fmaxf(acc[ms][ns][e] + bias[n_l], 0.f);
          const int orow = (m & ~255) * 4 + (2 * ((m >> 4) & 15) + po) * 32 + (2 * (m & 15) + pq);
          outb[(size_t)orow * 128 + n_l] = f2bf(val);
        } else {
          float val = acc[ms][ns][e] + bias[n_g];
          if (res) val += bf2f(res[(size_t)m * 256 + n_g]);
          val = fmaxf(val, 0.f);
          outb[(size_t)m * 256 + n_g] = f2bf(val);
          if (outf32) outf32[(size_t)m * 256 + n_g] = val;
        }
      }
    }
  }
  if constexpr (MODE == 5) {
#pragma unroll
    for (int o = 32; o > 0; o >>= 1) ls += __shfl_xor(ls, o);
    if (l == 0) red[wv] = ls;
    __syncthreads();
    if (tid == 0) atomicAdd(sacc, red[0] + red[1] + red[2] + red[3]);
  }
}

// ========================= VQ block =========================================
__global__ __launch_bounds__(256) void rownorm_kernel(
    const float* __restrict__ a, float* __restrict__ nrm, int rows)
{
  const int wv = threadIdx.x >> 6, lane = threadIdx.x & 63;
  const int r = blockIdx.x * 4 + wv;
  if (r >= rows) return;
  const float* p = a + (size_t)r * DC;
  float s = 0.f;
#pragma unroll
  for (int i = 0; i < 4; ++i) { float v = p[lane + 64 * i]; s = fmaf(v, v, s); }
#pragma unroll
  for (int o = 32; o > 0; o >>= 1) s += __shfl_xor(s, o);
  if (lane == 0) nrm[r] = s;
}

__global__ void initq_kernel(const float* __restrict__ pi, float* __restrict__ logq,
                             float* __restrict__ Sacc)
{
  const int k = blockIdx.x * 256 + threadIdx.x;
  logq[k] = logf(fmaxf(pi[k], EPSQ));
  if (k == 0) *Sacc = 0.f;
}

// one BA iteration over bf16 DV; per-block Q-partials to PART (no atomics).
__global__ __launch_bounds__(256) void ba2_kernel(
    unsigned* __restrict__ DV, const float* __restrict__ logq,
    float* __restrict__ part, int* __restrict__ idxout, int storeP)
{
  __shared__ float qp[4][1024];
  const int tid = threadIdx.x;
  const int wv = tid >> 6, lane = tid & 63;
  for (int i = tid; i < 4096; i += 256) ((float*)qp)[i] = 0.f;
  __syncthreads();

  float2 lq[8];
#pragma unroll
  for (int it = 0; it < 8; ++it) lq[it] = *(const float2*)&logq[it * 128 + lane * 2];

  const int n0 = blockIdx.x * 16;
  for (int rr = 0; rr < 4; ++rr) {
    const int n = n0 + wv * 4 + rr;
    unsigned* rowp = DV + (size_t)n * 512;
    float l0[8], l1[8];
    float mx = -1e30f;
#pragma unroll
    for (int it = 0; it < 8; ++it) {
      const unsigned w = rowp[it * 64 + lane];
      l0[it] = lq[it].x - BETA_F * bf2f((short)(w & 0xFFFFu));
      l1[it] = lq[it].y - BETA_F * bf2f((short)(w >> 16));
      mx = fmaxf(mx, fmaxf(l0[it], l1[it]));
    }
#pragma unroll
    for (int o = 32; o > 0; o >>= 1) mx = fmaxf(mx, __shfl_xor(mx, o));
    float e0[8], e1[8];
    float s = 0.f;
#pragma unroll
    for (int it = 0; it < 8; ++it) {
      e0[it] = __expf(l0[it] - mx);
      e1[it] = __expf(l1[it] - mx);
      s += e0[it] + e1[it];
    }
#pragma unroll
    for (int o = 32; o > 0; o >>= 1) s += __shfl_xor(s, o);
    const float inv = 1.f / s;
#pragma unroll
    for (int it = 0; it < 8; ++it) {
      qp[wv][it * 128 + lane * 2]     += e0[it] * inv;
      qp[wv][it * 128 + lane * 2 + 1] += e1[it] * inv;
    }

    if (storeP) {
#pragma unroll
      for (int it = 0; it < 8; ++it)
        rowp[it * 64 + lane] = pack2(e0[it] * inv, e1[it] * inv);
      float bv = l0[0]; int bi = lane * 2;
      if (l1[0] > bv) { bv = l1[0]; bi = lane * 2 + 1; }
#pragma unroll
      for (int it = 1; it < 8; ++it) {
        const int k = it * 128 + lane * 2;
        if (l0[it] > bv) { bv = l0[it]; bi = k; }
        if (l1[it] > bv) { bv = l1[it]; bi = k + 1; }
      }
#pragma unroll
      for (int o = 32; o > 0; o >>= 1) {
        const float ov = __shfl_xor(bv, o);
        const int oi = __shfl_xor(bi, o);
        if (ov > bv || (ov == bv && oi < bi)) { bv = ov; bi = oi; }
      }
      if (lane == 0) idxout[n] = bi;
    }
  }
  __syncthreads();
  for (int k = tid; k < 1024; k += 256) {
    part[(size_t)blockIdx.x * 1024 + k] = qp[0][k] + qp[1][k] + qp[2][k] + qp[3][k];
  }
}

// reduce stage 1: 64 blocks; block b sums PART rows [32b,32b+32) -> PART2[b][1024]
__global__ __launch_bounds__(256) void qred1_kernel(
    const float* __restrict__ part, float* __restrict__ part2)
{
  const int b = blockIdx.x;
  const int tid = threadIdx.x;
  const float* p = part + (size_t)b * 32 * 1024;
#pragma unroll
  for (int j = 0; j < 4; ++j) {
    const int k = tid + j * 256;
    float s = 0.f;
#pragma unroll
    for (int r = 0; r < 32; ++r) s += p[(size_t)r * 1024 + k];
    part2[(size_t)b * 1024 + k] = s;
  }
}

// reduce stage 2: 4 blocks x 256; sum 64 entries/column -> qsum, logq
__global__ __launch_bounds__(256) void qred2_kernel(
    const float* __restrict__ part2, float* __restrict__ qsum, float* __restrict__ logq)
{
  const int k = blockIdx.x * 256 + threadIdx.x;
  float s = 0.f;
#pragma unroll
  for (int r = 0; r < 64; ++r) s += part2[(size_t)r * 1024 + k];
  qsum[k] = s;
  logq[k] = logf(fmaxf(s * (1.f / 32768.f), EPSQ));
}

__global__ __launch_bounds__(1024) void ent_kernel(
    const float* __restrict__ qsum, float* __restrict__ out_ent)
{
  const int k = threadIdx.x;
  const float q = fmaxf(qsum[k] * (1.f / 32768.f), EPSQ);
  float v = q * logf(q);
#pragma unroll
  for (int o = 32; o > 0; o >>= 1) v += __shfl_xor(v, o);
  __shared__ float red[16];
  const int wv = k >> 6, lane = k & 63;
  if (lane == 0) red[wv] = v;
  __syncthreads();
  if (k == 0) {
    float s = 0.f;
    for (int i = 0; i < 16; ++i) s += red[i];
    *out_ent = 0.01f * s;
  }
}

__global__ void scalars_kernel(const float* __restrict__ S, float* __restrict__ out2)
{
  const float s = *S;
  out2[0] = 0.25f * s / 8388608.f;
  out2[1] = s / 8388608.f;
}

__global__ void gather16_kernel(const int* __restrict__ idx, const short* __restrict__ cbb,
                                short* __restrict__ out)
{
  const int t = blockIdx.x * 256 + threadIdx.x;
  const int m = t >> 6, d4 = (t & 63) * 4;
  *(s16x4*)(out + (size_t)m * 256 + d4) = *(const s16x4*)(cbb + (size_t)idx[m] * 256 + d4);
}

// ========================= convT3: 128->3, 32->64, direct ==================
__global__ __launch_bounds__(256) void convt3_kernel(
    const short* __restrict__ in, const float* __restrict__ w,
    const float* __restrict__ bias, float* __restrict__ out)
{
  __shared__ __align__(16) short li[100 * 136];
  __shared__ float lw[6144];
  const int tid = threadIdx.x;
  const int tile = blockIdx.x;          // 0..15
  const int b = blockIdx.y;
  const int ty0 = (tile >> 2) * 16, tx0 = (tile & 3) * 16;
  const int iy0 = (tile >> 2) * 8 - 1, ix0 = (tile & 3) * 8 - 1;
  for (int s = tid; s < 1600; s += 256) {
    const int pix = s >> 4, ch = s & 15;
    const int r = pix / 10, c = pix - r * 10;
    const int ih = iy0 + r, iw = ix0 + c;
    s16x8 v = {0, 0, 0, 0, 0, 0, 0, 0};
    if ((unsigned)ih < 32u && (unsigned)iw < 32u)
      v = *(const s16x8*)(in + ((size_t)b * 1024 + ih * 32 + iw) * 128 + ch * 8);
    *(s16x8*)&li[pix * 136 + ch * 8] = v;
  }
  for (int s = tid; s < 6144; s += 256) lw[s] = w[s];
  __syncthreads();
  const int ty = tid >> 4, tx = tid & 15;
  const int oh2 = ty0 + ty, ow2 = tx0 + tx;
  const int kh0 = (oh2 + 1) & 1, kw0 = (ow2 + 1) & 1;
  const int ih0 = (oh2 + 1 - kh0) >> 1, iw0 = (ow2 + 1 - kw0) >> 1;
  const int rl0 = ih0 - iy0, cl0 = iw0 - ix0;
  const int p00 = rl0 * 10 + cl0, p01 = p00 - 1, p10 = p00 - 10, p11 = p00 - 11;
  const int wi00 = kh0 * 4 + kw0, wi01 = wi00 + 2, wi10 = wi00 + 8, wi11 = wi00 + 10;
  float acc0 = 0.f, acc1 = 0.f, acc2 = 0.f;
  for (int ch = 0; ch < 16; ++ch) {
    const s16x8 v00 = *(const s16x8*)&li[p00 * 136 + ch * 8];
    const s16x8 v01 = *(const s16x8*)&li[p01 * 136 + ch * 8];
    const s16x8 v10 = *(const s16x8*)&li[p10 * 136 + ch * 8];
    const s16x8 v11 = *(const s16x8*)&li[p11 * 136 + ch * 8];
#pragma unroll
    for (int e = 0; e < 8; ++e) {
      const int ci = ch * 8 + e;
      const float* wr = &lw[ci * 48];
      const float f00 = bf2f(v00[e]), f01 = bf2f(v01[e]);
      const float f10 = bf2f(v10[e]), f11 = bf2f(v11[e]);
      acc0 = fmaf(wr[wi00], f00, fmaf(wr[wi01], f01, fmaf(wr[wi10], f10, fmaf(wr[wi11], f11, acc0))));
      acc1 = fmaf(wr[16 + wi00], f00, fmaf(wr[16 + wi01], f01, fmaf(wr[16 + wi10], f10, fmaf(wr[16 + wi11], f11, acc1))));
      acc2 = fmaf(wr[32 + wi00], f00, fmaf(wr[32 + wi01], f01, fmaf(wr[32 + wi10], f10, fmaf(wr[32 + wi11], f11, acc2))));
    }
  }
  const size_t ob = ((size_t)(b * 3) * 64 + oh2) * 64 + ow2;
  out[ob] = acc0 + bias[0];
  out[ob + 4096] = acc1 + bias[1];
  out[ob + 8192] = acc2 + bias[2];
}

// =====================================================================
extern "C" void kernel_launch(void* const* d_in, const int* in_sizes, int n_in,
                              void* d_out, int out_size, void* d_ws, size_t ws_size,
                              hipStream_t stream)
{
  const float* x     = (const float*)d_in[0];
  const float* ew1   = (const float*)d_in[1];
  const float* eb1   = (const float*)d_in[2];
  const float* ew2   = (const float*)d_in[3];
  const float* eb2   = (const float*)d_in[4];
  const float* ew3   = (const float*)d_in[5];
  const float* eb3   = (const float*)d_in[6];
  const float* er1aw = (const float*)d_in[7];
  const float* er1ab = (const float*)d_in[8];
  const float* er1bw = (const float*)d_in[9];
  const float* er1bb = (const float*)d_in[10];
  const float* er2aw = (const float*)d_in[11];
  const float* er2ab = (const float*)d_in[12];
  const float* er2bw = (const float*)d_in[13];
  const float* er2bb = (const float*)d_in[14];
  const float* cb    = (const float*)d_in[15];
  const float* pi    = (const float*)d_in[16];
  const float* dr1aw = (const float*)d_in[17];
  const float* dr1ab = (const float*)d_in[18];
  const float* dr1bw = (const float*)d_in[19];
  const float* dr1bb = (const float*)d_in[20];
  const float* dr2aw = (const float*)d_in[21];
  const float* dr2ab = (const float*)d_in[22];
  const float* dr2bw = (const float*)d_in[23];
  const float* dr2bb = (const float*)d_in[24];
  const float* dw1   = (const float*)d_in[25];
  const float* db1   = (const float*)d_in[26];
  const float* dwt2  = (const float*)d_in[27];
  const float* dbt2  = (const float*)d_in[28];
  const float* dwt3  = (const float*)d_in[29];
  const float* dbt3  = (const float*)d_in[30];

  float* outf = (float*)d_out;

  // workspace layout (bytes), ~169 MB of 256 MiB
  char* W = (char*)d_ws;
  short* BIGA  = (short*)W;                    // 33.5MB: conv1-out -> ZF32 -> convt2-out
  float* ZF32  = (float*)W;
  short* DV    = (short*)(W + 33554432);       // 67MB bf16 [32768][1024]: dv -> P
  short* X0    = (short*)(W + 100663296);      // 16.7MB each
  short* X1    = (short*)(W + 117440512);
  short* X2    = (short*)(W + 134217728);
  short* WT3   = (short*)(W + 150994944);      // 1,179,648 B
  short* WT2   = (short*)(W + 152174592);      // 1,048,576 B
  short* WTT2  = (short*)(W + 153223168);      // 1,048,576 B
  short* CBB   = (short*)(W + 154271744);      //   524,288 B
  short* CBT   = (short*)(W + 154796032);      //   524,288 B
  float* cn    = (float*)(W + 155320320);      //     4,096 B
  float* qsum  = (float*)(W + 155324416);
  float* logq  = (float*)(W + 155328512);
  int*   idx   = (int*)(W + 155332608);        //   131,072 B
  float* Sacc  = (float*)(W + 155463680);
  short* zerob = (short*)(W + 155463696);
  float* PART  = (float*)(W + 160000000);      // 8,388,608 B [2048][1024]
  float* PART2 = (float*)(W + 168388608);      //   262,144 B [64][1024]

  const dim3 blk(256);
  // conv3x3: MODE 0, KIT 72, AK 256, KPN 256, TS 65536; grid (256, 2)
  #define IG3(A_, W_, B_, R_, O_, F_) \
    igemm_kernel<0,72,256,256,65536><<<dim3(256, 2), blk, 0, stream>>>( \
        A_, W_, B_, R_, O_, F_, nullptr, zerob)

  init0_kernel<<<dim3(1), dim3(64), 0, stream>>>(zerob);

  // -------- encoder --------
  conv1_kernel<<<dim3(4, NB), blk, 0, stream>>>(x, ew1, eb1, BIGA);
  w2t_kernel<<<dim3(2048), blk, 0, stream>>>(ew2, WT2);
  igemm_kernel<2,64,128,128,32768><<<dim3(256, 2), blk, 0, stream>>>(
      BIGA, WT2, eb2, nullptr, X0, nullptr, nullptr, zerob);
  w3t_kernel<<<dim3(2304), blk, 0, stream>>>(ew3, WT3);
  IG3(X0, WT3, eb3, nullptr, X1, nullptr);                 // h3
  w3t_kernel<<<dim3(2304), blk, 0, stream>>>(er1aw, WT3);
  IG3(X1, WT3, er1ab, nullptr, X2, nullptr);
  w3t_kernel<<<dim3(2304), blk, 0, stream>>>(er1bw, WT3);
  IG3(X2, WT3, er1bb, X1, X0, nullptr);                    // h4
  w3t_kernel<<<dim3(2304), blk, 0, stream>>>(er2aw, WT3);
  IG3(X0, WT3, er2ab, nullptr, X1, nullptr);
  w3t_kernel<<<dim3(2304), blk, 0, stream>>>(er2bw, WT3);
  IG3(X1, WT3, er2bb, X0, X2, ZF32);                       // z (bf16 + fp32 dup)

  // -------- VQ / Blahut-Arimoto --------
  rownorm_kernel<<<dim3(KCB / 4), blk, 0, stream>>>(cb, cn, KCB);
  cbbf_kernel<<<dim3(1024), blk, 0, stream>>>(cb, CBB);
  cbt_kernel<<<dim3(1024), blk, 0, stream>>>(cb, CBT);
  initq_kernel<<<dim3(4), blk, 0, stream>>>(pi, logq, Sacc);
  // DV = cn[n] - 2 * zf @ cb^T  (MODE 4): grid (256, 8)
  igemm_kernel<4,8,256,256,0><<<dim3(256, 8), blk, 0, stream>>>(
      X2, CBB, cn, nullptr, DV, nullptr, nullptr, zerob);
  for (int i = 0; i < 5; ++i) {
    ba2_kernel<<<dim3(NROW / 16), blk, 0, stream>>>(
        (unsigned*)DV, logq, PART, idx, (i == 4) ? 1 : 0);
    qred1_kernel<<<dim3(64), blk, 0, stream>>>(PART, PART2);
    qred2_kernel<<<dim3(4), blk, 0, stream>>>(PART2, qsum, logq);
  }
  ent_kernel<<<dim3(1), dim3(1024), 0, stream>>>(qsum, outf + 1572866);
  // pvq (MODE 5): zq_soft = P @ cbT, fused loss vs ZF32; grid (256, 2)
  igemm_kernel<5,32,1024,1024,0><<<dim3(256, 2), blk, 0, stream>>>(
      DV, CBT, nullptr, nullptr, nullptr, ZF32, Sacc, zerob);
  scalars_kernel<<<dim3(1), dim3(1), 0, stream>>>(Sacc, outf + 1572864);
  gather16_kernel<<<dim3(8192), blk, 0, stream>>>(idx, CBB, X0);  // zq_hard NHWC bf16

  // -------- decoder --------
  w3t_kernel<<<dim3(2304), blk, 0, stream>>>(dr1aw, WT3);
  IG3(X0, WT3, dr1ab, nullptr, X1, nullptr);
  w3t_kernel<<<dim3(2304), blk, 0, stream>>>(dr1bw, WT3);
  IG3(X1, WT3, dr1bb, X0, X2, nullptr);                    // y1
  w3t_kernel<<<dim3(2304), blk, 0, stream>>>(dr2aw, WT3);
  IG3(X2, WT3, dr2ab, nullptr, X0, nullptr);
  w3t_kernel<<<dim3(2304), blk, 0, stream>>>(dr2bw, WT3);
  IG3(X0, WT3, dr2bb, X2, X1, nullptr);                    // y2
  w3t_kernel<<<dim3(2304), blk, 0, stream>>>(dw1, WT3);
  IG3(X1, WT3, db1, nullptr, X0, nullptr);                 // y3
  wtt2_kernel<<<dim3(2048), blk, 0, stream>>>(dwt2, WTT2);
  // convT2 (MODE 3): grid (256, 4 parities)
  igemm_kernel<3,32,256,256,32768><<<dim3(256, 4), blk, 0, stream>>>(
      X0, WTT2, dbt2, nullptr, BIGA, nullptr, nullptr, zerob);
  convt3_kernel<<<dim3(16, NB), blk, 0, stream>>>(BIGA, dwt3, dbt3, outf);
  #undef IG3
}

// Round 10
// 1005.976 us; speedup vs baseline: 2.2143x; 1.0249x over previous
//
#include <hip/hip_runtime.h>
#include <math.h>

// ---------------- problem constants ----------------
#define NB   128
#define DC   256
#define SP   256
#define NROW 32768
#define KCB  1024
#define BETA_F 0.1f
#define EPSQ 1e-10f

typedef __attribute__((ext_vector_type(8))) short s16x8;
typedef __attribute__((ext_vector_type(4))) short s16x4;
typedef __attribute__((ext_vector_type(4))) float f32x4;

__device__ __forceinline__ short f2bf(float f) {
  unsigned u = __builtin_bit_cast(unsigned, f);
  unsigned r = (u + 0x7FFFu + ((u >> 16) & 1u)) >> 16;
  return (short)r;
}
__device__ __forceinline__ float bf2f(short s) {
  unsigned u = ((unsigned)(unsigned short)s) << 16;
  return __builtin_bit_cast(float, u);
}
__device__ __forceinline__ unsigned pack2(float a, float b) {
  return (unsigned)(unsigned short)f2bf(a) | ((unsigned)(unsigned short)f2bf(b) << 16);
}

// ========================= init: zero the zero-source buffer ===============
__global__ void init0_kernel(short* __restrict__ zerob)
{
  if (threadIdx.x < 8) zerob[threadIdx.x] = 0;
}

// ========================= weight transposes (fp32 -> bf16) =================
__global__ void w3t_kernel(const float* __restrict__ w, short* __restrict__ o)
{
  const int i = blockIdx.x * 256 + threadIdx.x;  // 589824
  const int ci = i & 255, co = (i >> 8) & 255, j = i >> 16;
  o[i] = f2bf(w[((size_t)(co * 256 + ci)) * 9 + j]);
}
__global__ void w2t_kernel(const float* __restrict__ w, short* __restrict__ o)
{
  const int i = blockIdx.x * 256 + threadIdx.x;  // 524288
  const int ci = i & 127, co = (i >> 7) & 255, j = i >> 15;
  o[i] = f2bf(w[((size_t)(co * 128 + ci)) * 16 + j]);
}
__global__ void wtt2_kernel(const float* __restrict__ w, short* __restrict__ o)
{
  const int i = blockIdx.x * 256 + threadIdx.x;  // 524288
  const int ci = i & 255, co = (i >> 8) & 127, j = (i >> 15) & 3, p = i >> 17;
  const int po = p >> 1, pq = p & 1, a = j >> 1, b2 = j & 1;
  const int kh = (1 - po) + 2 * a, kw = (1 - pq) + 2 * b2;
  o[i] = f2bf(w[((size_t)(ci * 128 + co)) * 16 + kh * 4 + kw]);
}
__global__ void cbbf_kernel(const float* __restrict__ cb, short* __restrict__ o)
{
  const int i = blockIdx.x * 256 + threadIdx.x;  // 262144
  o[i] = f2bf(cb[i]);
}
__global__ void cbt_kernel(const float* __restrict__ cb, short* __restrict__ o)
{
  const int i = blockIdx.x * 256 + threadIdx.x;  // 262144
  const int d = i >> 10, k = i & 1023;
  o[i] = f2bf(cb[(size_t)k * 256 + d]);
}

// ========================= conv1: 3->128, 4x4 s2, 64->32, out NHWC bf16 =====
__global__ __launch_bounds__(256) void conv1_kernel(
    const float* __restrict__ x, const float* __restrict__ w,
    const float* __restrict__ bias, short* __restrict__ out)
{
  __shared__ float li[3][34][34];
  const int tid = threadIdx.x;
  const int tile = blockIdx.x;          // 0..3 quadrant of 32x32 output
  const int b = blockIdx.y;
  const int qy = tile >> 1, qx = tile & 1;
  const int ihlo = qy * 32 - 1, iwlo = qx * 32 - 1;
  for (int ci = 0; ci < 3; ++ci)
    for (int s = tid; s < 1156; s += 256) {
      const int r = s / 34, c = s - r * 34;
      const int ih = ihlo + r, iw = iwlo + c;
      float v = 0.f;
      if ((unsigned)ih < 64u && (unsigned)iw < 64u)
        v = x[((size_t)(b * 3 + ci) * 64 + ih) * 64 + iw];
      li[ci][r][c] = v;
    }
  __syncthreads();

  const int wv = tid >> 6, l = tid & 63;
  const int co0 = 2 * l, co1 = 2 * l + 1;
  float w0[48], w1[48];
#pragma unroll
  for (int j = 0; j < 48; ++j) {
    w0[j] = w[(size_t)co0 * 48 + j];
    w1[j] = w[(size_t)co1 * 48 + j];
  }
  const float b0 = bias[co0], b1 = bias[co1];

  for (int pass = 0; pass < 64; ++pass) {
    const int pix = pass * 4 + wv;            // 0..255
    const int py = pix >> 4, px = pix & 15;
    float s0 = b0, s1 = b1;
#pragma unroll
    for (int ci = 0; ci < 3; ++ci)
#pragma unroll
      for (int kh = 0; kh < 4; ++kh)
#pragma unroll
        for (int kw = 0; kw < 4; ++kw) {
          const int j = ci * 16 + kh * 4 + kw;
          const float v = li[ci][2 * py + kh][2 * px + kw];  // wave-broadcast
          s0 = fmaf(v, w0[j], s0);
          s1 = fmaf(v, w1[j], s1);
        }
    s0 = fmaxf(s0, 0.f);
    s1 = fmaxf(s1, 0.f);
    const int oh = qy * 16 + py, ow = qx * 16 + px;
    ((unsigned*)(out + ((size_t)b * 1024 + oh * 32 + ow) * 128))[l] = pack2(s0, s1);
  }
}

// ========================= MFMA implicit GEMM (m97-style 128x128 tile) ======
// 4 waves as 2x2; wave tile 64x64 = acc[4][4]; A and B both staged in LDS.
template<int MODE, int KIT, int AK, int KPN, int TS>
__global__ __launch_bounds__(256) void igemm_kernel(
    const short* __restrict__ Abuf, const short* __restrict__ Bw,
    const float* __restrict__ bias, const short* __restrict__ res,
    short* __restrict__ outb, float* __restrict__ outf32,
    float* __restrict__ sacc, const short* __restrict__ zerob)
{
  __shared__ __align__(16) short Alds[2][8192];   // per buf: [A 4096 | B 4096]
  __shared__ float red[4];
  const int tid = threadIdx.x;
  const int wv = tid >> 6, l = tid & 63;
  const int wm = wv >> 1, wn = wv & 1;
  const int lcol = l & 15, lk = l >> 4;
  const int m0 = blockIdx.x * 128;

  int ncol0 = 0, po = 0, pq = 0;
  const short* Bp = Bw;
  if constexpr (MODE == 3) {
    po = blockIdx.y >> 1; pq = blockIdx.y & 1;
    Bp += (size_t)blockIdx.y * 131072;            // per-parity slab
  } else {
    ncol0 = blockIdx.y * 128;
    Bp += (size_t)ncol0 * KPN;
  }

  const int cpos = l & 3;
  const int rl_[2] = { (wv * 2) * 16 + (l >> 2), (wv * 2 + 1) * 16 + (l >> 2) };
  const int cc_[2] = { cpos ^ ((rl_[0] >> 1) & 3), cpos ^ ((rl_[1] >> 1) & 3) };

  f32x4 acc[4][4];
#pragma unroll
  for (int i = 0; i < 4; ++i)
#pragma unroll
    for (int j = 0; j < 4; ++j) acc[i][j] = (f32x4){0.f, 0.f, 0.f, 0.f};

  const int aoff_base = lcol * 32 + ((lk ^ ((lcol >> 1) & 3)) * 8);

  auto STAGE = [&](int it, int bufc) {
    int jj, kk;
    if constexpr (MODE == 0 || MODE == 3) { jj = it >> 3; kk = it & 7; }
    else if constexpr (MODE == 2)         { jj = it >> 2; kk = it & 3; }
    else                                  { jj = 0; kk = it; }
    const int choff = kk * 32;
    (void)jj;
#pragma unroll
    for (int q = 0; q < 2; ++q) {
      const int rl = rl_[q], cc = cc_[q];
      const int m = m0 + rl;
      const short* srcA;
      if constexpr (MODE == 0) {
        const int q3 = jj / 3;
        const int ih = ((m >> 4) & 15) + q3 - 1, iw = (m & 15) + (jj - q3 * 3) - 1;
        const bool v = ((unsigned)ih < 16u) & ((unsigned)iw < 16u);
        srcA = v ? Abuf + (size_t)((m & ~255) + ih * 16 + iw) * AK + choff + cc * 8 : zerob;
      } else if constexpr (MODE == 2) {
        const int ih = 2 * ((m >> 4) & 15) + (jj >> 2) - 1, iw = 2 * (m & 15) + (jj & 3) - 1;
        const bool v = ((unsigned)ih < 32u) & ((unsigned)iw < 32u);
        srcA = v ? Abuf + (size_t)((m >> 8) * 1024 + ih * 32 + iw) * AK + choff + cc * 8 : zerob;
      } else if constexpr (MODE == 3) {
        const int ih = ((m >> 4) & 15) + po - (jj >> 1), iw = (m & 15) + pq - (jj & 1);
        const bool v = ((unsigned)ih < 16u) & ((unsigned)iw < 16u);
        srcA = v ? Abuf + (size_t)((m & ~255) + ih * 16 + iw) * AK + choff + cc * 8 : zerob;
      } else {
        srcA = Abuf + (size_t)m * AK + choff + cc * 8;
      }
      __builtin_amdgcn_global_load_lds(
          (const __attribute__((address_space(1))) void*)srcA,
          (__attribute__((address_space(3))) void*)(&Alds[bufc][(wv * 2 + q) * 512]),
          16, 0, 0);
      const short* srcB = Bp + (size_t)jj * TS + (size_t)rl * KPN + choff + cc * 8;
      __builtin_amdgcn_global_load_lds(
          (const __attribute__((address_space(1))) void*)srcB,
          (__attribute__((address_space(3))) void*)(&Alds[bufc][4096 + (wv * 2 + q) * 512]),
          16, 0, 0);
    }
  };

  auto COMPUTE = [&](int it, int bufc) {
    (void)it;
    s16x8 a[4], b[4];
#pragma unroll
    for (int ms = 0; ms < 4; ++ms)
      a[ms] = *(const s16x8*)&Alds[bufc][wm * 2048 + ms * 512 + aoff_base];
#pragma unroll
    for (int ns = 0; ns < 4; ++ns)
      b[ns] = *(const s16x8*)&Alds[bufc][4096 + wn * 2048 + ns * 512 + aoff_base];
#pragma unroll
    for (int ms = 0; ms < 4; ++ms)
#pragma unroll
      for (int ns = 0; ns < 4; ++ns)
        acc[ms][ns] = __builtin_amdgcn_mfma_f32_16x16x32_bf16(a[ms], b[ns], acc[ms][ns], 0, 0, 0);
  };

  STAGE(0, 0);
  for (int it = 0; it < KIT; it += 2) {
    __syncthreads();
    if (it + 1 < KIT) STAGE(it + 1, 1);
    COMPUTE(it, 0);
    __syncthreads();
    if (it + 2 < KIT) STAGE(it + 2, 0);
    COMPUTE(it + 1, 1);
  }

  // ---------------- epilogue ----------------
  const int r4 = lk * 4;
  float ls = 0.f;
#pragma unroll
  for (int ms = 0; ms < 4; ++ms) {
#pragma unroll
    for (int ns = 0; ns < 4; ++ns) {
      const int n_l = wn * 64 + ns * 16 + lcol;
      const int n_g = ncol0 + n_l;
#pragma unroll
      for (int e = 0; e < 4; ++e) {
        const int m = m0 + wm * 64 + ms * 16 + r4 + e;
        if constexpr (MODE == 4) {
          const float val = bias[n_g] - 2.f * acc[ms][ns][e];
          outb[(size_t)m * 1024 + n_g] = f2bf(val);
        } else if constexpr (MODE == 5) {
          const float d = acc[ms][ns][e] - outf32[(size_t)m * 256 + n_g];
          ls = fmaf(d, d, ls);
        } else if constexpr (MODE == 3) {
          const float val = fmaxf(acc[ms][ns][e] + bias[n_l], 0.f);
          const int orow = (m & ~255) * 4 + (2 * ((m >> 4) & 15) + po) * 32 + (2 * (m & 15) + pq);
          outb[(size_t)orow * 128 + n_l] = f2bf(val);
        } else {
          float val = acc[ms][ns][e] + bias[n_g];
          if (res) val += bf2f(res[(size_t)m * 256 + n_g]);
          val = fmaxf(val, 0.f);
          outb[(size_t)m * 256 + n_g] = f2bf(val);
          if (outf32) outf32[(size_t)m * 256 + n_g] = val;
        }
      }
    }
  }
  if constexpr (MODE == 5) {
#pragma unroll
    for (int o = 32; o > 0; o >>= 1) ls += __shfl_xor(ls, o);
    if (l == 0) red[wv] = ls;
    __syncthreads();
    if (tid == 0) atomicAdd(sacc, red[0] + red[1] + red[2] + red[3]);
  }
}

// ========================= VQ block =========================================
__global__ __launch_bounds__(256) void rownorm_kernel(
    const float* __restrict__ a, float* __restrict__ nrm, int rows)
{
  const int wv = threadIdx.x >> 6, lane = threadIdx.x & 63;
  const int r = blockIdx.x * 4 + wv;
  if (r >= rows) return;
  const float* p = a + (size_t)r * DC;
  float s = 0.f;
#pragma unroll
  for (int i = 0; i < 4; ++i) { float v = p[lane + 64 * i]; s = fmaf(v, v, s); }
#pragma unroll
  for (int o = 32; o > 0; o >>= 1) s += __shfl_xor(s, o);
  if (lane == 0) nrm[r] = s;
}

__global__ void initq_kernel(const float* __restrict__ pi, float* __restrict__ logq,
                             float* __restrict__ Sacc)
{
  const int k = blockIdx.x * 256 + threadIdx.x;
  logq[k] = logf(fmaxf(pi[k], EPSQ));
  if (k == 0) *Sacc = 0.f;
}

// one BA iteration over bf16 DV; register-accumulated Q, uint4 row I/O.
// lane owns k in [8*lane, 8*lane+8) and [512+8*lane, 512+8*lane+8).
__global__ __launch_bounds__(256) void ba2_kernel(
    uint4* __restrict__ DV, const float* __restrict__ logq,
    float* __restrict__ part, int* __restrict__ idxout, int storeP)
{
  __shared__ float qp[4][1024];
  const int tid = threadIdx.x;
  const int wv = tid >> 6, lane = tid & 63;

  float lq[16];
  {
    const float4* lq4 = (const float4*)logq;   // 256 float4
#pragma unroll
    for (int h = 0; h < 2; ++h) {
      const float4 a = lq4[h * 128 + 2 * lane];
      const float4 b = lq4[h * 128 + 2 * lane + 1];
      lq[h * 8 + 0] = a.x; lq[h * 8 + 1] = a.y; lq[h * 8 + 2] = a.z; lq[h * 8 + 3] = a.w;
      lq[h * 8 + 4] = b.x; lq[h * 8 + 5] = b.y; lq[h * 8 + 6] = b.z; lq[h * 8 + 7] = b.w;
    }
  }

  float qacc[16];
#pragma unroll
  for (int j = 0; j < 16; ++j) qacc[j] = 0.f;

  const int n0 = blockIdx.x * 16;
  for (int rr = 0; rr < 4; ++rr) {
    const int n = n0 + wv * 4 + rr;
    uint4* rowp = DV + (size_t)n * 128;        // 128 uint4 per row
    uint4 w[2];
    w[0] = rowp[lane];
    w[1] = rowp[64 + lane];
    float lv[16];
    float mx = -1e30f;
#pragma unroll
    for (int h = 0; h < 2; ++h) {
      const unsigned* u = (const unsigned*)&w[h];
#pragma unroll
      for (int p = 0; p < 4; ++p) {
        lv[h * 8 + 2 * p]     = lq[h * 8 + 2 * p]     - BETA_F * bf2f((short)(u[p] & 0xFFFFu));
        lv[h * 8 + 2 * p + 1] = lq[h * 8 + 2 * p + 1] - BETA_F * bf2f((short)(u[p] >> 16));
      }
    }
#pragma unroll
    for (int j = 0; j < 16; ++j) mx = fmaxf(mx, lv[j]);
#pragma unroll
    for (int o = 32; o > 0; o >>= 1) mx = fmaxf(mx, __shfl_xor(mx, o));
    float e[16];
    float s = 0.f;
#pragma unroll
    for (int j = 0; j < 16; ++j) { e[j] = __expf(lv[j] - mx); s += e[j]; }
#pragma unroll
    for (int o = 32; o > 0; o >>= 1) s += __shfl_xor(s, o);
    const float inv = 1.f / s;
#pragma unroll
    for (int j = 0; j < 16; ++j) qacc[j] += e[j] * inv;

    if (storeP) {
#pragma unroll
      for (int h = 0; h < 2; ++h) {
        unsigned* u = (unsigned*)&w[h];
#pragma unroll
        for (int p = 0; p < 4; ++p)
          u[p] = pack2(e[h * 8 + 2 * p] * inv, e[h * 8 + 2 * p + 1] * inv);
      }
      rowp[lane] = w[0];
      rowp[64 + lane] = w[1];
      // argmax (first max; k ascending within each half per lane)
      float bv = lv[0]; int bi = 8 * lane;
#pragma unroll
      for (int h = 0; h < 2; ++h)
#pragma unroll
        for (int j = 0; j < 8; ++j) {
          const int k = h * 512 + 8 * lane + j;
          const float v = lv[h * 8 + j];
          if (v > bv || (v == bv && k < bi)) { bv = v; bi = k; }
        }
#pragma unroll
      for (int o = 32; o > 0; o >>= 1) {
        const float ov = __shfl_xor(bv, o);
        const int oi = __shfl_xor(bi, o);
        if (ov > bv || (ov == bv && oi < bi)) { bv = ov; bi = oi; }
      }
      if (lane == 0) idxout[n] = bi;
    }
  }
  __syncthreads();
#pragma unroll
  for (int h = 0; h < 2; ++h)
#pragma unroll
    for (int j = 0; j < 8; ++j)
      qp[wv][h * 512 + 8 * lane + j] = qacc[h * 8 + j];
  __syncthreads();
  for (int k = tid; k < 1024; k += 256) {
    part[(size_t)blockIdx.x * 1024 + k] = qp[0][k] + qp[1][k] + qp[2][k] + qp[3][k];
  }
}

// reduce stage 1: 64 blocks; block b sums PART rows [32b,32b+32) -> PART2[b][1024]
__global__ __launch_bounds__(256) void qred1_kernel(
    const float* __restrict__ part, float* __restrict__ part2)
{
  const int b = blockIdx.x;
  const int tid = threadIdx.x;
  const float* p = part + (size_t)b * 32 * 1024;
#pragma unroll
  for (int j = 0; j < 4; ++j) {
    const int k = tid + j * 256;
    float s = 0.f;
#pragma unroll
    for (int r = 0; r < 32; ++r) s += p[(size_t)r * 1024 + k];
    part2[(size_t)b * 1024 + k] = s;
  }
}

// reduce stage 2: 4 blocks x 256; sum 64 entries/column -> qsum, logq
__global__ __launch_bounds__(256) void qred2_kernel(
    const float* __restrict__ part2, float* __restrict__ qsum, float* __restrict__ logq)
{
  const int k = blockIdx.x * 256 + threadIdx.x;
  float s = 0.f;
#pragma unroll
  for (int r = 0; r < 64; ++r) s += part2[(size_t)r * 1024 + k];
  qsum[k] = s;
  logq[k] = logf(fmaxf(s * (1.f / 32768.f), EPSQ));
}

__global__ __launch_bounds__(1024) void ent_kernel(
    const float* __restrict__ qsum, float* __restrict__ out_ent)
{
  const int k = threadIdx.x;
  const float q = fmaxf(qsum[k] * (1.f / 32768.f), EPSQ);
  float v = q * logf(q);
#pragma unroll
  for (int o = 32; o > 0; o >>= 1) v += __shfl_xor(v, o);
  __shared__ float red[16];
  const int wv = k >> 6, lane = k & 63;
  if (lane == 0) red[wv] = v;
  __syncthreads();
  if (k == 0) {
    float s = 0.f;
    for (int i = 0; i < 16; ++i) s += red[i];
    *out_ent = 0.01f * s;
  }
}

__global__ void scalars_kernel(const float* __restrict__ S, float* __restrict__ out2)
{
  const float s = *S;
  out2[0] = 0.25f * s / 8388608.f;
  out2[1] = s / 8388608.f;
}

__global__ void gather16_kernel(const int* __restrict__ idx, const short* __restrict__ cbb,
                                short* __restrict__ out)
{
  const int t = blockIdx.x * 256 + threadIdx.x;
  const int m = t >> 6, d4 = (t & 63) * 4;
  *(s16x4*)(out + (size_t)m * 256 + d4) = *(const s16x4*)(cbb + (size_t)idx[m] * 256 + d4);
}

// ========================= convT3: 128->3, 32->64, XOR-swizzled LDS ========
__global__ __launch_bounds__(256) void convt3_kernel(
    const short* __restrict__ in, const float* __restrict__ w,
    const float* __restrict__ bias, float* __restrict__ out)
{
  __shared__ __align__(16) short li[100 * 128];  // [pix][slot], slot = ch ^ (pix&15)
  __shared__ float lw[6144];
  const int tid = threadIdx.x;
  const int tile = blockIdx.x;          // 0..15
  const int b = blockIdx.y;
  const int ty0 = (tile >> 2) * 16, tx0 = (tile & 3) * 16;
  const int iy0 = (tile >> 2) * 8 - 1, ix0 = (tile & 3) * 8 - 1;
  for (int s = tid; s < 1600; s += 256) {
    const int pix = s >> 4, ch = s & 15;
    const int r = pix / 10, c = pix - r * 10;
    const int ih = iy0 + r, iw = ix0 + c;
    s16x8 v = {0, 0, 0, 0, 0, 0, 0, 0};
    if ((unsigned)ih < 32u && (unsigned)iw < 32u)
      v = *(const s16x8*)(in + ((size_t)b * 1024 + ih * 32 + iw) * 128 + ch * 8);
    const int slot = ch ^ (pix & 15);
    *(s16x8*)&li[pix * 128 + slot * 8] = v;
  }
  for (int s = tid; s < 6144; s += 256) lw[s] = w[s];
  __syncthreads();
  const int ty = tid >> 4, tx = tid & 15;
  const int oh2 = ty0 + ty, ow2 = tx0 + tx;
  const int kh0 = (oh2 + 1) & 1, kw0 = (ow2 + 1) & 1;
  const int ih0 = (oh2 + 1 - kh0) >> 1, iw0 = (ow2 + 1 - kw0) >> 1;
  const int rl0 = ih0 - iy0, cl0 = iw0 - ix0;
  const int p00 = rl0 * 10 + cl0, p01 = p00 - 1, p10 = p00 - 10, p11 = p00 - 11;
  const int wi00 = kh0 * 4 + kw0, wi01 = wi00 + 2, wi10 = wi00 + 8, wi11 = wi00 + 10;
  float acc0 = 0.f, acc1 = 0.f, acc2 = 0.f;
  for (int ch = 0; ch < 16; ++ch) {
    const s16x8 v00 = *(const s16x8*)&li[p00 * 128 + (ch ^ (p00 & 15)) * 8];
    const s16x8 v01 = *(const s16x8*)&li[p01 * 128 + (ch ^ (p01 & 15)) * 8];
    const s16x8 v10 = *(const s16x8*)&li[p10 * 128 + (ch ^ (p10 & 15)) * 8];
    const s16x8 v11 = *(const s16x8*)&li[p11 * 128 + (ch ^ (p11 & 15)) * 8];
#pragma unroll
    for (int e = 0; e < 8; ++e) {
      const int ci = ch * 8 + e;
      const float* wr = &lw[ci * 48];
      const float f00 = bf2f(v00[e]), f01 = bf2f(v01[e]);
      const float f10 = bf2f(v10[e]), f11 = bf2f(v11[e]);
      acc0 = fmaf(wr[wi00], f00, fmaf(wr[wi01], f01, fmaf(wr[wi10], f10, fmaf(wr[wi11], f11, acc0))));
      acc1 = fmaf(wr[16 + wi00], f00, fmaf(wr[16 + wi01], f01, fmaf(wr[16 + wi10], f10, fmaf(wr[16 + wi11], f11, acc1))));
      acc2 = fmaf(wr[32 + wi00], f00, fmaf(wr[32 + wi01], f01, fmaf(wr[32 + wi10], f10, fmaf(wr[32 + wi11], f11, acc2))));
    }
  }
  const size_t ob = ((size_t)(b * 3) * 64 + oh2) * 64 + ow2;
  out[ob] = acc0 + bias[0];
  out[ob + 4096] = acc1 + bias[1];
  out[ob + 8192] = acc2 + bias[2];
}

// =====================================================================
extern "C" void kernel_launch(void* const* d_in, const int* in_sizes, int n_in,
                              void* d_out, int out_size, void* d_ws, size_t ws_size,
                              hipStream_t stream)
{
  const float* x     = (const float*)d_in[0];
  const float* ew1   = (const float*)d_in[1];
  const float* eb1   = (const float*)d_in[2];
  const float* ew2   = (const float*)d_in[3];
  const float* eb2   = (const float*)d_in[4];
  const float* ew3   = (const float*)d_in[5];
  const float* eb3   = (const float*)d_in[6];
  const float* er1aw = (const float*)d_in[7];
  const float* er1ab = (const float*)d_in[8];
  const float* er1bw = (const float*)d_in[9];
  const float* er1bb = (const float*)d_in[10];
  const float* er2aw = (const float*)d_in[11];
  const float* er2ab = (const float*)d_in[12];
  const float* er2bw = (const float*)d_in[13];
  const float* er2bb = (const float*)d_in[14];
  const float* cb    = (const float*)d_in[15];
  const float* pi    = (const float*)d_in[16];
  const float* dr1aw = (const float*)d_in[17];
  const float* dr1ab = (const float*)d_in[18];
  const float* dr1bw = (const float*)d_in[19];
  const float* dr1bb = (const float*)d_in[20];
  const float* dr2aw = (const float*)d_in[21];
  const float* dr2ab = (const float*)d_in[22];
  const float* dr2bw = (const float*)d_in[23];
  const float* dr2bb = (const float*)d_in[24];
  const float* dw1   = (const float*)d_in[25];
  const float* db1   = (const float*)d_in[26];
  const float* dwt2  = (const float*)d_in[27];
  const float* dbt2  = (const float*)d_in[28];
  const float* dwt3  = (const float*)d_in[29];
  const float* dbt3  = (const float*)d_in[30];

  float* outf = (float*)d_out;

  // workspace layout (bytes), ~169 MB of 256 MiB
  char* W = (char*)d_ws;
  short* BIGA  = (short*)W;                    // 33.5MB: conv1-out -> ZF32 -> convt2-out
  float* ZF32  = (float*)W;
  short* DV    = (short*)(W + 33554432);       // 67MB bf16 [32768][1024]: dv -> P
  short* X0    = (short*)(W + 100663296);      // 16.7MB each
  short* X1    = (short*)(W + 117440512);
  short* X2    = (short*)(W + 134217728);
  short* WT3   = (short*)(W + 150994944);      // 1,179,648 B
  short* WT2   = (short*)(W + 152174592);      // 1,048,576 B
  short* WTT2  = (short*)(W + 153223168);      // 1,048,576 B
  short* CBB   = (short*)(W + 154271744);      //   524,288 B
  short* CBT   = (short*)(W + 154796032);      //   524,288 B
  float* cn    = (float*)(W + 155320320);      //     4,096 B
  float* qsum  = (float*)(W + 155324416);
  float* logq  = (float*)(W + 155328512);
  int*   idx   = (int*)(W + 155332608);        //   131,072 B
  float* Sacc  = (float*)(W + 155463680);
  short* zerob = (short*)(W + 155463696);
  float* PART  = (float*)(W + 160000000);      // 8,388,608 B [2048][1024]
  float* PART2 = (float*)(W + 168388608);      //   262,144 B [64][1024]

  const dim3 blk(256);
  #define IG3(A_, W_, B_, R_, O_, F_) \
    igemm_kernel<0,72,256,256,65536><<<dim3(256, 2), blk, 0, stream>>>( \
        A_, W_, B_, R_, O_, F_, nullptr, zerob)

  init0_kernel<<<dim3(1), dim3(64), 0, stream>>>(zerob);

  // -------- encoder --------
  conv1_kernel<<<dim3(4, NB), blk, 0, stream>>>(x, ew1, eb1, BIGA);
  w2t_kernel<<<dim3(2048), blk, 0, stream>>>(ew2, WT2);
  igemm_kernel<2,64,128,128,32768><<<dim3(256, 2), blk, 0, stream>>>(
      BIGA, WT2, eb2, nullptr, X0, nullptr, nullptr, zerob);
  w3t_kernel<<<dim3(2304), blk, 0, stream>>>(ew3, WT3);
  IG3(X0, WT3, eb3, nullptr, X1, nullptr);                 // h3
  w3t_kernel<<<dim3(2304), blk, 0, stream>>>(er1aw, WT3);
  IG3(X1, WT3, er1ab, nullptr, X2, nullptr);
  w3t_kernel<<<dim3(2304), blk, 0, stream>>>(er1bw, WT3);
  IG3(X2, WT3, er1bb, X1, X0, nullptr);                    // h4
  w3t_kernel<<<dim3(2304), blk, 0, stream>>>(er2aw, WT3);
  IG3(X0, WT3, er2ab, nullptr, X1, nullptr);
  w3t_kernel<<<dim3(2304), blk, 0, stream>>>(er2bw, WT3);
  IG3(X1, WT3, er2bb, X0, X2, ZF32);                       // z (bf16 + fp32 dup)

  // -------- VQ / Blahut-Arimoto --------
  rownorm_kernel<<<dim3(KCB / 4), blk, 0, stream>>>(cb, cn, KCB);
  cbbf_kernel<<<dim3(1024), blk, 0, stream>>>(cb, CBB);
  cbt_kernel<<<dim3(1024), blk, 0, stream>>>(cb, CBT);
  initq_kernel<<<dim3(4), blk, 0, stream>>>(pi, logq, Sacc);
  igemm_kernel<4,8,256,256,0><<<dim3(256, 8), blk, 0, stream>>>(
      X2, CBB, cn, nullptr, DV, nullptr, nullptr, zerob);
  for (int i = 0; i < 5; ++i) {
    ba2_kernel<<<dim3(NROW / 16), blk, 0, stream>>>(
        (uint4*)DV, logq, PART, idx, (i == 4) ? 1 : 0);
    qred1_kernel<<<dim3(64), blk, 0, stream>>>(PART, PART2);
    qred2_kernel<<<dim3(4), blk, 0, stream>>>(PART2, qsum, logq);
  }
  ent_kernel<<<dim3(1), dim3(1024), 0, stream>>>(qsum, outf + 1572866);
  igemm_kernel<5,32,1024,1024,0><<<dim3(256, 2), blk, 0, stream>>>(
      DV, CBT, nullptr, nullptr, nullptr, ZF32, Sacc, zerob);
  scalars_kernel<<<dim3(1), dim3(1), 0, stream>>>(Sacc, outf + 1572864);
  gather16_kernel<<<dim3(8192), blk, 0, stream>>>(idx, CBB, X0);  // zq_hard NHWC bf16

  // -------- decoder --------
  w3t_kernel<<<dim3(2304), blk, 0, stream>>>(dr1aw, WT3);
  IG3(X0, WT3, dr1ab, nullptr, X1, nullptr);
  w3t_kernel<<<dim3(2304), blk, 0, stream>>>(dr1bw, WT3);
  IG3(X1, WT3, dr1bb, X0, X2, nullptr);                    // y1
  w3t_kernel<<<dim3(2304), blk, 0, stream>>>(dr2aw, WT3);
  IG3(X2, WT3, dr2ab, nullptr, X0, nullptr);
  w3t_kernel<<<dim3(2304), blk, 0, stream>>>(dr2bw, WT3);
  IG3(X0, WT3, dr2bb, X2, X1, nullptr);                    // y2
  w3t_kernel<<<dim3(2304), blk, 0, stream>>>(dw1, WT3);
  IG3(X1, WT3, db1, nullptr, X0, nullptr);                 // y3
  wtt2_kernel<<<dim3(2048), blk, 0, stream>>>(dwt2, WTT2);
  igemm_kernel<3,32,256,256,32768><<<dim3(256, 4), blk, 0, stream>>>(
      X0, WTT2, dbt2, nullptr, BIGA, nullptr, nullptr, zerob);
  convt3_kernel<<<dim3(16, NB), blk, 0, stream>>>(BIGA, dwt3, dbt3, outf);
  #undef IG3
}

// Round 11
// 984.944 us; speedup vs baseline: 2.2616x; 1.0214x over previous
//
#include <hip/hip_runtime.h>
#include <math.h>

// ---------------- problem constants ----------------
#define NB   128
#define DC   256
#define SP   256
#define NROW 32768
#define KCB  1024
#define BETA_F 0.1f
#define EPSQ 1e-10f

typedef __attribute__((ext_vector_type(8))) short s16x8;
typedef __attribute__((ext_vector_type(4))) short s16x4;
typedef __attribute__((ext_vector_type(4))) float f32x4;

__device__ __forceinline__ short f2bf(float f) {
  unsigned u = __builtin_bit_cast(unsigned, f);
  unsigned r = (u + 0x7FFFu + ((u >> 16) & 1u)) >> 16;
  return (short)r;
}
__device__ __forceinline__ float bf2f(short s) {
  unsigned u = ((unsigned)(unsigned short)s) << 16;
  return __builtin_bit_cast(float, u);
}
__device__ __forceinline__ unsigned pack2(float a, float b) {
  return (unsigned)(unsigned short)f2bf(a) | ((unsigned)(unsigned short)f2bf(b) << 16);
}

// ========================= init: zero the zero-source buffer ===============
__global__ void init0_kernel(short* __restrict__ zerob)
{
  if (threadIdx.x < 8) zerob[threadIdx.x] = 0;
}

// ========================= weight transposes (fp32 -> bf16) =================
__global__ void w3t_kernel(const float* __restrict__ w, short* __restrict__ o)
{
  const int i = blockIdx.x * 256 + threadIdx.x;  // 589824
  const int ci = i & 255, co = (i >> 8) & 255, j = i >> 16;
  o[i] = f2bf(w[((size_t)(co * 256 + ci)) * 9 + j]);
}
__global__ void w2t_kernel(const float* __restrict__ w, short* __restrict__ o)
{
  const int i = blockIdx.x * 256 + threadIdx.x;  // 524288
  const int ci = i & 127, co = (i >> 7) & 255, j = i >> 15;
  o[i] = f2bf(w[((size_t)(co * 128 + ci)) * 16 + j]);
}
__global__ void wtt2_kernel(const float* __restrict__ w, short* __restrict__ o)
{
  const int i = blockIdx.x * 256 + threadIdx.x;  // 524288
  const int ci = i & 255, co = (i >> 8) & 127, j = (i >> 15) & 3, p = i >> 17;
  const int po = p >> 1, pq = p & 1, a = j >> 1, b2 = j & 1;
  const int kh = (1 - po) + 2 * a, kw = (1 - pq) + 2 * b2;
  o[i] = f2bf(w[((size_t)(ci * 128 + co)) * 16 + kh * 4 + kw]);
}
__global__ void cbbf_kernel(const float* __restrict__ cb, short* __restrict__ o)
{
  const int i = blockIdx.x * 256 + threadIdx.x;  // 262144
  o[i] = f2bf(cb[i]);
}
__global__ void cbt_kernel(const float* __restrict__ cb, short* __restrict__ o)
{
  const int i = blockIdx.x * 256 + threadIdx.x;  // 262144
  const int d = i >> 10, k = i & 1023;
  o[i] = f2bf(cb[(size_t)k * 256 + d]);
}

// ========================= conv1: 3->128, 4x4 s2, 64->32, out NHWC bf16 =====
__global__ __launch_bounds__(256) void conv1_kernel(
    const float* __restrict__ x, const float* __restrict__ w,
    const float* __restrict__ bias, short* __restrict__ out)
{
  __shared__ float li[3][34][34];
  const int tid = threadIdx.x;
  const int tile = blockIdx.x;          // 0..3 quadrant of 32x32 output
  const int b = blockIdx.y;
  const int qy = tile >> 1, qx = tile & 1;
  const int ihlo = qy * 32 - 1, iwlo = qx * 32 - 1;
  for (int ci = 0; ci < 3; ++ci)
    for (int s = tid; s < 1156; s += 256) {
      const int r = s / 34, c = s - r * 34;
      const int ih = ihlo + r, iw = iwlo + c;
      float v = 0.f;
      if ((unsigned)ih < 64u && (unsigned)iw < 64u)
        v = x[((size_t)(b * 3 + ci) * 64 + ih) * 64 + iw];
      li[ci][r][c] = v;
    }
  __syncthreads();

  const int wv = tid >> 6, l = tid & 63;
  const int co0 = 2 * l, co1 = 2 * l + 1;
  float w0[48], w1[48];
#pragma unroll
  for (int j = 0; j < 48; ++j) {
    w0[j] = w[(size_t)co0 * 48 + j];
    w1[j] = w[(size_t)co1 * 48 + j];
  }
  const float b0 = bias[co0], b1 = bias[co1];

  for (int pass = 0; pass < 64; ++pass) {
    const int pix = pass * 4 + wv;            // 0..255
    const int py = pix >> 4, px = pix & 15;
    float s0 = b0, s1 = b1;
#pragma unroll
    for (int ci = 0; ci < 3; ++ci)
#pragma unroll
      for (int kh = 0; kh < 4; ++kh)
#pragma unroll
        for (int kw = 0; kw < 4; ++kw) {
          const int j = ci * 16 + kh * 4 + kw;
          const float v = li[ci][2 * py + kh][2 * px + kw];  // wave-broadcast
          s0 = fmaf(v, w0[j], s0);
          s1 = fmaf(v, w1[j], s1);
        }
    s0 = fmaxf(s0, 0.f);
    s1 = fmaxf(s1, 0.f);
    const int oh = qy * 16 + py, ow = qx * 16 + px;
    ((unsigned*)(out + ((size_t)b * 1024 + oh * 32 + ow) * 128))[l] = pack2(s0, s1);
  }
}

// ========================= MFMA implicit GEMM (128x128 tile, BK=64) =========
// 4 waves as 2x2; wave tile 64x64 = acc[4][4]; A and B both staged in LDS.
// Per stage: two 32-ci chunk-planes -> 32 MFMAs per barrier phase.
// KIT counts chunk-PAIRS. LDS per buf: [A c0 | A c1 | B c0 | B c1] x 4096 shorts.
template<int MODE, int KIT, int AK, int KPN, int TS>
__global__ __launch_bounds__(256) void igemm_kernel(
    const short* __restrict__ Abuf, const short* __restrict__ Bw,
    const float* __restrict__ bias, const short* __restrict__ res,
    short* __restrict__ outb, float* __restrict__ outf32,
    float* __restrict__ sacc, const short* __restrict__ zerob)
{
  __shared__ __align__(16) short Alds[2][16384];
  __shared__ float red[4];
  const int tid = threadIdx.x;
  const int wv = tid >> 6, l = tid & 63;
  const int wm = wv >> 1, wn = wv & 1;
  const int lcol = l & 15, lk = l >> 4;
  const int m0 = blockIdx.x * 128;

  int ncol0 = 0, po = 0, pq = 0;
  const short* Bp = Bw;
  if constexpr (MODE == 3) {
    po = blockIdx.y >> 1; pq = blockIdx.y & 1;
    Bp += (size_t)blockIdx.y * 131072;            // per-parity slab
  } else {
    ncol0 = blockIdx.y * 128;
    Bp += (size_t)ncol0 * KPN;
  }

  const int cpos = l & 3;
  const int rl_[2] = { (wv * 2) * 16 + (l >> 2), (wv * 2 + 1) * 16 + (l >> 2) };
  const int cc_[2] = { cpos ^ ((rl_[0] >> 1) & 3), cpos ^ ((rl_[1] >> 1) & 3) };

  f32x4 acc[4][4];
#pragma unroll
  for (int i = 0; i < 4; ++i)
#pragma unroll
    for (int j = 0; j < 4; ++j) acc[i][j] = (f32x4){0.f, 0.f, 0.f, 0.f};

  const int aoff_base = lcol * 32 + ((lk ^ ((lcol >> 1) & 3)) * 8);

  auto STAGE = [&](int it, int bufc) {
    int jj, kp;
    if constexpr (MODE == 0 || MODE == 3) { jj = it >> 2; kp = it & 3; }
    else if constexpr (MODE == 2)         { jj = it >> 1; kp = it & 1; }
    else                                  { jj = 0; kp = it; }
    (void)jj;
#pragma unroll
    for (int c = 0; c < 2; ++c) {
      const int choff = (2 * kp + c) * 32;
#pragma unroll
      for (int q = 0; q < 2; ++q) {
        const int rl = rl_[q], cc = cc_[q];
        const int m = m0 + rl;
        const short* srcA;
        if constexpr (MODE == 0) {
          const int q3 = jj / 3;
          const int ih = ((m >> 4) & 15) + q3 - 1, iw = (m & 15) + (jj - q3 * 3) - 1;
          const bool v = ((unsigned)ih < 16u) & ((unsigned)iw < 16u);
          srcA = v ? Abuf + (size_t)((m & ~255) + ih * 16 + iw) * AK + choff + cc * 8 : zerob;
        } else if constexpr (MODE == 2) {
          const int ih = 2 * ((m >> 4) & 15) + (jj >> 2) - 1, iw = 2 * (m & 15) + (jj & 3) - 1;
          const bool v = ((unsigned)ih < 32u) & ((unsigned)iw < 32u);
          srcA = v ? Abuf + (size_t)((m >> 8) * 1024 + ih * 32 + iw) * AK + choff + cc * 8 : zerob;
        } else if constexpr (MODE == 3) {
          const int ih = ((m >> 4) & 15) + po - (jj >> 1), iw = (m & 15) + pq - (jj & 1);
          const bool v = ((unsigned)ih < 16u) & ((unsigned)iw < 16u);
          srcA = v ? Abuf + (size_t)((m & ~255) + ih * 16 + iw) * AK + choff + cc * 8 : zerob;
        } else {
          srcA = Abuf + (size_t)m * AK + choff + cc * 8;
        }
        __builtin_amdgcn_global_load_lds(
            (const __attribute__((address_space(1))) void*)srcA,
            (__attribute__((address_space(3))) void*)(&Alds[bufc][c * 4096 + (wv * 2 + q) * 512]),
            16, 0, 0);
        const short* srcB = Bp + (size_t)jj * TS + (size_t)rl * KPN + choff + cc * 8;
        __builtin_amdgcn_global_load_lds(
            (const __attribute__((address_space(1))) void*)srcB,
            (__attribute__((address_space(3))) void*)(&Alds[bufc][8192 + c * 4096 + (wv * 2 + q) * 512]),
            16, 0, 0);
      }
    }
  };

  auto COMPUTE = [&](int it, int bufc) {
    (void)it;
#pragma unroll
    for (int c = 0; c < 2; ++c) {
      s16x8 a[4], b[4];
#pragma unroll
      for (int ms = 0; ms < 4; ++ms)
        a[ms] = *(const s16x8*)&Alds[bufc][c * 4096 + wm * 2048 + ms * 512 + aoff_base];
#pragma unroll
      for (int ns = 0; ns < 4; ++ns)
        b[ns] = *(const s16x8*)&Alds[bufc][8192 + c * 4096 + wn * 2048 + ns * 512 + aoff_base];
#pragma unroll
      for (int ms = 0; ms < 4; ++ms)
#pragma unroll
        for (int ns = 0; ns < 4; ++ns)
          acc[ms][ns] = __builtin_amdgcn_mfma_f32_16x16x32_bf16(a[ms], b[ns], acc[ms][ns], 0, 0, 0);
    }
  };

  STAGE(0, 0);
  for (int it = 0; it < KIT; it += 2) {
    __syncthreads();
    if (it + 1 < KIT) STAGE(it + 1, 1);
    COMPUTE(it, 0);
    __syncthreads();
    if (it + 2 < KIT) STAGE(it + 2, 0);
    COMPUTE(it + 1, 1);
  }

  // ---------------- epilogue ----------------
  const int r4 = lk * 4;
  float ls = 0.f;
#pragma unroll
  for (int ms = 0; ms < 4; ++ms) {
#pragma unroll
    for (int ns = 0; ns < 4; ++ns) {
      const int n_l = wn * 64 + ns * 16 + lcol;
      const int n_g = ncol0 + n_l;
#pragma unroll
      for (int e = 0; e < 4; ++e) {
        const int m = m0 + wm * 64 + ms * 16 + r4 + e;
        if constexpr (MODE == 4) {
          const float val = bias[n_g] - 2.f * acc[ms][ns][e];
          outb[(size_t)m * 1024 + n_g] = f2bf(val);
        } else if constexpr (MODE == 5) {
          const float d = acc[ms][ns][e] - outf32[(size_t)m * 256 + n_g];
          ls = fmaf(d, d, ls);
        } else if constexpr (MODE == 3) {
          const float val = fmaxf(acc[ms][ns][e] + bias[n_l], 0.f);
          const int orow = (m & ~255) * 4 + (2 * ((m >> 4) & 15) + po) * 32 + (2 * (m & 15) + pq);
          outb[(size_t)orow * 128 + n_l] = f2bf(val);
        } else {
          float val = acc[ms][ns][e] + bias[n_g];
          if (res) val += bf2f(res[(size_t)m * 256 + n_g]);
          val = fmaxf(val, 0.f);
          outb[(size_t)m * 256 + n_g] = f2bf(val);
          if (outf32) outf32[(size_t)m * 256 + n_g] = val;
        }
      }
    }
  }
  if constexpr (MODE == 5) {
#pragma unroll
    for (int o = 32; o > 0; o >>= 1) ls += __shfl_xor(ls, o);
    if (l == 0) red[wv] = ls;
    __syncthreads();
    if (tid == 0) atomicAdd(sacc, red[0] + red[1] + red[2] + red[3]);
  }
}

// ========================= VQ block =========================================
__global__ __launch_bounds__(256) void rownorm_kernel(
    const float* __restrict__ a, float* __restrict__ nrm, int rows)
{
  const int wv = threadIdx.x >> 6, lane = threadIdx.x & 63;
  const int r = blockIdx.x * 4 + wv;
  if (r >= rows) return;
  const float* p = a + (size_t)r * DC;
  float s = 0.f;
#pragma unroll
  for (int i = 0; i < 4; ++i) { float v = p[lane + 64 * i]; s = fmaf(v, v, s); }
#pragma unroll
  for (int o = 32; o > 0; o >>= 1) s += __shfl_xor(s, o);
  if (lane == 0) nrm[r] = s;
}

__global__ void initq_kernel(const float* __restrict__ pi, float* __restrict__ logq,
                             float* __restrict__ Sacc)
{
  const int k = blockIdx.x * 256 + threadIdx.x;
  logq[k] = logf(fmaxf(pi[k], EPSQ));
  if (k == 0) *Sacc = 0.f;
}

// one BA iteration over bf16 DV; register-accumulated Q, uint4 row I/O.
__global__ __launch_bounds__(256) void ba2_kernel(
    uint4* __restrict__ DV, const float* __restrict__ logq,
    float* __restrict__ part, int* __restrict__ idxout, int storeP)
{
  __shared__ float qp[4][1024];
  const int tid = threadIdx.x;
  const int wv = tid >> 6, lane = tid & 63;

  float lq[16];
  {
    const float4* lq4 = (const float4*)logq;   // 256 float4
#pragma unroll
    for (int h = 0; h < 2; ++h) {
      const float4 a = lq4[h * 128 + 2 * lane];
      const float4 b = lq4[h * 128 + 2 * lane + 1];
      lq[h * 8 + 0] = a.x; lq[h * 8 + 1] = a.y; lq[h * 8 + 2] = a.z; lq[h * 8 + 3] = a.w;
      lq[h * 8 + 4] = b.x; lq[h * 8 + 5] = b.y; lq[h * 8 + 6] = b.z; lq[h * 8 + 7] = b.w;
    }
  }

  float qacc[16];
#pragma unroll
  for (int j = 0; j < 16; ++j) qacc[j] = 0.f;

  const int n0 = blockIdx.x * 16;
  for (int rr = 0; rr < 4; ++rr) {
    const int n = n0 + wv * 4 + rr;
    uint4* rowp = DV + (size_t)n * 128;        // 128 uint4 per row
    uint4 w[2];
    w[0] = rowp[lane];
    w[1] = rowp[64 + lane];
    float lv[16];
    float mx = -1e30f;
#pragma unroll
    for (int h = 0; h < 2; ++h) {
      const unsigned* u = (const unsigned*)&w[h];
#pragma unroll
      for (int p = 0; p < 4; ++p) {
        lv[h * 8 + 2 * p]     = lq[h * 8 + 2 * p]     - BETA_F * bf2f((short)(u[p] & 0xFFFFu));
        lv[h * 8 + 2 * p + 1] = lq[h * 8 + 2 * p + 1] - BETA_F * bf2f((short)(u[p] >> 16));
      }
    }
#pragma unroll
    for (int j = 0; j < 16; ++j) mx = fmaxf(mx, lv[j]);
#pragma unroll
    for (int o = 32; o > 0; o >>= 1) mx = fmaxf(mx, __shfl_xor(mx, o));
    float e[16];
    float s = 0.f;
#pragma unroll
    for (int j = 0; j < 16; ++j) { e[j] = __expf(lv[j] - mx); s += e[j]; }
#pragma unroll
    for (int o = 32; o > 0; o >>= 1) s += __shfl_xor(s, o);
    const float inv = 1.f / s;
#pragma unroll
    for (int j = 0; j < 16; ++j) qacc[j] += e[j] * inv;

    if (storeP) {
#pragma unroll
      for (int h = 0; h < 2; ++h) {
        unsigned* u = (unsigned*)&w[h];
#pragma unroll
        for (int p = 0; p < 4; ++p)
          u[p] = pack2(e[h * 8 + 2 * p] * inv, e[h * 8 + 2 * p + 1] * inv);
      }
      rowp[lane] = w[0];
      rowp[64 + lane] = w[1];
      float bv = lv[0]; int bi = 8 * lane;
#pragma unroll
      for (int h = 0; h < 2; ++h)
#pragma unroll
        for (int j = 0; j < 8; ++j) {
          const int k = h * 512 + 8 * lane + j;
          const float v = lv[h * 8 + j];
          if (v > bv || (v == bv && k < bi)) { bv = v; bi = k; }
        }
#pragma unroll
      for (int o = 32; o > 0; o >>= 1) {
        const float ov = __shfl_xor(bv, o);
        const int oi = __shfl_xor(bi, o);
        if (ov > bv || (ov == bv && oi < bi)) { bv = ov; bi = oi; }
      }
      if (lane == 0) idxout[n] = bi;
    }
  }
  __syncthreads();
#pragma unroll
  for (int h = 0; h < 2; ++h)
#pragma unroll
    for (int j = 0; j < 8; ++j)
      qp[wv][h * 512 + 8 * lane + j] = qacc[h * 8 + j];
  __syncthreads();
  for (int k = tid; k < 1024; k += 256) {
    part[(size_t)blockIdx.x * 1024 + k] = qp[0][k] + qp[1][k] + qp[2][k] + qp[3][k];
  }
}

// reduce stage 1: 64 blocks; block b sums PART rows [32b,32b+32) -> PART2[b][1024]
__global__ __launch_bounds__(256) void qred1_kernel(
    const float* __restrict__ part, float* __restrict__ part2)
{
  const int b = blockIdx.x;
  const int tid = threadIdx.x;
  const float* p = part + (size_t)b * 32 * 1024;
#pragma unroll
  for (int j = 0; j < 4; ++j) {
    const int k = tid + j * 256;
    float s = 0.f;
#pragma unroll
    for (int r = 0; r < 32; ++r) s += p[(size_t)r * 1024 + k];
    part2[(size_t)b * 1024 + k] = s;
  }
}

// reduce stage 2: 4 blocks x 256; sum 64 entries/column -> qsum, logq
__global__ __launch_bounds__(256) void qred2_kernel(
    const float* __restrict__ part2, float* __restrict__ qsum, float* __restrict__ logq)
{
  const int k = blockIdx.x * 256 + threadIdx.x;
  float s = 0.f;
#pragma unroll
  for (int r = 0; r < 64; ++r) s += part2[(size_t)r * 1024 + k];
  qsum[k] = s;
  logq[k] = logf(fmaxf(s * (1.f / 32768.f), EPSQ));
}

__global__ __launch_bounds__(1024) void ent_kernel(
    const float* __restrict__ qsum, float* __restrict__ out_ent)
{
  const int k = threadIdx.x;
  const float q = fmaxf(qsum[k] * (1.f / 32768.f), EPSQ);
  float v = q * logf(q);
#pragma unroll
  for (int o = 32; o > 0; o >>= 1) v += __shfl_xor(v, o);
  __shared__ float red[16];
  const int wv = k >> 6, lane = k & 63;
  if (lane == 0) red[wv] = v;
  __syncthreads();
  if (k == 0) {
    float s = 0.f;
    for (int i = 0; i < 16; ++i) s += red[i];
    *out_ent = 0.01f * s;
  }
}

__global__ void scalars_kernel(const float* __restrict__ S, float* __restrict__ out2)
{
  const float s = *S;
  out2[0] = 0.25f * s / 8388608.f;
  out2[1] = s / 8388608.f;
}

__global__ void gather16_kernel(const int* __restrict__ idx, const short* __restrict__ cbb,
                                short* __restrict__ out)
{
  const int t = blockIdx.x * 256 + threadIdx.x;
  const int m = t >> 6, d4 = (t & 63) * 4;
  *(s16x4*)(out + (size_t)m * 256 + d4) = *(const s16x4*)(cbb + (size_t)idx[m] * 256 + d4);
}

// ========================= convT3: 128->3, 32->64 ==========================
__global__ __launch_bounds__(256) void convt3_kernel(
    const short* __restrict__ in, const float* __restrict__ w,
    const float* __restrict__ bias, float* __restrict__ out)
{
  __shared__ __align__(16) short li[100 * 128];  // [pix][slot], slot = ch ^ (pix&15)
  __shared__ float lw[6144];
  const int tid = threadIdx.x;
  const int tile = blockIdx.x;          // 0..15
  const int b = blockIdx.y;
  const int ty0 = (tile >> 2) * 16, tx0 = (tile & 3) * 16;
  const int iy0 = (tile >> 2) * 8 - 1, ix0 = (tile & 3) * 8 - 1;
  for (int s = tid; s < 1600; s += 256) {
    const int pix = s >> 4, ch = s & 15;
    const int r = pix / 10, c = pix - r * 10;
    const int ih = iy0 + r, iw = ix0 + c;
    s16x8 v = {0, 0, 0, 0, 0, 0, 0, 0};
    if ((unsigned)ih < 32u && (unsigned)iw < 32u)
      v = *(const s16x8*)(in + ((size_t)b * 1024 + ih * 32 + iw) * 128 + ch * 8);
    const int slot = ch ^ (pix & 15);
    *(s16x8*)&li[pix * 128 + slot * 8] = v;
  }
  for (int s = tid; s < 6144; s += 256) lw[s] = w[s];
  __syncthreads();
  const int ty = tid >> 4, tx = tid & 15;
  const int oh2 = ty0 + ty, ow2 = tx0 + tx;
  const int kh0 = (oh2 + 1) & 1, kw0 = (ow2 + 1) & 1;
  const int ih0 = (oh2 + 1 - kh0) >> 1, iw0 = (ow2 + 1 - kw0) >> 1;
  const int rl0 = ih0 - iy0, cl0 = iw0 - ix0;
  const int p00 = rl0 * 10 + cl0, p01 = p00 - 1, p10 = p00 - 10, p11 = p00 - 11;
  const int wi00 = kh0 * 4 + kw0, wi01 = wi00 + 2, wi10 = wi00 + 8, wi11 = wi00 + 10;
  float acc0 = 0.f, acc1 = 0.f, acc2 = 0.f;
  for (int ch = 0; ch < 16; ++ch) {
    const s16x8 v00 = *(const s16x8*)&li[p00 * 128 + (ch ^ (p00 & 15)) * 8];
    const s16x8 v01 = *(const s16x8*)&li[p01 * 128 + (ch ^ (p01 & 15)) * 8];
    const s16x8 v10 = *(const s16x8*)&li[p10 * 128 + (ch ^ (p10 & 15)) * 8];
    const s16x8 v11 = *(const s16x8*)&li[p11 * 128 + (ch ^ (p11 & 15)) * 8];
#pragma unroll
    for (int e = 0; e < 8; ++e) {
      const int ci = ch * 8 + e;
      const float* wr = &lw[ci * 48];
      const float f00 = bf2f(v00[e]), f01 = bf2f(v01[e]);
      const float f10 = bf2f(v10[e]), f11 = bf2f(v11[e]);
      acc0 = fmaf(wr[wi00], f00, fmaf(wr[wi01], f01, fmaf(wr[wi10], f10, fmaf(wr[wi11], f11, acc0))));
      acc1 = fmaf(wr[16 + wi00], f00, fmaf(wr[16 + wi01], f01, fmaf(wr[16 + wi10], f10, fmaf(wr[16 + wi11], f11, acc1))));
      acc2 = fmaf(wr[32 + wi00], f00, fmaf(wr[32 + wi01], f01, fmaf(wr[32 + wi10], f10, fmaf(wr[32 + wi11], f11, acc2))));
    }
  }
  const size_t ob = ((size_t)(b * 3) * 64 + oh2) * 64 + ow2;
  out[ob] = acc0 + bias[0];
  out[ob + 4096] = acc1 + bias[1];
  out[ob + 8192] = acc2 + bias[2];
}

// =====================================================================
extern "C" void kernel_launch(void* const* d_in, const int* in_sizes, int n_in,
                              void* d_out, int out_size, void* d_ws, size_t ws_size,
                              hipStream_t stream)
{
  const float* x     = (const float*)d_in[0];
  const float* ew1   = (const float*)d_in[1];
  const float* eb1   = (const float*)d_in[2];
  const float* ew2   = (const float*)d_in[3];
  const float* eb2   = (const float*)d_in[4];
  const float* ew3   = (const float*)d_in[5];
  const float* eb3   = (const float*)d_in[6];
  const float* er1aw = (const float*)d_in[7];
  const float* er1ab = (const float*)d_in[8];
  const float* er1bw = (const float*)d_in[9];
  const float* er1bb = (const float*)d_in[10];
  const float* er2aw = (const float*)d_in[11];
  const float* er2ab = (const float*)d_in[12];
  const float* er2bw = (const float*)d_in[13];
  const float* er2bb = (const float*)d_in[14];
  const float* cb    = (const float*)d_in[15];
  const float* pi    = (const float*)d_in[16];
  const float* dr1aw = (const float*)d_in[17];
  const float* dr1ab = (const float*)d_in[18];
  const float* dr1bw = (const float*)d_in[19];
  const float* dr1bb = (const float*)d_in[20];
  const float* dr2aw = (const float*)d_in[21];
  const float* dr2ab = (const float*)d_in[22];
  const float* dr2bw = (const float*)d_in[23];
  const float* dr2bb = (const float*)d_in[24];
  const float* dw1   = (const float*)d_in[25];
  const float* db1   = (const float*)d_in[26];
  const float* dwt2  = (const float*)d_in[27];
  const float* dbt2  = (const float*)d_in[28];
  const float* dwt3  = (const float*)d_in[29];
  const float* dbt3  = (const float*)d_in[30];

  float* outf = (float*)d_out;

  // workspace layout (bytes), ~169 MB of 256 MiB
  char* W = (char*)d_ws;
  short* BIGA  = (short*)W;                    // 33.5MB: conv1-out -> ZF32 -> convt2-out
  float* ZF32  = (float*)W;
  short* DV    = (short*)(W + 33554432);       // 67MB bf16 [32768][1024]: dv -> P
  short* X0    = (short*)(W + 100663296);      // 16.7MB each
  short* X1    = (short*)(W + 117440512);
  short* X2    = (short*)(W + 134217728);
  short* WT3   = (short*)(W + 150994944);      // 1,179,648 B
  short* WT2   = (short*)(W + 152174592);      // 1,048,576 B
  short* WTT2  = (short*)(W + 153223168);      // 1,048,576 B
  short* CBB   = (short*)(W + 154271744);      //   524,288 B
  short* CBT   = (short*)(W + 154796032);      //   524,288 B
  float* cn    = (float*)(W + 155320320);      //     4,096 B
  float* qsum  = (float*)(W + 155324416);
  float* logq  = (float*)(W + 155328512);
  int*   idx   = (int*)(W + 155332608);        //   131,072 B
  float* Sacc  = (float*)(W + 155463680);
  short* zerob = (short*)(W + 155463696);
  float* PART  = (float*)(W + 160000000);      // 8,388,608 B [2048][1024]
  float* PART2 = (float*)(W + 168388608);      //   262,144 B [64][1024]

  const dim3 blk(256);
  // conv3x3: 9 taps x 4 pairs = KIT 36
  #define IG3(A_, W_, B_, R_, O_, F_) \
    igemm_kernel<0,36,256,256,65536><<<dim3(256, 2), blk, 0, stream>>>( \
        A_, W_, B_, R_, O_, F_, nullptr, zerob)

  init0_kernel<<<dim3(1), dim3(64), 0, stream>>>(zerob);

  // -------- encoder --------
  conv1_kernel<<<dim3(4, NB), blk, 0, stream>>>(x, ew1, eb1, BIGA);
  w2t_kernel<<<dim3(2048), blk, 0, stream>>>(ew2, WT2);
  // conv2: 16 taps x 2 pairs = KIT 32
  igemm_kernel<2,32,128,128,32768><<<dim3(256, 2), blk, 0, stream>>>(
      BIGA, WT2, eb2, nullptr, X0, nullptr, nullptr, zerob);
  w3t_kernel<<<dim3(2304), blk, 0, stream>>>(ew3, WT3);
  IG3(X0, WT3, eb3, nullptr, X1, nullptr);                 // h3
  w3t_kernel<<<dim3(2304), blk, 0, stream>>>(er1aw, WT3);
  IG3(X1, WT3, er1ab, nullptr, X2, nullptr);
  w3t_kernel<<<dim3(2304), blk, 0, stream>>>(er1bw, WT3);
  IG3(X2, WT3, er1bb, X1, X0, nullptr);                    // h4
  w3t_kernel<<<dim3(2304), blk, 0, stream>>>(er2aw, WT3);
  IG3(X0, WT3, er2ab, nullptr, X1, nullptr);
  w3t_kernel<<<dim3(2304), blk, 0, stream>>>(er2bw, WT3);
  IG3(X1, WT3, er2bb, X0, X2, ZF32);                       // z (bf16 + fp32 dup)

  // -------- VQ / Blahut-Arimoto --------
  rownorm_kernel<<<dim3(KCB / 4), blk, 0, stream>>>(cb, cn, KCB);
  cbbf_kernel<<<dim3(1024), blk, 0, stream>>>(cb, CBB);
  cbt_kernel<<<dim3(1024), blk, 0, stream>>>(cb, CBT);
  initq_kernel<<<dim3(4), blk, 0, stream>>>(pi, logq, Sacc);
  // dist: K=256 -> 4 pairs
  igemm_kernel<4,4,256,256,0><<<dim3(256, 8), blk, 0, stream>>>(
      X2, CBB, cn, nullptr, DV, nullptr, nullptr, zerob);
  for (int i = 0; i < 5; ++i) {
    ba2_kernel<<<dim3(NROW / 16), blk, 0, stream>>>(
        (uint4*)DV, logq, PART, idx, (i == 4) ? 1 : 0);
    qred1_kernel<<<dim3(64), blk, 0, stream>>>(PART, PART2);
    qred2_kernel<<<dim3(4), blk, 0, stream>>>(PART2, qsum, logq);
  }
  ent_kernel<<<dim3(1), dim3(1024), 0, stream>>>(qsum, outf + 1572866);
  // pvq: K=1024 -> 16 pairs
  igemm_kernel<5,16,1024,1024,0><<<dim3(256, 2), blk, 0, stream>>>(
      DV, CBT, nullptr, nullptr, nullptr, ZF32, Sacc, zerob);
  scalars_kernel<<<dim3(1), dim3(1), 0, stream>>>(Sacc, outf + 1572864);
  gather16_kernel<<<dim3(8192), blk, 0, stream>>>(idx, CBB, X0);  // zq_hard NHWC bf16

  // -------- decoder --------
  w3t_kernel<<<dim3(2304), blk, 0, stream>>>(dr1aw, WT3);
  IG3(X0, WT3, dr1ab, nullptr, X1, nullptr);
  w3t_kernel<<<dim3(2304), blk, 0, stream>>>(dr1bw, WT3);
  IG3(X1, WT3, dr1bb, X0, X2, nullptr);                    // y1
  w3t_kernel<<<dim3(2304), blk, 0, stream>>>(dr2aw, WT3);
  IG3(X2, WT3, dr2ab, nullptr, X0, nullptr);
  w3t_kernel<<<dim3(2304), blk, 0, stream>>>(dr2bw, WT3);
  IG3(X0, WT3, dr2bb, X2, X1, nullptr);                    // y2
  w3t_kernel<<<dim3(2304), blk, 0, stream>>>(dw1, WT3);
  IG3(X1, WT3, db1, nullptr, X0, nullptr);                 // y3
  wtt2_kernel<<<dim3(2048), blk, 0, stream>>>(dwt2, WTT2);
  // convT2: 4 taps x 4 pairs = KIT 16
  igemm_kernel<3,16,256,256,32768><<<dim3(256, 4), blk, 0, stream>>>(
      X0, WTT2, dbt2, nullptr, BIGA, nullptr, nullptr, zerob);
  convt3_kernel<<<dim3(16, NB), blk, 0, stream>>>(BIGA, dwt3, dbt3, outf);
  #undef IG3
}

// Round 12
// 976.812 us; speedup vs baseline: 2.2804x; 1.0083x over previous
//
#include <hip/hip_runtime.h>
#include <math.h>

// ---------------- problem constants ----------------
#define NB   128
#define DC   256
#define SP   256
#define NROW 32768
#define KCB  1024
#define BETA_F 0.1f
#define EPSQ 1e-10f

typedef __attribute__((ext_vector_type(8))) short s16x8;
typedef __attribute__((ext_vector_type(4))) short s16x4;
typedef __attribute__((ext_vector_type(4))) float f32x4;

__device__ __forceinline__ short f2bf(float f) {
  unsigned u = __builtin_bit_cast(unsigned, f);
  unsigned r = (u + 0x7FFFu + ((u >> 16) & 1u)) >> 16;
  return (short)r;
}
__device__ __forceinline__ float bf2f(short s) {
  unsigned u = ((unsigned)(unsigned short)s) << 16;
  return __builtin_bit_cast(float, u);
}
__device__ __forceinline__ unsigned pack2(float a, float b) {
  return (unsigned)(unsigned short)f2bf(a) | ((unsigned)(unsigned short)f2bf(b) << 16);
}

// ========================= init: zero the zero-source buffer ===============
__global__ void init0_kernel(short* __restrict__ zerob)
{
  if (threadIdx.x < 8) zerob[threadIdx.x] = 0;
}

// ========================= weight transposes (fp32 -> bf16) =================
// all ten conv3x3 weights in one launch: blockIdx.y = weight slab
__global__ void w3t10_kernel(
    const float* __restrict__ w0, const float* __restrict__ w1,
    const float* __restrict__ w2, const float* __restrict__ w3,
    const float* __restrict__ w4, const float* __restrict__ w5,
    const float* __restrict__ w6, const float* __restrict__ w7,
    const float* __restrict__ w8, const float* __restrict__ w9,
    short* __restrict__ o)
{
  const float* ws[10] = {w0, w1, w2, w3, w4, w5, w6, w7, w8, w9};
  const float* w = ws[blockIdx.y];
  const int i = blockIdx.x * 256 + threadIdx.x;  // 589824
  const int ci = i & 255, co = (i >> 8) & 255, j = i >> 16;
  o[(size_t)blockIdx.y * 589824 + i] = f2bf(w[((size_t)(co * 256 + ci)) * 9 + j]);
}
__global__ void w2t_kernel(const float* __restrict__ w, short* __restrict__ o)
{
  const int i = blockIdx.x * 256 + threadIdx.x;  // 524288
  const int ci = i & 127, co = (i >> 7) & 255, j = i >> 15;
  o[i] = f2bf(w[((size_t)(co * 128 + ci)) * 16 + j]);
}
__global__ void wtt2_kernel(const float* __restrict__ w, short* __restrict__ o)
{
  const int i = blockIdx.x * 256 + threadIdx.x;  // 524288
  const int ci = i & 255, co = (i >> 8) & 127, j = (i >> 15) & 3, p = i >> 17;
  const int po = p >> 1, pq = p & 1, a = j >> 1, b2 = j & 1;
  const int kh = (1 - po) + 2 * a, kw = (1 - pq) + 2 * b2;
  o[i] = f2bf(w[((size_t)(ci * 128 + co)) * 16 + kh * 4 + kw]);
}
__global__ void cbbf_kernel(const float* __restrict__ cb, short* __restrict__ o)
{
  const int i = blockIdx.x * 256 + threadIdx.x;  // 262144
  o[i] = f2bf(cb[i]);
}
__global__ void cbt_kernel(const float* __restrict__ cb, short* __restrict__ o)
{
  const int i = blockIdx.x * 256 + threadIdx.x;  // 262144
  const int d = i >> 10, k = i & 1023;
  o[i] = f2bf(cb[(size_t)k * 256 + d]);
}

// ========================= conv1: 3->128, 4x4 s2, 64->32, out NHWC bf16 =====
__global__ __launch_bounds__(256) void conv1_kernel(
    const float* __restrict__ x, const float* __restrict__ w,
    const float* __restrict__ bias, short* __restrict__ out)
{
  __shared__ float li[3][34][34];
  const int tid = threadIdx.x;
  const int tile = blockIdx.x;          // 0..3 quadrant of 32x32 output
  const int b = blockIdx.y;
  const int qy = tile >> 1, qx = tile & 1;
  const int ihlo = qy * 32 - 1, iwlo = qx * 32 - 1;
  for (int ci = 0; ci < 3; ++ci)
    for (int s = tid; s < 1156; s += 256) {
      const int r = s / 34, c = s - r * 34;
      const int ih = ihlo + r, iw = iwlo + c;
      float v = 0.f;
      if ((unsigned)ih < 64u && (unsigned)iw < 64u)
        v = x[((size_t)(b * 3 + ci) * 64 + ih) * 64 + iw];
      li[ci][r][c] = v;
    }
  __syncthreads();

  const int wv = tid >> 6, l = tid & 63;
  const int co0 = 2 * l, co1 = 2 * l + 1;
  float w0[48], w1[48];
#pragma unroll
  for (int j = 0; j < 48; ++j) {
    w0[j] = w[(size_t)co0 * 48 + j];
    w1[j] = w[(size_t)co1 * 48 + j];
  }
  const float b0 = bias[co0], b1 = bias[co1];

  for (int pass = 0; pass < 64; ++pass) {
    const int pix = pass * 4 + wv;            // 0..255
    const int py = pix >> 4, px = pix & 15;
    float s0 = b0, s1 = b1;
#pragma unroll
    for (int ci = 0; ci < 3; ++ci)
#pragma unroll
      for (int kh = 0; kh < 4; ++kh)
#pragma unroll
        for (int kw = 0; kw < 4; ++kw) {
          const int j = ci * 16 + kh * 4 + kw;
          const float v = li[ci][2 * py + kh][2 * px + kw];  // wave-broadcast
          s0 = fmaf(v, w0[j], s0);
          s1 = fmaf(v, w1[j], s1);
        }
    s0 = fmaxf(s0, 0.f);
    s1 = fmaxf(s1, 0.f);
    const int oh = qy * 16 + py, ow = qx * 16 + px;
    ((unsigned*)(out + ((size_t)b * 1024 + oh * 32 + ow) * 128))[l] = pack2(s0, s1);
  }
}

// ========================= MFMA implicit GEMM (128x128 tile, BK=32) =========
// 4 waves as 2x2; wave tile 64x64 = acc[4][4]; A and B both staged in LDS.
// 3 LDS buffers, depth-2 prefetch, counted vmcnt(4) + raw s_barrier per step.
template<int MODE, int KIT, int AK, int KPN, int TS>
__global__ __launch_bounds__(256) void igemm_kernel(
    const short* __restrict__ Abuf, const short* __restrict__ Bw,
    const float* __restrict__ bias, const short* __restrict__ res,
    short* __restrict__ outb, float* __restrict__ outf32,
    float* __restrict__ sacc, const short* __restrict__ zerob)
{
  __shared__ __align__(16) short Alds[3][8192];   // per buf: [A 4096 | B 4096]
  __shared__ float red[4];
  const int tid = threadIdx.x;
  const int wv = tid >> 6, l = tid & 63;
  const int wm = wv >> 1, wn = wv & 1;
  const int lcol = l & 15, lk = l >> 4;
  const int m0 = blockIdx.x * 128;

  int ncol0 = 0, po = 0, pq = 0;
  const short* Bp = Bw;
  if constexpr (MODE == 3) {
    po = blockIdx.y >> 1; pq = blockIdx.y & 1;
    Bp += (size_t)blockIdx.y * 131072;            // per-parity slab
  } else {
    ncol0 = blockIdx.y * 128;
    Bp += (size_t)ncol0 * KPN;
  }

  const int cpos = l & 3;
  const int rl_[2] = { (wv * 2) * 16 + (l >> 2), (wv * 2 + 1) * 16 + (l >> 2) };
  const int cc_[2] = { cpos ^ ((rl_[0] >> 1) & 3), cpos ^ ((rl_[1] >> 1) & 3) };

  f32x4 acc[4][4];
#pragma unroll
  for (int i = 0; i < 4; ++i)
#pragma unroll
    for (int j = 0; j < 4; ++j) acc[i][j] = (f32x4){0.f, 0.f, 0.f, 0.f};

  const int aoff_base = lcol * 32 + ((lk ^ ((lcol >> 1) & 3)) * 8);

  auto STAGE = [&](int it, int bufc) {
    int jj, kk;
    if constexpr (MODE == 0 || MODE == 3) { jj = it >> 3; kk = it & 7; }
    else if constexpr (MODE == 2)         { jj = it >> 2; kk = it & 3; }
    else                                  { jj = 0; kk = it; }
    const int choff = kk * 32;
    (void)jj;
#pragma unroll
    for (int q = 0; q < 2; ++q) {
      const int rl = rl_[q], cc = cc_[q];
      const int m = m0 + rl;
      const short* srcA;
      if constexpr (MODE == 0) {
        const int q3 = jj / 3;
        const int ih = ((m >> 4) & 15) + q3 - 1, iw = (m & 15) + (jj - q3 * 3) - 1;
        const bool v = ((unsigned)ih < 16u) & ((unsigned)iw < 16u);
        srcA = v ? Abuf + (size_t)((m & ~255) + ih * 16 + iw) * AK + choff + cc * 8 : zerob;
      } else if constexpr (MODE == 2) {
        const int ih = 2 * ((m >> 4) & 15) + (jj >> 2) - 1, iw = 2 * (m & 15) + (jj & 3) - 1;
        const bool v = ((unsigned)ih < 32u) & ((unsigned)iw < 32u);
        srcA = v ? Abuf + (size_t)((m >> 8) * 1024 + ih * 32 + iw) * AK + choff + cc * 8 : zerob;
      } else if constexpr (MODE == 3) {
        const int ih = ((m >> 4) & 15) + po - (jj >> 1), iw = (m & 15) + pq - (jj & 1);
        const bool v = ((unsigned)ih < 16u) & ((unsigned)iw < 16u);
        srcA = v ? Abuf + (size_t)((m & ~255) + ih * 16 + iw) * AK + choff + cc * 8 : zerob;
      } else {
        srcA = Abuf + (size_t)m * AK + choff + cc * 8;
      }
      __builtin_amdgcn_global_load_lds(
          (const __attribute__((address_space(1))) void*)srcA,
          (__attribute__((address_space(3))) void*)(&Alds[bufc][(wv * 2 + q) * 512]),
          16, 0, 0);
      const short* srcB = Bp + (size_t)jj * TS + (size_t)rl * KPN + choff + cc * 8;
      __builtin_amdgcn_global_load_lds(
          (const __attribute__((address_space(1))) void*)srcB,
          (__attribute__((address_space(3))) void*)(&Alds[bufc][4096 + (wv * 2 + q) * 512]),
          16, 0, 0);
    }
  };

  auto COMPUTE = [&](int bufc) {
    s16x8 a[4], b[4];
#pragma unroll
    for (int ms = 0; ms < 4; ++ms)
      a[ms] = *(const s16x8*)&Alds[bufc][wm * 2048 + ms * 512 + aoff_base];
#pragma unroll
    for (int ns = 0; ns < 4; ++ns)
      b[ns] = *(const s16x8*)&Alds[bufc][4096 + wn * 2048 + ns * 512 + aoff_base];
#pragma unroll
    for (int ms = 0; ms < 4; ++ms)
#pragma unroll
      for (int ns = 0; ns < 4; ++ns)
        acc[ms][ns] = __builtin_amdgcn_mfma_f32_16x16x32_bf16(a[ms], b[ns], acc[ms][ns], 0, 0, 0);
  };

  // depth-2 prefetch, 3 buffers, counted vmcnt
  STAGE(0, 0);
  STAGE(1, 1);
  int buf = 0, nbuf = 2;
#pragma unroll 1
  for (int it = 0; it < KIT; ++it) {
    if (it + 1 < KIT) {
      asm volatile("s_waitcnt vmcnt(4)" ::: "memory");   // stage it landed; it+1 in flight
    } else {
      asm volatile("s_waitcnt vmcnt(0)" ::: "memory");   // last stage must land
    }
    __builtin_amdgcn_s_barrier();
    __builtin_amdgcn_sched_barrier(0);
    if (it + 2 < KIT) STAGE(it + 2, nbuf);
    __builtin_amdgcn_s_setprio(1);
    COMPUTE(buf);
    __builtin_amdgcn_s_setprio(0);
    buf = (buf == 2) ? 0 : buf + 1;
    nbuf = (nbuf == 2) ? 0 : nbuf + 1;
  }

  // ---------------- epilogue ----------------
  const int r4 = lk * 4;
  float ls = 0.f;
#pragma unroll
  for (int ms = 0; ms < 4; ++ms) {
#pragma unroll
    for (int ns = 0; ns < 4; ++ns) {
      const int n_l = wn * 64 + ns * 16 + lcol;
      const int n_g = ncol0 + n_l;
#pragma unroll
      for (int e = 0; e < 4; ++e) {
        const int m = m0 + wm * 64 + ms * 16 + r4 + e;
        if constexpr (MODE == 4) {
          const float val = bias[n_g] - 2.f * acc[ms][ns][e];
          outb[(size_t)m * 1024 + n_g] = f2bf(val);
        } else if constexpr (MODE == 5) {
          const float d = acc[ms][ns][e] - outf32[(size_t)m * 256 + n_g];
          ls = fmaf(d, d, ls);
        } else if constexpr (MODE == 3) {
          const float val = fmaxf(acc[ms][ns][e] + bias[n_l], 0.f);
          const int orow = (m & ~255) * 4 + (2 * ((m >> 4) & 15) + po) * 32 + (2 * (m & 15) + pq);
          outb[(size_t)orow * 128 + n_l] = f2bf(val);
        } else {
          float val = acc[ms][ns][e] + bias[n_g];
          if (res) val += bf2f(res[(size_t)m * 256 + n_g]);
          val = fmaxf(val, 0.f);
          outb[(size_t)m * 256 + n_g] = f2bf(val);
          if (outf32) outf32[(size_t)m * 256 + n_g] = val;
        }
      }
    }
  }
  if constexpr (MODE == 5) {
#pragma unroll
    for (int o = 32; o > 0; o >>= 1) ls += __shfl_xor(ls, o);
    if (l == 0) red[wv] = ls;
    __syncthreads();
    if (tid == 0) atomicAdd(sacc, red[0] + red[1] + red[2] + red[3]);
  }
}

// ========================= VQ block =========================================
__global__ __launch_bounds__(256) void rownorm_kernel(
    const float* __restrict__ a, float* __restrict__ nrm, int rows)
{
  const int wv = threadIdx.x >> 6, lane = threadIdx.x & 63;
  const int r = blockIdx.x * 4 + wv;
  if (r >= rows) return;
  const float* p = a + (size_t)r * DC;
  float s = 0.f;
#pragma unroll
  for (int i = 0; i < 4; ++i) { float v = p[lane + 64 * i]; s = fmaf(v, v, s); }
#pragma unroll
  for (int o = 32; o > 0; o >>= 1) s += __shfl_xor(s, o);
  if (lane == 0) nrm[r] = s;
}

__global__ void initq_kernel(const float* __restrict__ pi, float* __restrict__ logq,
                             float* __restrict__ Sacc)
{
  const int k = blockIdx.x * 256 + threadIdx.x;
  logq[k] = logf(fmaxf(pi[k], EPSQ));
  if (k == 0) *Sacc = 0.f;
}

// one BA iteration over bf16 DV; register-accumulated Q, uint4 row I/O.
__global__ __launch_bounds__(256) void ba2_kernel(
    uint4* __restrict__ DV, const float* __restrict__ logq,
    float* __restrict__ part, int* __restrict__ idxout, int storeP)
{
  __shared__ float qp[4][1024];
  const int tid = threadIdx.x;
  const int wv = tid >> 6, lane = tid & 63;

  float lq[16];
  {
    const float4* lq4 = (const float4*)logq;   // 256 float4
#pragma unroll
    for (int h = 0; h < 2; ++h) {
      const float4 a = lq4[h * 128 + 2 * lane];
      const float4 b = lq4[h * 128 + 2 * lane + 1];
      lq[h * 8 + 0] = a.x; lq[h * 8 + 1] = a.y; lq[h * 8 + 2] = a.z; lq[h * 8 + 3] = a.w;
      lq[h * 8 + 4] = b.x; lq[h * 8 + 5] = b.y; lq[h * 8 + 6] = b.z; lq[h * 8 + 7] = b.w;
    }
  }

  float qacc[16];
#pragma unroll
  for (int j = 0; j < 16; ++j) qacc[j] = 0.f;

  const int n0 = blockIdx.x * 16;
  for (int rr = 0; rr < 4; ++rr) {
    const int n = n0 + wv * 4 + rr;
    uint4* rowp = DV + (size_t)n * 128;        // 128 uint4 per row
    uint4 w[2];
    w[0] = rowp[lane];
    w[1] = rowp[64 + lane];
    float lv[16];
    float mx = -1e30f;
#pragma unroll
    for (int h = 0; h < 2; ++h) {
      const unsigned* u = (const unsigned*)&w[h];
#pragma unroll
      for (int p = 0; p < 4; ++p) {
        lv[h * 8 + 2 * p]     = lq[h * 8 + 2 * p]     - BETA_F * bf2f((short)(u[p] & 0xFFFFu));
        lv[h * 8 + 2 * p + 1] = lq[h * 8 + 2 * p + 1] - BETA_F * bf2f((short)(u[p] >> 16));
      }
    }
#pragma unroll
    for (int j = 0; j < 16; ++j) mx = fmaxf(mx, lv[j]);
#pragma unroll
    for (int o = 32; o > 0; o >>= 1) mx = fmaxf(mx, __shfl_xor(mx, o));
    float e[16];
    float s = 0.f;
#pragma unroll
    for (int j = 0; j < 16; ++j) { e[j] = __expf(lv[j] - mx); s += e[j]; }
#pragma unroll
    for (int o = 32; o > 0; o >>= 1) s += __shfl_xor(s, o);
    const float inv = 1.f / s;
#pragma unroll
    for (int j = 0; j < 16; ++j) qacc[j] += e[j] * inv;

    if (storeP) {
#pragma unroll
      for (int h = 0; h < 2; ++h) {
        unsigned* u = (unsigned*)&w[h];
#pragma unroll
        for (int p = 0; p < 4; ++p)
          u[p] = pack2(e[h * 8 + 2 * p] * inv, e[h * 8 + 2 * p + 1] * inv);
      }
      rowp[lane] = w[0];
      rowp[64 + lane] = w[1];
      float bv = lv[0]; int bi = 8 * lane;
#pragma unroll
      for (int h = 0; h < 2; ++h)
#pragma unroll
        for (int j = 0; j < 8; ++j) {
          const int k = h * 512 + 8 * lane + j;
          const float v = lv[h * 8 + j];
          if (v > bv || (v == bv && k < bi)) { bv = v; bi = k; }
        }
#pragma unroll
      for (int o = 32; o > 0; o >>= 1) {
        const float ov = __shfl_xor(bv, o);
        const int oi = __shfl_xor(bi, o);
        if (ov > bv || (ov == bv && oi < bi)) { bv = ov; bi = oi; }
      }
      if (lane == 0) idxout[n] = bi;
    }
  }
  __syncthreads();
#pragma unroll
  for (int h = 0; h < 2; ++h)
#pragma unroll
    for (int j = 0; j < 8; ++j)
      qp[wv][h * 512 + 8 * lane + j] = qacc[h * 8 + j];
  __syncthreads();
  for (int k = tid; k < 1024; k += 256) {
    part[(size_t)blockIdx.x * 1024 + k] = qp[0][k] + qp[1][k] + qp[2][k] + qp[3][k];
  }
}

// reduce stage 1: 64 blocks; block b sums PART rows [32b,32b+32) -> PART2[b][1024]
__global__ __launch_bounds__(256) void qred1_kernel(
    const float* __restrict__ part, float* __restrict__ part2)
{
  const int b = blockIdx.x;
  const int tid = threadIdx.x;
  const float* p = part + (size_t)b * 32 * 1024;
#pragma unroll
  for (int j = 0; j < 4; ++j) {
    const int k = tid + j * 256;
    float s = 0.f;
#pragma unroll
    for (int r = 0; r < 32; ++r) s += p[(size_t)r * 1024 + k];
    part2[(size_t)b * 1024 + k] = s;
  }
}

// reduce stage 2: 4 blocks x 256; sum 64 entries/column -> qsum, logq
__global__ __launch_bounds__(256) void qred2_kernel(
    const float* __restrict__ part2, float* __restrict__ qsum, float* __restrict__ logq)
{
  const int k = blockIdx.x * 256 + threadIdx.x;
  float s = 0.f;
#pragma unroll
  for (int r = 0; r < 64; ++r) s += part2[(size_t)r * 1024 + k];
  qsum[k] = s;
  logq[k] = logf(fmaxf(s * (1.f / 32768.f), EPSQ));
}

__global__ __launch_bounds__(1024) void ent_kernel(
    const float* __restrict__ qsum, float* __restrict__ out_ent)
{
  const int k = threadIdx.x;
  const float q = fmaxf(qsum[k] * (1.f / 32768.f), EPSQ);
  float v = q * logf(q);
#pragma unroll
  for (int o = 32; o > 0; o >>= 1) v += __shfl_xor(v, o);
  __shared__ float red[16];
  const int wv = k >> 6, lane = k & 63;
  if (lane == 0) red[wv] = v;
  __syncthreads();
  if (k == 0) {
    float s = 0.f;
    for (int i = 0; i < 16; ++i) s += red[i];
    *out_ent = 0.01f * s;
  }
}

__global__ void scalars_kernel(const float* __restrict__ S, float* __restrict__ out2)
{
  const float s = *S;
  out2[0] = 0.25f * s / 8388608.f;
  out2[1] = s / 8388608.f;
}

__global__ void gather16_kernel(const int* __restrict__ idx, const short* __restrict__ cbb,
                                short* __restrict__ out)
{
  const int t = blockIdx.x * 256 + threadIdx.x;
  const int m = t >> 6, d4 = (t & 63) * 4;
  *(s16x4*)(out + (size_t)m * 256 + d4) = *(const s16x4*)(cbb + (size_t)idx[m] * 256 + d4);
}

// ========================= convT3: 128->3, 32->64 ==========================
__global__ __launch_bounds__(256) void convt3_kernel(
    const short* __restrict__ in, const float* __restrict__ w,
    const float* __restrict__ bias, float* __restrict__ out)
{
  __shared__ __align__(16) short li[100 * 128];  // [pix][slot], slot = ch ^ (pix&15)
  __shared__ float lw[6144];
  const int tid = threadIdx.x;
  const int tile = blockIdx.x;          // 0..15
  const int b = blockIdx.y;
  const int ty0 = (tile >> 2) * 16, tx0 = (tile & 3) * 16;
  const int iy0 = (tile >> 2) * 8 - 1, ix0 = (tile & 3) * 8 - 1;
  for (int s = tid; s < 1600; s += 256) {
    const int pix = s >> 4, ch = s & 15;
    const int r = pix / 10, c = pix - r * 10;
    const int ih = iy0 + r, iw = ix0 + c;
    s16x8 v = {0, 0, 0, 0, 0, 0, 0, 0};
    if ((unsigned)ih < 32u && (unsigned)iw < 32u)
      v = *(const s16x8*)(in + ((size_t)b * 1024 + ih * 32 + iw) * 128 + ch * 8);
    const int slot = ch ^ (pix & 15);
    *(s16x8*)&li[pix * 128 + slot * 8] = v;
  }
  for (int s = tid; s < 6144; s += 256) lw[s] = w[s];
  __syncthreads();
  const int ty = tid >> 4, tx = tid & 15;
  const int oh2 = ty0 + ty, ow2 = tx0 + tx;
  const int kh0 = (oh2 + 1) & 1, kw0 = (ow2 + 1) & 1;
  const int ih0 = (oh2 + 1 - kh0) >> 1, iw0 = (ow2 + 1 - kw0) >> 1;
  const int rl0 = ih0 - iy0, cl0 = iw0 - ix0;
  const int p00 = rl0 * 10 + cl0, p01 = p00 - 1, p10 = p00 - 10, p11 = p00 - 11;
  const int wi00 = kh0 * 4 + kw0, wi01 = wi00 + 2, wi10 = wi00 + 8, wi11 = wi00 + 10;
  float acc0 = 0.f, acc1 = 0.f, acc2 = 0.f;
  for (int ch = 0; ch < 16; ++ch) {
    const s16x8 v00 = *(const s16x8*)&li[p00 * 128 + (ch ^ (p00 & 15)) * 8];
    const s16x8 v01 = *(const s16x8*)&li[p01 * 128 + (ch ^ (p01 & 15)) * 8];
    const s16x8 v10 = *(const s16x8*)&li[p10 * 128 + (ch ^ (p10 & 15)) * 8];
    const s16x8 v11 = *(const s16x8*)&li[p11 * 128 + (ch ^ (p11 & 15)) * 8];
#pragma unroll
    for (int e = 0; e < 8; ++e) {
      const int ci = ch * 8 + e;
      const float* wr = &lw[ci * 48];
      const float f00 = bf2f(v00[e]), f01 = bf2f(v01[e]);
      const float f10 = bf2f(v10[e]), f11 = bf2f(v11[e]);
      acc0 = fmaf(wr[wi00], f00, fmaf(wr[wi01], f01, fmaf(wr[wi10], f10, fmaf(wr[wi11], f11, acc0))));
      acc1 = fmaf(wr[16 + wi00], f00, fmaf(wr[16 + wi01], f01, fmaf(wr[16 + wi10], f10, fmaf(wr[16 + wi11], f11, acc1))));
      acc2 = fmaf(wr[32 + wi00], f00, fmaf(wr[32 + wi01], f01, fmaf(wr[32 + wi10], f10, fmaf(wr[32 + wi11], f11, acc2))));
    }
  }
  const size_t ob = ((size_t)(b * 3) * 64 + oh2) * 64 + ow2;
  out[ob] = acc0 + bias[0];
  out[ob + 4096] = acc1 + bias[1];
  out[ob + 8192] = acc2 + bias[2];
}

// =====================================================================
extern "C" void kernel_launch(void* const* d_in, const int* in_sizes, int n_in,
                              void* d_out, int out_size, void* d_ws, size_t ws_size,
                              hipStream_t stream)
{
  const float* x     = (const float*)d_in[0];
  const float* ew1   = (const float*)d_in[1];
  const float* eb1   = (const float*)d_in[2];
  const float* ew2   = (const float*)d_in[3];
  const float* eb2   = (const float*)d_in[4];
  const float* ew3   = (const float*)d_in[5];
  const float* eb3   = (const float*)d_in[6];
  const float* er1aw = (const float*)d_in[7];
  const float* er1ab = (const float*)d_in[8];
  const float* er1bw = (const float*)d_in[9];
  const float* er1bb = (const float*)d_in[10];
  const float* er2aw = (const float*)d_in[11];
  const float* er2ab = (const float*)d_in[12];
  const float* er2bw = (const float*)d_in[13];
  const float* er2bb = (const float*)d_in[14];
  const float* cb    = (const float*)d_in[15];
  const float* pi    = (const float*)d_in[16];
  const float* dr1aw = (const float*)d_in[17];
  const float* dr1ab = (const float*)d_in[18];
  const float* dr1bw = (const float*)d_in[19];
  const float* dr1bb = (const float*)d_in[20];
  const float* dr2aw = (const float*)d_in[21];
  const float* dr2ab = (const float*)d_in[22];
  const float* dr2bw = (const float*)d_in[23];
  const float* dr2bb = (const float*)d_in[24];
  const float* dw1   = (const float*)d_in[25];
  const float* db1   = (const float*)d_in[26];
  const float* dwt2  = (const float*)d_in[27];
  const float* dbt2  = (const float*)d_in[28];
  const float* dwt3  = (const float*)d_in[29];
  const float* dbt3  = (const float*)d_in[30];

  float* outf = (float*)d_out;

  // workspace layout (bytes), ~182 MB of 256 MiB
  char* W = (char*)d_ws;
  short* BIGA  = (short*)W;                    // 33.5MB: conv1-out -> ZF32 -> convt2-out
  float* ZF32  = (float*)W;
  short* DV    = (short*)(W + 33554432);       // 67MB bf16 [32768][1024]: dv -> P
  short* X0    = (short*)(W + 100663296);      // 16.7MB each
  short* X1    = (short*)(W + 117440512);
  short* X2    = (short*)(W + 134217728);
  short* WT2   = (short*)(W + 152174592);      // 1,048,576 B
  short* WTT2  = (short*)(W + 153223168);      // 1,048,576 B
  short* CBB   = (short*)(W + 154271744);      //   524,288 B
  short* CBT   = (short*)(W + 154796032);      //   524,288 B
  float* cn    = (float*)(W + 155320320);      //     4,096 B
  float* qsum  = (float*)(W + 155324416);
  float* logq  = (float*)(W + 155328512);
  int*   idx   = (int*)(W + 155332608);        //   131,072 B
  float* Sacc  = (float*)(W + 155463680);
  short* zerob = (short*)(W + 155463696);
  float* PART  = (float*)(W + 160000000);      // 8,388,608 B [2048][1024]
  float* PART2 = (float*)(W + 168388608);      //   262,144 B [64][1024]
  short* WT3S  = (short*)(W + 168650752);      // 10 x 1,179,648 B = 11,796,480 B

  const dim3 blk(256);
  #define WTSLAB(i) (WT3S + (size_t)(i) * 589824)
  // conv3x3: MODE 0, KIT 72 (32-chunk stages), grid (256, 2)
  #define IG3(A_, Wi_, B_, R_, O_, F_) \
    igemm_kernel<0,72,256,256,65536><<<dim3(256, 2), blk, 0, stream>>>( \
        A_, WTSLAB(Wi_), B_, R_, O_, F_, nullptr, zerob)

  init0_kernel<<<dim3(1), dim3(64), 0, stream>>>(zerob);
  // all ten conv3x3 weight transposes in one launch
  w3t10_kernel<<<dim3(2304, 10), blk, 0, stream>>>(
      ew3, er1aw, er1bw, er2aw, er2bw, dr1aw, dr1bw, dr2aw, dr2bw, dw1, WT3S);

  // -------- encoder --------
  conv1_kernel<<<dim3(4, NB), blk, 0, stream>>>(x, ew1, eb1, BIGA);
  w2t_kernel<<<dim3(2048), blk, 0, stream>>>(ew2, WT2);
  igemm_kernel<2,64,128,128,32768><<<dim3(256, 2), blk, 0, stream>>>(
      BIGA, WT2, eb2, nullptr, X0, nullptr, nullptr, zerob);
  IG3(X0, 0, eb3, nullptr, X1, nullptr);                   // h3
  IG3(X1, 1, er1ab, nullptr, X2, nullptr);
  IG3(X2, 2, er1bb, X1, X0, nullptr);                      // h4
  IG3(X0, 3, er2ab, nullptr, X1, nullptr);
  IG3(X1, 4, er2bb, X0, X2, ZF32);                         // z (bf16 + fp32 dup)

  // -------- VQ / Blahut-Arimoto --------
  rownorm_kernel<<<dim3(KCB / 4), blk, 0, stream>>>(cb, cn, KCB);
  cbbf_kernel<<<dim3(1024), blk, 0, stream>>>(cb, CBB);
  cbt_kernel<<<dim3(1024), blk, 0, stream>>>(cb, CBT);
  initq_kernel<<<dim3(4), blk, 0, stream>>>(pi, logq, Sacc);
  igemm_kernel<4,8,256,256,0><<<dim3(256, 8), blk, 0, stream>>>(
      X2, CBB, cn, nullptr, DV, nullptr, nullptr, zerob);
  for (int i = 0; i < 5; ++i) {
    ba2_kernel<<<dim3(NROW / 16), blk, 0, stream>>>(
        (uint4*)DV, logq, PART, idx, (i == 4) ? 1 : 0);
    qred1_kernel<<<dim3(64), blk, 0, stream>>>(PART, PART2);
    qred2_kernel<<<dim3(4), blk, 0, stream>>>(PART2, qsum, logq);
  }
  ent_kernel<<<dim3(1), dim3(1024), 0, stream>>>(qsum, outf + 1572866);
  igemm_kernel<5,32,1024,1024,0><<<dim3(256, 2), blk, 0, stream>>>(
      DV, CBT, nullptr, nullptr, nullptr, ZF32, Sacc, zerob);
  scalars_kernel<<<dim3(1), dim3(1), 0, stream>>>(Sacc, outf + 1572864);
  gather16_kernel<<<dim3(8192), blk, 0, stream>>>(idx, CBB, X0);  // zq_hard NHWC bf16

  // -------- decoder --------
  IG3(X0, 5, dr1ab, nullptr, X1, nullptr);
  IG3(X1, 6, dr1bb, X0, X2, nullptr);                      // y1
  IG3(X2, 7, dr2ab, nullptr, X0, nullptr);
  IG3(X0, 8, dr2bb, X2, X1, nullptr);                      // y2
  IG3(X1, 9, db1, nullptr, X0, nullptr);                   // y3
  wtt2_kernel<<<dim3(2048), blk, 0, stream>>>(dwt2, WTT2);
  igemm_kernel<3,32,256,256,32768><<<dim3(256, 4), blk, 0, stream>>>(
      X0, WTT2, dbt2, nullptr, BIGA, nullptr, nullptr, zerob);
  convt3_kernel<<<dim3(16, NB), blk, 0, stream>>>(BIGA, dwt3, dbt3, outf);
  #undef IG3
  #undef WTSLAB
}

// Round 13
// 965.895 us; speedup vs baseline: 2.3062x; 1.0113x over previous
//
#include <hip/hip_runtime.h>
#include <math.h>

// ---------------- problem constants ----------------
#define NB   128
#define DC   256
#define SP   256
#define NROW 32768
#define KCB  1024
#define BETA_F 0.1f
#define EPSQ 1e-10f

typedef __attribute__((ext_vector_type(8))) short s16x8;
typedef __attribute__((ext_vector_type(4))) short s16x4;
typedef __attribute__((ext_vector_type(4))) float f32x4;

__device__ __forceinline__ short f2bf(float f) {
  unsigned u = __builtin_bit_cast(unsigned, f);
  unsigned r = (u + 0x7FFFu + ((u >> 16) & 1u)) >> 16;
  return (short)r;
}
__device__ __forceinline__ float bf2f(short s) {
  unsigned u = ((unsigned)(unsigned short)s) << 16;
  return __builtin_bit_cast(float, u);
}
__device__ __forceinline__ unsigned pack2(float a, float b) {
  return (unsigned)(unsigned short)f2bf(a) | ((unsigned)(unsigned short)f2bf(b) << 16);
}

// ========================= init: zero zero-buffer + ticket =================
__global__ void init0_kernel(short* __restrict__ zerob, unsigned* __restrict__ ticket)
{
  if (threadIdx.x < 8) zerob[threadIdx.x] = 0;
  if (threadIdx.x == 0) *ticket = 0u;
}

// ========================= weight transposes (fp32 -> bf16) =================
__global__ void w3t10_kernel(
    const float* __restrict__ w0, const float* __restrict__ w1,
    const float* __restrict__ w2, const float* __restrict__ w3,
    const float* __restrict__ w4, const float* __restrict__ w5,
    const float* __restrict__ w6, const float* __restrict__ w7,
    const float* __restrict__ w8, const float* __restrict__ w9,
    short* __restrict__ o)
{
  const float* ws[10] = {w0, w1, w2, w3, w4, w5, w6, w7, w8, w9};
  const float* w = ws[blockIdx.y];
  const int i = blockIdx.x * 256 + threadIdx.x;  // 589824
  const int ci = i & 255, co = (i >> 8) & 255, j = i >> 16;
  o[(size_t)blockIdx.y * 589824 + i] = f2bf(w[((size_t)(co * 256 + ci)) * 9 + j]);
}
__global__ void w2t_kernel(const float* __restrict__ w, short* __restrict__ o)
{
  const int i = blockIdx.x * 256 + threadIdx.x;  // 524288
  const int ci = i & 127, co = (i >> 7) & 255, j = i >> 15;
  o[i] = f2bf(w[((size_t)(co * 128 + ci)) * 16 + j]);
}
__global__ void wtt2_kernel(const float* __restrict__ w, short* __restrict__ o)
{
  const int i = blockIdx.x * 256 + threadIdx.x;  // 524288
  const int ci = i & 255, co = (i >> 8) & 127, j = (i >> 15) & 3, p = i >> 17;
  const int po = p >> 1, pq = p & 1, a = j >> 1, b2 = j & 1;
  const int kh = (1 - po) + 2 * a, kw = (1 - pq) + 2 * b2;
  o[i] = f2bf(w[((size_t)(ci * 128 + co)) * 16 + kh * 4 + kw]);
}
__global__ void cbbf_kernel(const float* __restrict__ cb, short* __restrict__ o)
{
  const int i = blockIdx.x * 256 + threadIdx.x;  // 262144
  o[i] = f2bf(cb[i]);
}
__global__ void cbt_kernel(const float* __restrict__ cb, short* __restrict__ o)
{
  const int i = blockIdx.x * 256 + threadIdx.x;  // 262144
  const int d = i >> 10, k = i & 1023;
  o[i] = f2bf(cb[(size_t)k * 256 + d]);
}

// ========================= conv1: 3->128, 4x4 s2, 64->32, out NHWC bf16 =====
__global__ __launch_bounds__(256) void conv1_kernel(
    const float* __restrict__ x, const float* __restrict__ w,
    const float* __restrict__ bias, short* __restrict__ out)
{
  __shared__ float li[3][34][34];
  const int tid = threadIdx.x;
  const int tile = blockIdx.x;          // 0..3 quadrant of 32x32 output
  const int b = blockIdx.y;
  const int qy = tile >> 1, qx = tile & 1;
  const int ihlo = qy * 32 - 1, iwlo = qx * 32 - 1;
  for (int ci = 0; ci < 3; ++ci)
    for (int s = tid; s < 1156; s += 256) {
      const int r = s / 34, c = s - r * 34;
      const int ih = ihlo + r, iw = iwlo + c;
      float v = 0.f;
      if ((unsigned)ih < 64u && (unsigned)iw < 64u)
        v = x[((size_t)(b * 3 + ci) * 64 + ih) * 64 + iw];
      li[ci][r][c] = v;
    }
  __syncthreads();

  const int wv = tid >> 6, l = tid & 63;
  const int co0 = 2 * l, co1 = 2 * l + 1;
  float w0[48], w1[48];
#pragma unroll
  for (int j = 0; j < 48; ++j) {
    w0[j] = w[(size_t)co0 * 48 + j];
    w1[j] = w[(size_t)co1 * 48 + j];
  }
  const float b0 = bias[co0], b1 = bias[co1];

  for (int pass = 0; pass < 64; ++pass) {
    const int pix = pass * 4 + wv;            // 0..255
    const int py = pix >> 4, px = pix & 15;
    float s0 = b0, s1 = b1;
#pragma unroll
    for (int ci = 0; ci < 3; ++ci)
#pragma unroll
      for (int kh = 0; kh < 4; ++kh)
#pragma unroll
        for (int kw = 0; kw < 4; ++kw) {
          const int j = ci * 16 + kh * 4 + kw;
          const float v = li[ci][2 * py + kh][2 * px + kw];  // wave-broadcast
          s0 = fmaf(v, w0[j], s0);
          s1 = fmaf(v, w1[j], s1);
        }
    s0 = fmaxf(s0, 0.f);
    s1 = fmaxf(s1, 0.f);
    const int oh = qy * 16 + py, ow = qx * 16 + px;
    ((unsigned*)(out + ((size_t)b * 1024 + oh * 32 + ow) * 128))[l] = pack2(s0, s1);
  }
}

// ========================= MFMA implicit GEMM (128x128 tile, BK=32) =========
// 4 waves as 2x2; wave tile 64x64 = acc[4][4]; A and B both staged in LDS.
// 4 LDS buffers, depth-3 prefetch, counted vmcnt(8) + raw s_barrier per step.
template<int MODE, int KIT, int AK, int KPN, int TS>
__global__ __launch_bounds__(256) void igemm_kernel(
    const short* __restrict__ Abuf, const short* __restrict__ Bw,
    const float* __restrict__ bias, const short* __restrict__ res,
    short* __restrict__ outb, float* __restrict__ outf32,
    float* __restrict__ sacc, const short* __restrict__ zerob)
{
  __shared__ __align__(16) short Alds[4][8192];   // per buf: [A 4096 | B 4096]
  __shared__ float red[4];
  const int tid = threadIdx.x;
  const int wv = tid >> 6, l = tid & 63;
  const int wm = wv >> 1, wn = wv & 1;
  const int lcol = l & 15, lk = l >> 4;
  const int m0 = blockIdx.x * 128;

  int ncol0 = 0, po = 0, pq = 0;
  const short* Bp = Bw;
  if constexpr (MODE == 3) {
    po = blockIdx.y >> 1; pq = blockIdx.y & 1;
    Bp += (size_t)blockIdx.y * 131072;            // per-parity slab
  } else {
    ncol0 = blockIdx.y * 128;
    Bp += (size_t)ncol0 * KPN;
  }

  const int cpos = l & 3;
  const int rl_[2] = { (wv * 2) * 16 + (l >> 2), (wv * 2 + 1) * 16 + (l >> 2) };
  const int cc_[2] = { cpos ^ ((rl_[0] >> 1) & 3), cpos ^ ((rl_[1] >> 1) & 3) };

  f32x4 acc[4][4];
#pragma unroll
  for (int i = 0; i < 4; ++i)
#pragma unroll
    for (int j = 0; j < 4; ++j) acc[i][j] = (f32x4){0.f, 0.f, 0.f, 0.f};

  const int aoff_base = lcol * 32 + ((lk ^ ((lcol >> 1) & 3)) * 8);

  auto STAGE = [&](int it, int bufc) {
    int jj, kk;
    if constexpr (MODE == 0 || MODE == 3) { jj = it >> 3; kk = it & 7; }
    else if constexpr (MODE == 2)         { jj = it >> 2; kk = it & 3; }
    else                                  { jj = 0; kk = it; }
    const int choff = kk * 32;
    (void)jj;
#pragma unroll
    for (int q = 0; q < 2; ++q) {
      const int rl = rl_[q], cc = cc_[q];
      const int m = m0 + rl;
      const short* srcA;
      if constexpr (MODE == 0) {
        const int q3 = jj / 3;
        const int ih = ((m >> 4) & 15) + q3 - 1, iw = (m & 15) + (jj - q3 * 3) - 1;
        const bool v = ((unsigned)ih < 16u) & ((unsigned)iw < 16u);
        srcA = v ? Abuf + (size_t)((m & ~255) + ih * 16 + iw) * AK + choff + cc * 8 : zerob;
      } else if constexpr (MODE == 2) {
        const int ih = 2 * ((m >> 4) & 15) + (jj >> 2) - 1, iw = 2 * (m & 15) + (jj & 3) - 1;
        const bool v = ((unsigned)ih < 32u) & ((unsigned)iw < 32u);
        srcA = v ? Abuf + (size_t)((m >> 8) * 1024 + ih * 32 + iw) * AK + choff + cc * 8 : zerob;
      } else if constexpr (MODE == 3) {
        const int ih = ((m >> 4) & 15) + po - (jj >> 1), iw = (m & 15) + pq - (jj & 1);
        const bool v = ((unsigned)ih < 16u) & ((unsigned)iw < 16u);
        srcA = v ? Abuf + (size_t)((m & ~255) + ih * 16 + iw) * AK + choff + cc * 8 : zerob;
      } else {
        srcA = Abuf + (size_t)m * AK + choff + cc * 8;
      }
      __builtin_amdgcn_global_load_lds(
          (const __attribute__((address_space(1))) void*)srcA,
          (__attribute__((address_space(3))) void*)(&Alds[bufc][(wv * 2 + q) * 512]),
          16, 0, 0);
      const short* srcB = Bp + (size_t)jj * TS + (size_t)rl * KPN + choff + cc * 8;
      __builtin_amdgcn_global_load_lds(
          (const __attribute__((address_space(1))) void*)srcB,
          (__attribute__((address_space(3))) void*)(&Alds[bufc][4096 + (wv * 2 + q) * 512]),
          16, 0, 0);
    }
  };

  auto COMPUTE = [&](int bufc) {
    s16x8 a[4], b[4];
#pragma unroll
    for (int ms = 0; ms < 4; ++ms)
      a[ms] = *(const s16x8*)&Alds[bufc][wm * 2048 + ms * 512 + aoff_base];
#pragma unroll
    for (int ns = 0; ns < 4; ++ns)
      b[ns] = *(const s16x8*)&Alds[bufc][4096 + wn * 2048 + ns * 512 + aoff_base];
#pragma unroll
    for (int ms = 0; ms < 4; ++ms)
#pragma unroll
      for (int ns = 0; ns < 4; ++ns)
        acc[ms][ns] = __builtin_amdgcn_mfma_f32_16x16x32_bf16(a[ms], b[ns], acc[ms][ns], 0, 0, 0);
  };

  // depth-3 prefetch, 4 buffers, counted vmcnt
  STAGE(0, 0);
  STAGE(1, 1);
  STAGE(2, 2);
  int buf = 0, nbuf = 3;
#pragma unroll 1
  for (int it = 0; it < KIT; ++it) {
    if (it + 2 < KIT) {
      asm volatile("s_waitcnt vmcnt(8)" ::: "memory");   // stage it landed; it+1,it+2 in flight
    } else if (it + 1 < KIT) {
      asm volatile("s_waitcnt vmcnt(4)" ::: "memory");
    } else {
      asm volatile("s_waitcnt vmcnt(0)" ::: "memory");
    }
    __builtin_amdgcn_s_barrier();
    __builtin_amdgcn_sched_barrier(0);
    if (it + 3 < KIT) STAGE(it + 3, nbuf);
    __builtin_amdgcn_s_setprio(1);
    COMPUTE(buf);
    __builtin_amdgcn_s_setprio(0);
    buf = (buf + 1) & 3;
    nbuf = (nbuf + 1) & 3;
  }

  // ---------------- epilogue ----------------
  const int r4 = lk * 4;
  float ls = 0.f;
#pragma unroll
  for (int ms = 0; ms < 4; ++ms) {
#pragma unroll
    for (int ns = 0; ns < 4; ++ns) {
      const int n_l = wn * 64 + ns * 16 + lcol;
      const int n_g = ncol0 + n_l;
#pragma unroll
      for (int e = 0; e < 4; ++e) {
        const int m = m0 + wm * 64 + ms * 16 + r4 + e;
        if constexpr (MODE == 4) {
          const float val = bias[n_g] - 2.f * acc[ms][ns][e];
          outb[(size_t)m * 1024 + n_g] = f2bf(val);
        } else if constexpr (MODE == 5) {
          const float d = acc[ms][ns][e] - outf32[(size_t)m * 256 + n_g];
          ls = fmaf(d, d, ls);
        } else if constexpr (MODE == 3) {
          const float val = fmaxf(acc[ms][ns][e] + bias[n_l], 0.f);
          const int orow = (m & ~255) * 4 + (2 * ((m >> 4) & 15) + po) * 32 + (2 * (m & 15) + pq);
          outb[(size_t)orow * 128 + n_l] = f2bf(val);
        } else {
          float val = acc[ms][ns][e] + bias[n_g];
          if (res) val += bf2f(res[(size_t)m * 256 + n_g]);
          val = fmaxf(val, 0.f);
          outb[(size_t)m * 256 + n_g] = f2bf(val);
          if (outf32) outf32[(size_t)m * 256 + n_g] = val;
        }
      }
    }
  }
  if constexpr (MODE == 5) {
#pragma unroll
    for (int o = 32; o > 0; o >>= 1) ls += __shfl_xor(ls, o);
    if (l == 0) red[wv] = ls;
    __syncthreads();
    if (tid == 0) atomicAdd(sacc, red[0] + red[1] + red[2] + red[3]);
  }
}

// ========================= VQ block =========================================
__global__ __launch_bounds__(256) void rownorm_kernel(
    const float* __restrict__ a, float* __restrict__ nrm, int rows)
{
  const int wv = threadIdx.x >> 6, lane = threadIdx.x & 63;
  const int r = blockIdx.x * 4 + wv;
  if (r >= rows) return;
  const float* p = a + (size_t)r * DC;
  float s = 0.f;
#pragma unroll
  for (int i = 0; i < 4; ++i) { float v = p[lane + 64 * i]; s = fmaf(v, v, s); }
#pragma unroll
  for (int o = 32; o > 0; o >>= 1) s += __shfl_xor(s, o);
  if (lane == 0) nrm[r] = s;
}

__global__ void initq_kernel(const float* __restrict__ pi, float* __restrict__ logq,
                             float* __restrict__ Sacc)
{
  const int k = blockIdx.x * 256 + threadIdx.x;
  logq[k] = logf(fmaxf(pi[k], EPSQ));
  if (k == 0) *Sacc = 0.f;
}

// one BA iteration over bf16 DV; register-accumulated Q, uint4 row I/O.
__global__ __launch_bounds__(256) void ba2_kernel(
    uint4* __restrict__ DV, const float* __restrict__ logq,
    float* __restrict__ part, int* __restrict__ idxout, int storeP)
{
  __shared__ float qp[4][1024];
  const int tid = threadIdx.x;
  const int wv = tid >> 6, lane = tid & 63;

  float lq[16];
  {
    const float4* lq4 = (const float4*)logq;   // 256 float4
#pragma unroll
    for (int h = 0; h < 2; ++h) {
      const float4 a = lq4[h * 128 + 2 * lane];
      const float4 b = lq4[h * 128 + 2 * lane + 1];
      lq[h * 8 + 0] = a.x; lq[h * 8 + 1] = a.y; lq[h * 8 + 2] = a.z; lq[h * 8 + 3] = a.w;
      lq[h * 8 + 4] = b.x; lq[h * 8 + 5] = b.y; lq[h * 8 + 6] = b.z; lq[h * 8 + 7] = b.w;
    }
  }

  float qacc[16];
#pragma unroll
  for (int j = 0; j < 16; ++j) qacc[j] = 0.f;

  const int n0 = blockIdx.x * 16;
  for (int rr = 0; rr < 4; ++rr) {
    const int n = n0 + wv * 4 + rr;
    uint4* rowp = DV + (size_t)n * 128;        // 128 uint4 per row
    uint4 w[2];
    w[0] = rowp[lane];
    w[1] = rowp[64 + lane];
    float lv[16];
    float mx = -1e30f;
#pragma unroll
    for (int h = 0; h < 2; ++h) {
      const unsigned* u = (const unsigned*)&w[h];
#pragma unroll
      for (int p = 0; p < 4; ++p) {
        lv[h * 8 + 2 * p]     = lq[h * 8 + 2 * p]     - BETA_F * bf2f((short)(u[p] & 0xFFFFu));
        lv[h * 8 + 2 * p + 1] = lq[h * 8 + 2 * p + 1] - BETA_F * bf2f((short)(u[p] >> 16));
      }
    }
#pragma unroll
    for (int j = 0; j < 16; ++j) mx = fmaxf(mx, lv[j]);
#pragma unroll
    for (int o = 32; o > 0; o >>= 1) mx = fmaxf(mx, __shfl_xor(mx, o));
    float e[16];
    float s = 0.f;
#pragma unroll
    for (int j = 0; j < 16; ++j) { e[j] = __expf(lv[j] - mx); s += e[j]; }
#pragma unroll
    for (int o = 32; o > 0; o >>= 1) s += __shfl_xor(s, o);
    const float inv = 1.f / s;
#pragma unroll
    for (int j = 0; j < 16; ++j) qacc[j] += e[j] * inv;

    if (storeP) {
#pragma unroll
      for (int h = 0; h < 2; ++h) {
        unsigned* u = (unsigned*)&w[h];
#pragma unroll
        for (int p = 0; p < 4; ++p)
          u[p] = pack2(e[h * 8 + 2 * p] * inv, e[h * 8 + 2 * p + 1] * inv);
      }
      rowp[lane] = w[0];
      rowp[64 + lane] = w[1];
      float bv = lv[0]; int bi = 8 * lane;
#pragma unroll
      for (int h = 0; h < 2; ++h)
#pragma unroll
        for (int j = 0; j < 8; ++j) {
          const int k = h * 512 + 8 * lane + j;
          const float v = lv[h * 8 + j];
          if (v > bv || (v == bv && k < bi)) { bv = v; bi = k; }
        }
#pragma unroll
      for (int o = 32; o > 0; o >>= 1) {
        const float ov = __shfl_xor(bv, o);
        const int oi = __shfl_xor(bi, o);
        if (ov > bv || (ov == bv && oi < bi)) { bv = ov; bi = oi; }
      }
      if (lane == 0) idxout[n] = bi;
    }
  }
  __syncthreads();
#pragma unroll
  for (int h = 0; h < 2; ++h)
#pragma unroll
    for (int j = 0; j < 8; ++j)
      qp[wv][h * 512 + 8 * lane + j] = qacc[h * 8 + j];
  __syncthreads();
  for (int k = tid; k < 1024; k += 256) {
    part[(size_t)blockIdx.x * 1024 + k] = qp[0][k] + qp[1][k] + qp[2][k] + qp[3][k];
  }
}

// fused reduce: 64 blocks; last block finishes qsum + logq (ticket pattern)
__global__ __launch_bounds__(256) void qredf_kernel(
    const float* __restrict__ part, float* __restrict__ part2,
    float* __restrict__ qsum, float* __restrict__ logq, unsigned* __restrict__ ticket)
{
  const int b = blockIdx.x;
  const int tid = threadIdx.x;
  const float* p = part + (size_t)b * 32 * 1024;
#pragma unroll
  for (int j = 0; j < 4; ++j) {
    const int k = tid + j * 256;
    float s = 0.f;
#pragma unroll
    for (int r = 0; r < 32; ++r) s += p[(size_t)r * 1024 + k];
    part2[(size_t)b * 1024 + k] = s;
  }
  __threadfence();
  __shared__ unsigned lastv;
  if (tid == 0) lastv = atomicAdd(ticket, 1u);
  __syncthreads();
  if (lastv == 63u) {
    __threadfence();
#pragma unroll
    for (int j = 0; j < 4; ++j) {
      const int k = tid + j * 256;
      float s = 0.f;
#pragma unroll
      for (int r = 0; r < 64; ++r) s += part2[(size_t)r * 1024 + k];
      qsum[k] = s;
      logq[k] = logf(fmaxf(s * (1.f / 32768.f), EPSQ));
    }
    if (tid == 0) *ticket = 0u;   // reset for next sweep / graph replay
  }
}

// fused entropy + loss scalars (after pvq): out3 = &outf[1572864]
__global__ __launch_bounds__(1024) void entsc_kernel(
    const float* __restrict__ qsum, const float* __restrict__ S, float* __restrict__ out3)
{
  const int k = threadIdx.x;
  const float q = fmaxf(qsum[k] * (1.f / 32768.f), EPSQ);
  float v = q * logf(q);
#pragma unroll
  for (int o = 32; o > 0; o >>= 1) v += __shfl_xor(v, o);
  __shared__ float red[16];
  const int wv = k >> 6, lane = k & 63;
  if (lane == 0) red[wv] = v;
  __syncthreads();
  if (k == 0) {
    float s = 0.f;
    for (int i = 0; i < 16; ++i) s += red[i];
    out3[2] = 0.01f * s;              // ent_loss
    const float sa = *S;
    out3[0] = 0.25f * sa / 8388608.f; // commit
    out3[1] = sa / 8388608.f;         // cb_loss
  }
}

__global__ void gather16_kernel(const int* __restrict__ idx, const short* __restrict__ cbb,
                                short* __restrict__ out)
{
  const int t = blockIdx.x * 256 + threadIdx.x;
  const int m = t >> 6, d4 = (t & 63) * 4;
  *(s16x4*)(out + (size_t)m * 256 + d4) = *(const s16x4*)(cbb + (size_t)idx[m] * 256 + d4);
}

// ========================= convT3: 128->3, 32->64, f32-staged LDS ==========
__global__ __launch_bounds__(256) void convt3_kernel(
    const short* __restrict__ in, const float* __restrict__ w,
    const float* __restrict__ bias, float* __restrict__ out)
{
  __shared__ __align__(16) float li[100 * 128];  // [pix][slot] f32, slot = ch ^ (pix&15)
  __shared__ float lw[6144];
  const int tid = threadIdx.x;
  const int tile = blockIdx.x;          // 0..15
  const int b = blockIdx.y;
  const int ty0 = (tile >> 2) * 16, tx0 = (tile & 3) * 16;
  const int iy0 = (tile >> 2) * 8 - 1, ix0 = (tile & 3) * 8 - 1;
  for (int s = tid; s < 1600; s += 256) {
    const int pix = s >> 4, ch = s & 15;
    const int r = pix / 10, c = pix - r * 10;
    const int ih = iy0 + r, iw = ix0 + c;
    s16x8 v = {0, 0, 0, 0, 0, 0, 0, 0};
    if ((unsigned)ih < 32u && (unsigned)iw < 32u)
      v = *(const s16x8*)(in + ((size_t)b * 1024 + ih * 32 + iw) * 128 + ch * 8);
    const int slot = ch ^ (pix & 15);
    f32x4 f0, f1;
#pragma unroll
    for (int e = 0; e < 4; ++e) { f0[e] = bf2f(v[e]); f1[e] = bf2f(v[e + 4]); }
    *(f32x4*)&li[pix * 128 + slot * 8] = f0;
    *(f32x4*)&li[pix * 128 + slot * 8 + 4] = f1;
  }
  for (int s = tid; s < 6144; s += 256) lw[s] = w[s];
  __syncthreads();
  const int ty = tid >> 4, tx = tid & 15;
  const int oh2 = ty0 + ty, ow2 = tx0 + tx;
  const int kh0 = (oh2 + 1) & 1, kw0 = (ow2 + 1) & 1;
  const int ih0 = (oh2 + 1 - kh0) >> 1, iw0 = (ow2 + 1 - kw0) >> 1;
  const int rl0 = ih0 - iy0, cl0 = iw0 - ix0;
  const int p00 = rl0 * 10 + cl0, p01 = p00 - 1, p10 = p00 - 10, p11 = p00 - 11;
  const int wi00 = kh0 * 4 + kw0, wi01 = wi00 + 2, wi10 = wi00 + 8, wi11 = wi00 + 10;
  float acc0 = 0.f, acc1 = 0.f, acc2 = 0.f;
  for (int ch = 0; ch < 16; ++ch) {
    float f00[8], f01[8], f10[8], f11[8];
    *(f32x4*)&f00[0] = *(const f32x4*)&li[p00 * 128 + (ch ^ (p00 & 15)) * 8];
    *(f32x4*)&f00[4] = *(const f32x4*)&li[p00 * 128 + (ch ^ (p00 & 15)) * 8 + 4];
    *(f32x4*)&f01[0] = *(const f32x4*)&li[p01 * 128 + (ch ^ (p01 & 15)) * 8];
    *(f32x4*)&f01[4] = *(const f32x4*)&li[p01 * 128 + (ch ^ (p01 & 15)) * 8 + 4];
    *(f32x4*)&f10[0] = *(const f32x4*)&li[p10 * 128 + (ch ^ (p10 & 15)) * 8];
    *(f32x4*)&f10[4] = *(const f32x4*)&li[p10 * 128 + (ch ^ (p10 & 15)) * 8 + 4];
    *(f32x4*)&f11[0] = *(const f32x4*)&li[p11 * 128 + (ch ^ (p11 & 15)) * 8];
    *(f32x4*)&f11[4] = *(const f32x4*)&li[p11 * 128 + (ch ^ (p11 & 15)) * 8 + 4];
#pragma unroll
    for (int e = 0; e < 8; ++e) {
      const int ci = ch * 8 + e;
      const float* wr = &lw[ci * 48];
      acc0 = fmaf(wr[wi00], f00[e], fmaf(wr[wi01], f01[e], fmaf(wr[wi10], f10[e], fmaf(wr[wi11], f11[e], acc0))));
      acc1 = fmaf(wr[16 + wi00], f00[e], fmaf(wr[16 + wi01], f01[e], fmaf(wr[16 + wi10], f10[e], fmaf(wr[16 + wi11], f11[e], acc1))));
      acc2 = fmaf(wr[32 + wi00], f00[e], fmaf(wr[32 + wi01], f01[e], fmaf(wr[32 + wi10], f10[e], fmaf(wr[32 + wi11], f11[e], acc2))));
    }
  }
  const size_t ob = ((size_t)(b * 3) * 64 + oh2) * 64 + ow2;
  out[ob] = acc0 + bias[0];
  out[ob + 4096] = acc1 + bias[1];
  out[ob + 8192] = acc2 + bias[2];
}

// =====================================================================
extern "C" void kernel_launch(void* const* d_in, const int* in_sizes, int n_in,
                              void* d_out, int out_size, void* d_ws, size_t ws_size,
                              hipStream_t stream)
{
  const float* x     = (const float*)d_in[0];
  const float* ew1   = (const float*)d_in[1];
  const float* eb1   = (const float*)d_in[2];
  const float* ew2   = (const float*)d_in[3];
  const float* eb2   = (const float*)d_in[4];
  const float* ew3   = (const float*)d_in[5];
  const float* eb3   = (const float*)d_in[6];
  const float* er1aw = (const float*)d_in[7];
  const float* er1ab = (const float*)d_in[8];
  const float* er1bw = (const float*)d_in[9];
  const float* er1bb = (const float*)d_in[10];
  const float* er2aw = (const float*)d_in[11];
  const float* er2ab = (const float*)d_in[12];
  const float* er2bw = (const float*)d_in[13];
  const float* er2bb = (const float*)d_in[14];
  const float* cb    = (const float*)d_in[15];
  const float* pi    = (const float*)d_in[16];
  const float* dr1aw = (const float*)d_in[17];
  const float* dr1ab = (const float*)d_in[18];
  const float* dr1bw = (const float*)d_in[19];
  const float* dr1bb = (const float*)d_in[20];
  const float* dr2aw = (const float*)d_in[21];
  const float* dr2ab = (const float*)d_in[22];
  const float* dr2bw = (const float*)d_in[23];
  const float* dr2bb = (const float*)d_in[24];
  const float* dw1   = (const float*)d_in[25];
  const float* db1   = (const float*)d_in[26];
  const float* dwt2  = (const float*)d_in[27];
  const float* dbt2  = (const float*)d_in[28];
  const float* dwt3  = (const float*)d_in[29];
  const float* dbt3  = (const float*)d_in[30];

  float* outf = (float*)d_out;

  // workspace layout (bytes), ~182 MB of 256 MiB
  char* W = (char*)d_ws;
  short* BIGA  = (short*)W;                    // 33.5MB: conv1-out -> ZF32 -> convt2-out
  float* ZF32  = (float*)W;
  short* DV    = (short*)(W + 33554432);       // 67MB bf16 [32768][1024]: dv -> P
  short* X0    = (short*)(W + 100663296);      // 16.7MB each
  short* X1    = (short*)(W + 117440512);
  short* X2    = (short*)(W + 134217728);
  short* WT2   = (short*)(W + 152174592);      // 1,048,576 B
  short* WTT2  = (short*)(W + 153223168);      // 1,048,576 B
  short* CBB   = (short*)(W + 154271744);      //   524,288 B
  short* CBT   = (short*)(W + 154796032);      //   524,288 B
  float* cn    = (float*)(W + 155320320);      //     4,096 B
  float* qsum  = (float*)(W + 155324416);
  float* logq  = (float*)(W + 155328512);
  int*   idx   = (int*)(W + 155332608);        //   131,072 B
  float* Sacc  = (float*)(W + 155463680);
  short* zerob = (short*)(W + 155463696);      //        16 B
  unsigned* ticket = (unsigned*)(W + 155463712);
  float* PART  = (float*)(W + 160000000);      // 8,388,608 B [2048][1024]
  float* PART2 = (float*)(W + 168388608);      //   262,144 B [64][1024]
  short* WT3S  = (short*)(W + 168650752);      // 10 x 1,179,648 B

  const dim3 blk(256);
  #define WTSLAB(i) (WT3S + (size_t)(i) * 589824)
  #define IG3(A_, Wi_, B_, R_, O_, F_) \
    igemm_kernel<0,72,256,256,65536><<<dim3(256, 2), blk, 0, stream>>>( \
        A_, WTSLAB(Wi_), B_, R_, O_, F_, nullptr, zerob)

  init0_kernel<<<dim3(1), dim3(64), 0, stream>>>(zerob, ticket);
  w3t10_kernel<<<dim3(2304, 10), blk, 0, stream>>>(
      ew3, er1aw, er1bw, er2aw, er2bw, dr1aw, dr1bw, dr2aw, dr2bw, dw1, WT3S);

  // -------- encoder --------
  conv1_kernel<<<dim3(4, NB), blk, 0, stream>>>(x, ew1, eb1, BIGA);
  w2t_kernel<<<dim3(2048), blk, 0, stream>>>(ew2, WT2);
  igemm_kernel<2,64,128,128,32768><<<dim3(256, 2), blk, 0, stream>>>(
      BIGA, WT2, eb2, nullptr, X0, nullptr, nullptr, zerob);
  IG3(X0, 0, eb3, nullptr, X1, nullptr);                   // h3
  IG3(X1, 1, er1ab, nullptr, X2, nullptr);
  IG3(X2, 2, er1bb, X1, X0, nullptr);                      // h4
  IG3(X0, 3, er2ab, nullptr, X1, nullptr);
  IG3(X1, 4, er2bb, X0, X2, ZF32);                         // z (bf16 + fp32 dup)

  // -------- VQ / Blahut-Arimoto --------
  rownorm_kernel<<<dim3(KCB / 4), blk, 0, stream>>>(cb, cn, KCB);
  cbbf_kernel<<<dim3(1024), blk, 0, stream>>>(cb, CBB);
  cbt_kernel<<<dim3(1024), blk, 0, stream>>>(cb, CBT);
  initq_kernel<<<dim3(4), blk, 0, stream>>>(pi, logq, Sacc);
  igemm_kernel<4,8,256,256,0><<<dim3(256, 8), blk, 0, stream>>>(
      X2, CBB, cn, nullptr, DV, nullptr, nullptr, zerob);
  for (int i = 0; i < 5; ++i) {
    ba2_kernel<<<dim3(NROW / 16), blk, 0, stream>>>(
        (uint4*)DV, logq, PART, idx, (i == 4) ? 1 : 0);
    qredf_kernel<<<dim3(64), blk, 0, stream>>>(PART, PART2, qsum, logq, ticket);
  }
  igemm_kernel<5,32,1024,1024,0><<<dim3(256, 2), blk, 0, stream>>>(
      DV, CBT, nullptr, nullptr, nullptr, ZF32, Sacc, zerob);
  entsc_kernel<<<dim3(1), dim3(1024), 0, stream>>>(qsum, Sacc, outf + 1572864);
  gather16_kernel<<<dim3(8192), blk, 0, stream>>>(idx, CBB, X0);  // zq_hard NHWC bf16

  // -------- decoder --------
  IG3(X0, 5, dr1ab, nullptr, X1, nullptr);
  IG3(X1, 6, dr1bb, X0, X2, nullptr);                      // y1
  IG3(X2, 7, dr2ab, nullptr, X0, nullptr);
  IG3(X0, 8, dr2bb, X2, X1, nullptr);                      // y2
  IG3(X1, 9, db1, nullptr, X0, nullptr);                   // y3
  wtt2_kernel<<<dim3(2048), blk, 0, stream>>>(dwt2, WTT2);
  igemm_kernel<3,32,256,256,32768><<<dim3(256, 4), blk, 0, stream>>>(
      X0, WTT2, dbt2, nullptr, BIGA, nullptr, nullptr, zerob);
  convt3_kernel<<<dim3(16, NB), blk, 0, stream>>>(BIGA, dwt3, dbt3, outf);
  #undef IG3
  #undef WTSLAB
}

// Round 14
// 947.139 us; speedup vs baseline: 2.3518x; 1.0198x over previous
//
#include <hip/hip_runtime.h>
#include <math.h>

// ---------------- problem constants ----------------
#define NB   128
#define DC   256
#define SP   256
#define NROW 32768
#define KCB  1024
#define BETA_F 0.1f
#define EPSQ 1e-10f

typedef __attribute__((ext_vector_type(8))) short s16x8;
typedef __attribute__((ext_vector_type(4))) short s16x4;
typedef __attribute__((ext_vector_type(4))) float f32x4;

__device__ __forceinline__ short f2bf(float f) {
  unsigned u = __builtin_bit_cast(unsigned, f);
  unsigned r = (u + 0x7FFFu + ((u >> 16) & 1u)) >> 16;
  return (short)r;
}
__device__ __forceinline__ float bf2f(short s) {
  unsigned u = ((unsigned)(unsigned short)s) << 16;
  return __builtin_bit_cast(float, u);
}
__device__ __forceinline__ unsigned pack2(float a, float b) {
  return (unsigned)(unsigned short)f2bf(a) | ((unsigned)(unsigned short)f2bf(b) << 16);
}

// ========================= init: zero zero-buffer + ticket =================
__global__ void init0_kernel(short* __restrict__ zerob, unsigned* __restrict__ ticket)
{
  if (threadIdx.x < 8) zerob[threadIdx.x] = 0;
  if (threadIdx.x == 0) *ticket = 0u;
}

// ========================= weight transposes (fp32 -> bf16) =================
__global__ void w3t10_kernel(
    const float* __restrict__ w0, const float* __restrict__ w1,
    const float* __restrict__ w2, const float* __restrict__ w3,
    const float* __restrict__ w4, const float* __restrict__ w5,
    const float* __restrict__ w6, const float* __restrict__ w7,
    const float* __restrict__ w8, const float* __restrict__ w9,
    short* __restrict__ o)
{
  const float* ws[10] = {w0, w1, w2, w3, w4, w5, w6, w7, w8, w9};
  const float* w = ws[blockIdx.y];
  const int i = blockIdx.x * 256 + threadIdx.x;  // 589824
  const int ci = i & 255, co = (i >> 8) & 255, j = i >> 16;
  o[(size_t)blockIdx.y * 589824 + i] = f2bf(w[((size_t)(co * 256 + ci)) * 9 + j]);
}
__global__ void w2t_kernel(const float* __restrict__ w, short* __restrict__ o)
{
  const int i = blockIdx.x * 256 + threadIdx.x;  // 524288
  const int ci = i & 127, co = (i >> 7) & 255, j = i >> 15;
  o[i] = f2bf(w[((size_t)(co * 128 + ci)) * 16 + j]);
}
__global__ void wtt2_kernel(const float* __restrict__ w, short* __restrict__ o)
{
  const int i = blockIdx.x * 256 + threadIdx.x;  // 524288
  const int ci = i & 255, co = (i >> 8) & 127, j = (i >> 15) & 3, p = i >> 17;
  const int po = p >> 1, pq = p & 1, a = j >> 1, b2 = j & 1;
  const int kh = (1 - po) + 2 * a, kw = (1 - pq) + 2 * b2;
  o[i] = f2bf(w[((size_t)(ci * 128 + co)) * 16 + kh * 4 + kw]);
}
__global__ void cbbf_kernel(const float* __restrict__ cb, short* __restrict__ o)
{
  const int i = blockIdx.x * 256 + threadIdx.x;  // 262144
  o[i] = f2bf(cb[i]);
}
__global__ void cbt_kernel(const float* __restrict__ cb, short* __restrict__ o)
{
  const int i = blockIdx.x * 256 + threadIdx.x;  // 262144
  const int d = i >> 10, k = i & 1023;
  o[i] = f2bf(cb[(size_t)k * 256 + d]);
}

// ========================= conv1: 3->128, 4x4 s2, 64->32, out NHWC bf16 =====
__global__ __launch_bounds__(256) void conv1_kernel(
    const float* __restrict__ x, const float* __restrict__ w,
    const float* __restrict__ bias, short* __restrict__ out)
{
  __shared__ float li[3][34][34];
  const int tid = threadIdx.x;
  const int tile = blockIdx.x;          // 0..3 quadrant of 32x32 output
  const int b = blockIdx.y;
  const int qy = tile >> 1, qx = tile & 1;
  const int ihlo = qy * 32 - 1, iwlo = qx * 32 - 1;
  for (int ci = 0; ci < 3; ++ci)
    for (int s = tid; s < 1156; s += 256) {
      const int r = s / 34, c = s - r * 34;
      const int ih = ihlo + r, iw = iwlo + c;
      float v = 0.f;
      if ((unsigned)ih < 64u && (unsigned)iw < 64u)
        v = x[((size_t)(b * 3 + ci) * 64 + ih) * 64 + iw];
      li[ci][r][c] = v;
    }
  __syncthreads();

  const int wv = tid >> 6, l = tid & 63;
  const int co0 = 2 * l, co1 = 2 * l + 1;
  float w0[48], w1[48];
#pragma unroll
  for (int j = 0; j < 48; ++j) {
    w0[j] = w[(size_t)co0 * 48 + j];
    w1[j] = w[(size_t)co1 * 48 + j];
  }
  const float b0 = bias[co0], b1 = bias[co1];

  for (int pass = 0; pass < 64; ++pass) {
    const int pix = pass * 4 + wv;            // 0..255
    const int py = pix >> 4, px = pix & 15;
    float s0 = b0, s1 = b1;
#pragma unroll
    for (int ci = 0; ci < 3; ++ci)
#pragma unroll
      for (int kh = 0; kh < 4; ++kh)
#pragma unroll
        for (int kw = 0; kw < 4; ++kw) {
          const int j = ci * 16 + kh * 4 + kw;
          const float v = li[ci][2 * py + kh][2 * px + kw];  // wave-broadcast
          s0 = fmaf(v, w0[j], s0);
          s1 = fmaf(v, w1[j], s1);
        }
    s0 = fmaxf(s0, 0.f);
    s1 = fmaxf(s1, 0.f);
    const int oh = qy * 16 + py, ow = qx * 16 + px;
    ((unsigned*)(out + ((size_t)b * 1024 + oh * 32 + ow) * 128))[l] = pack2(s0, s1);
  }
}

// ========================= MFMA implicit GEMM (128x128 tile, BK=32) =========
// 4 waves as 2x2; wave tile 64x64 = acc[4][4]; A and B both staged in LDS.
// 4 LDS buffers, depth-3 prefetch, counted vmcnt(8) + raw s_barrier per step.
template<int MODE, int KIT, int AK, int KPN, int TS>
__global__ __launch_bounds__(256) void igemm_kernel(
    const short* __restrict__ Abuf, const short* __restrict__ Bw,
    const float* __restrict__ bias, const short* __restrict__ res,
    short* __restrict__ outb, float* __restrict__ outf32,
    float* __restrict__ sacc, const short* __restrict__ zerob)
{
  __shared__ __align__(16) short Alds[4][8192];   // per buf: [A 4096 | B 4096]
  __shared__ float red[4];
  const int tid = threadIdx.x;
  const int wv = tid >> 6, l = tid & 63;
  const int wm = wv >> 1, wn = wv & 1;
  const int lcol = l & 15, lk = l >> 4;
  const int m0 = blockIdx.x * 128;

  int ncol0 = 0, po = 0, pq = 0;
  const short* Bp = Bw;
  if constexpr (MODE == 3) {
    po = blockIdx.y >> 1; pq = blockIdx.y & 1;
    Bp += (size_t)blockIdx.y * 131072;            // per-parity slab
  } else {
    ncol0 = blockIdx.y * 128;
    Bp += (size_t)ncol0 * KPN;
  }

  const int cpos = l & 3;
  const int rl_[2] = { (wv * 2) * 16 + (l >> 2), (wv * 2 + 1) * 16 + (l >> 2) };
  const int cc_[2] = { cpos ^ ((rl_[0] >> 1) & 3), cpos ^ ((rl_[1] >> 1) & 3) };

  f32x4 acc[4][4];
#pragma unroll
  for (int i = 0; i < 4; ++i)
#pragma unroll
    for (int j = 0; j < 4; ++j) acc[i][j] = (f32x4){0.f, 0.f, 0.f, 0.f};

  const int aoff_base = lcol * 32 + ((lk ^ ((lcol >> 1) & 3)) * 8);

  auto STAGE = [&](int it, int bufc) {
    int jj, kk;
    if constexpr (MODE == 0 || MODE == 3) { jj = it >> 3; kk = it & 7; }
    else if constexpr (MODE == 2)         { jj = it >> 2; kk = it & 3; }
    else                                  { jj = 0; kk = it; }
    const int choff = kk * 32;
    (void)jj;
#pragma unroll
    for (int q = 0; q < 2; ++q) {
      const int rl = rl_[q], cc = cc_[q];
      const int m = m0 + rl;
      const short* srcA;
      if constexpr (MODE == 0) {
        const int q3 = jj / 3;
        const int ih = ((m >> 4) & 15) + q3 - 1, iw = (m & 15) + (jj - q3 * 3) - 1;
        const bool v = ((unsigned)ih < 16u) & ((unsigned)iw < 16u);
        srcA = v ? Abuf + (size_t)((m & ~255) + ih * 16 + iw) * AK + choff + cc * 8 : zerob;
      } else if constexpr (MODE == 2) {
        const int ih = 2 * ((m >> 4) & 15) + (jj >> 2) - 1, iw = 2 * (m & 15) + (jj & 3) - 1;
        const bool v = ((unsigned)ih < 32u) & ((unsigned)iw < 32u);
        srcA = v ? Abuf + (size_t)((m >> 8) * 1024 + ih * 32 + iw) * AK + choff + cc * 8 : zerob;
      } else if constexpr (MODE == 3) {
        const int ih = ((m >> 4) & 15) + po - (jj >> 1), iw = (m & 15) + pq - (jj & 1);
        const bool v = ((unsigned)ih < 16u) & ((unsigned)iw < 16u);
        srcA = v ? Abuf + (size_t)((m & ~255) + ih * 16 + iw) * AK + choff + cc * 8 : zerob;
      } else {
        srcA = Abuf + (size_t)m * AK + choff + cc * 8;
      }
      __builtin_amdgcn_global_load_lds(
          (const __attribute__((address_space(1))) void*)srcA,
          (__attribute__((address_space(3))) void*)(&Alds[bufc][(wv * 2 + q) * 512]),
          16, 0, 0);
      const short* srcB = Bp + (size_t)jj * TS + (size_t)rl * KPN + choff + cc * 8;
      __builtin_amdgcn_global_load_lds(
          (const __attribute__((address_space(1))) void*)srcB,
          (__attribute__((address_space(3))) void*)(&Alds[bufc][4096 + (wv * 2 + q) * 512]),
          16, 0, 0);
    }
  };

  auto COMPUTE = [&](int bufc) {
    s16x8 a[4], b[4];
#pragma unroll
    for (int ms = 0; ms < 4; ++ms)
      a[ms] = *(const s16x8*)&Alds[bufc][wm * 2048 + ms * 512 + aoff_base];
#pragma unroll
    for (int ns = 0; ns < 4; ++ns)
      b[ns] = *(const s16x8*)&Alds[bufc][4096 + wn * 2048 + ns * 512 + aoff_base];
#pragma unroll
    for (int ms = 0; ms < 4; ++ms)
#pragma unroll
      for (int ns = 0; ns < 4; ++ns)
        acc[ms][ns] = __builtin_amdgcn_mfma_f32_16x16x32_bf16(a[ms], b[ns], acc[ms][ns], 0, 0, 0);
  };

  // depth-3 prefetch, 4 buffers, counted vmcnt
  STAGE(0, 0);
  STAGE(1, 1);
  STAGE(2, 2);
  int buf = 0, nbuf = 3;
#pragma unroll 1
  for (int it = 0; it < KIT; ++it) {
    if (it + 2 < KIT) {
      asm volatile("s_waitcnt vmcnt(8)" ::: "memory");   // stage it landed; it+1,it+2 in flight
    } else if (it + 1 < KIT) {
      asm volatile("s_waitcnt vmcnt(4)" ::: "memory");
    } else {
      asm volatile("s_waitcnt vmcnt(0)" ::: "memory");
    }
    __builtin_amdgcn_s_barrier();
    if (it + 3 < KIT) STAGE(it + 3, nbuf);
    __builtin_amdgcn_s_setprio(1);
    COMPUTE(buf);
    __builtin_amdgcn_s_setprio(0);
    buf = (buf + 1) & 3;
    nbuf = (nbuf + 1) & 3;
  }

  // ---------------- epilogue ----------------
  const int r4 = lk * 4;
  float ls = 0.f;
#pragma unroll
  for (int ms = 0; ms < 4; ++ms) {
#pragma unroll
    for (int ns = 0; ns < 4; ++ns) {
      const int n_l = wn * 64 + ns * 16 + lcol;
      const int n_g = ncol0 + n_l;
#pragma unroll
      for (int e = 0; e < 4; ++e) {
        const int m = m0 + wm * 64 + ms * 16 + r4 + e;
        if constexpr (MODE == 4) {
          const float val = bias[n_g] - 2.f * acc[ms][ns][e];
          outb[(size_t)m * 1024 + n_g] = f2bf(val);
        } else if constexpr (MODE == 5) {
          const float d = acc[ms][ns][e] - outf32[(size_t)m * 256 + n_g];
          ls = fmaf(d, d, ls);
        } else if constexpr (MODE == 3) {
          const float val = fmaxf(acc[ms][ns][e] + bias[n_l], 0.f);
          const int orow = (m & ~255) * 4 + (2 * ((m >> 4) & 15) + po) * 32 + (2 * (m & 15) + pq);
          outb[(size_t)orow * 128 + n_l] = f2bf(val);
        } else {
          float val = acc[ms][ns][e] + bias[n_g];
          if (res) val += bf2f(res[(size_t)m * 256 + n_g]);
          val = fmaxf(val, 0.f);
          outb[(size_t)m * 256 + n_g] = f2bf(val);
          if (outf32) outf32[(size_t)m * 256 + n_g] = val;
        }
      }
    }
  }
  if constexpr (MODE == 5) {
#pragma unroll
    for (int o = 32; o > 0; o >>= 1) ls += __shfl_xor(ls, o);
    if (l == 0) red[wv] = ls;
    __syncthreads();
    if (tid == 0) atomicAdd(sacc, red[0] + red[1] + red[2] + red[3]);
  }
}

// ========================= VQ block =========================================
__global__ __launch_bounds__(256) void rownorm_kernel(
    const float* __restrict__ a, float* __restrict__ nrm, int rows)
{
  const int wv = threadIdx.x >> 6, lane = threadIdx.x & 63;
  const int r = blockIdx.x * 4 + wv;
  if (r >= rows) return;
  const float* p = a + (size_t)r * DC;
  float s = 0.f;
#pragma unroll
  for (int i = 0; i < 4; ++i) { float v = p[lane + 64 * i]; s = fmaf(v, v, s); }
#pragma unroll
  for (int o = 32; o > 0; o >>= 1) s += __shfl_xor(s, o);
  if (lane == 0) nrm[r] = s;
}

__global__ void initq_kernel(const float* __restrict__ pi, float* __restrict__ logq,
                             float* __restrict__ Sacc)
{
  const int k = blockIdx.x * 256 + threadIdx.x;
  logq[k] = logf(fmaxf(pi[k], EPSQ));
  if (k == 0) *Sacc = 0.f;
}

// one BA iteration over bf16 DV; register-accumulated Q, uint4 row I/O.
__global__ __launch_bounds__(256) void ba2_kernel(
    uint4* __restrict__ DV, const float* __restrict__ logq,
    float* __restrict__ part, int* __restrict__ idxout, int storeP)
{
  __shared__ float qp[4][1024];
  const int tid = threadIdx.x;
  const int wv = tid >> 6, lane = tid & 63;

  float lq[16];
  {
    const float4* lq4 = (const float4*)logq;   // 256 float4
#pragma unroll
    for (int h = 0; h < 2; ++h) {
      const float4 a = lq4[h * 128 + 2 * lane];
      const float4 b = lq4[h * 128 + 2 * lane + 1];
      lq[h * 8 + 0] = a.x; lq[h * 8 + 1] = a.y; lq[h * 8 + 2] = a.z; lq[h * 8 + 3] = a.w;
      lq[h * 8 + 4] = b.x; lq[h * 8 + 5] = b.y; lq[h * 8 + 6] = b.z; lq[h * 8 + 7] = b.w;
    }
  }

  float qacc[16];
#pragma unroll
  for (int j = 0; j < 16; ++j) qacc[j] = 0.f;

  const int n0 = blockIdx.x * 16;
  for (int rr = 0; rr < 4; ++rr) {
    const int n = n0 + wv * 4 + rr;
    uint4* rowp = DV + (size_t)n * 128;        // 128 uint4 per row
    uint4 w[2];
    w[0] = rowp[lane];
    w[1] = rowp[64 + lane];
    float lv[16];
    float mx = -1e30f;
#pragma unroll
    for (int h = 0; h < 2; ++h) {
      const unsigned* u = (const unsigned*)&w[h];
#pragma unroll
      for (int p = 0; p < 4; ++p) {
        lv[h * 8 + 2 * p]     = lq[h * 8 + 2 * p]     - BETA_F * bf2f((short)(u[p] & 0xFFFFu));
        lv[h * 8 + 2 * p + 1] = lq[h * 8 + 2 * p + 1] - BETA_F * bf2f((short)(u[p] >> 16));
      }
    }
#pragma unroll
    for (int j = 0; j < 16; ++j) mx = fmaxf(mx, lv[j]);
#pragma unroll
    for (int o = 32; o > 0; o >>= 1) mx = fmaxf(mx, __shfl_xor(mx, o));
    float e[16];
    float s = 0.f;
#pragma unroll
    for (int j = 0; j < 16; ++j) { e[j] = __expf(lv[j] - mx); s += e[j]; }
#pragma unroll
    for (int o = 32; o > 0; o >>= 1) s += __shfl_xor(s, o);
    const float inv = 1.f / s;
#pragma unroll
    for (int j = 0; j < 16; ++j) qacc[j] += e[j] * inv;

    if (storeP) {
#pragma unroll
      for (int h = 0; h < 2; ++h) {
        unsigned* u = (unsigned*)&w[h];
#pragma unroll
        for (int p = 0; p < 4; ++p)
          u[p] = pack2(e[h * 8 + 2 * p] * inv, e[h * 8 + 2 * p + 1] * inv);
      }
      rowp[lane] = w[0];
      rowp[64 + lane] = w[1];
      float bv = lv[0]; int bi = 8 * lane;
#pragma unroll
      for (int h = 0; h < 2; ++h)
#pragma unroll
        for (int j = 0; j < 8; ++j) {
          const int k = h * 512 + 8 * lane + j;
          const float v = lv[h * 8 + j];
          if (v > bv || (v == bv && k < bi)) { bv = v; bi = k; }
        }
#pragma unroll
      for (int o = 32; o > 0; o >>= 1) {
        const float ov = __shfl_xor(bv, o);
        const int oi = __shfl_xor(bi, o);
        if (ov > bv || (ov == bv && oi < bi)) { bv = ov; bi = oi; }
      }
      if (lane == 0) idxout[n] = bi;
    }
  }
  __syncthreads();
#pragma unroll
  for (int h = 0; h < 2; ++h)
#pragma unroll
    for (int j = 0; j < 8; ++j)
      qp[wv][h * 512 + 8 * lane + j] = qacc[h * 8 + j];
  __syncthreads();
  for (int k = tid; k < 1024; k += 256) {
    part[(size_t)blockIdx.x * 1024 + k] = qp[0][k] + qp[1][k] + qp[2][k] + qp[3][k];
  }
}

// fused reduce: 64 blocks; last block finishes qsum + logq (ticket pattern)
__global__ __launch_bounds__(256) void qredf_kernel(
    const float* __restrict__ part, float* __restrict__ part2,
    float* __restrict__ qsum, float* __restrict__ logq, unsigned* __restrict__ ticket)
{
  const int b = blockIdx.x;
  const int tid = threadIdx.x;
  const float* p = part + (size_t)b * 32 * 1024;
#pragma unroll
  for (int j = 0; j < 4; ++j) {
    const int k = tid + j * 256;
    float s = 0.f;
#pragma unroll
    for (int r = 0; r < 32; ++r) s += p[(size_t)r * 1024 + k];
    part2[(size_t)b * 1024 + k] = s;
  }
  __threadfence();
  __shared__ unsigned lastv;
  if (tid == 0) lastv = atomicAdd(ticket, 1u);
  __syncthreads();
  if (lastv == 63u) {
    __threadfence();
#pragma unroll
    for (int j = 0; j < 4; ++j) {
      const int k = tid + j * 256;
      float s = 0.f;
#pragma unroll
      for (int r = 0; r < 64; ++r) s += part2[(size_t)r * 1024 + k];
      qsum[k] = s;
      logq[k] = logf(fmaxf(s * (1.f / 32768.f), EPSQ));
    }
    if (tid == 0) *ticket = 0u;   // reset for next sweep / graph replay
  }
}

// fused entropy + loss scalars (after pvq): out3 = &outf[1572864]
__global__ __launch_bounds__(1024) void entsc_kernel(
    const float* __restrict__ qsum, const float* __restrict__ S, float* __restrict__ out3)
{
  const int k = threadIdx.x;
  const float q = fmaxf(qsum[k] * (1.f / 32768.f), EPSQ);
  float v = q * logf(q);
#pragma unroll
  for (int o = 32; o > 0; o >>= 1) v += __shfl_xor(v, o);
  __shared__ float red[16];
  const int wv = k >> 6, lane = k & 63;
  if (lane == 0) red[wv] = v;
  __syncthreads();
  if (k == 0) {
    float s = 0.f;
    for (int i = 0; i < 16; ++i) s += red[i];
    out3[2] = 0.01f * s;              // ent_loss
    const float sa = *S;
    out3[0] = 0.25f * sa / 8388608.f; // commit
    out3[1] = sa / 8388608.f;         // cb_loss
  }
}

__global__ void gather16_kernel(const int* __restrict__ idx, const short* __restrict__ cbb,
                                short* __restrict__ out)
{
  const int t = blockIdx.x * 256 + threadIdx.x;
  const int m = t >> 6, d4 = (t & 63) * 4;
  *(s16x4*)(out + (size_t)m * 256 + d4) = *(const s16x4*)(cbb + (size_t)idx[m] * 256 + d4);
}

// ========================= convT3: 128->3, 32->64 (round-11 version) =======
__global__ __launch_bounds__(256) void convt3_kernel(
    const short* __restrict__ in, const float* __restrict__ w,
    const float* __restrict__ bias, float* __restrict__ out)
{
  __shared__ __align__(16) short li[100 * 128];  // [pix][slot], slot = ch ^ (pix&15)
  __shared__ float lw[6144];
  const int tid = threadIdx.x;
  const int tile = blockIdx.x;          // 0..15
  const int b = blockIdx.y;
  const int ty0 = (tile >> 2) * 16, tx0 = (tile & 3) * 16;
  const int iy0 = (tile >> 2) * 8 - 1, ix0 = (tile & 3) * 8 - 1;
  for (int s = tid; s < 1600; s += 256) {
    const int pix = s >> 4, ch = s & 15;
    const int r = pix / 10, c = pix - r * 10;
    const int ih = iy0 + r, iw = ix0 + c;
    s16x8 v = {0, 0, 0, 0, 0, 0, 0, 0};
    if ((unsigned)ih < 32u && (unsigned)iw < 32u)
      v = *(const s16x8*)(in + ((size_t)b * 1024 + ih * 32 + iw) * 128 + ch * 8);
    const int slot = ch ^ (pix & 15);
    *(s16x8*)&li[pix * 128 + slot * 8] = v;
  }
  for (int s = tid; s < 6144; s += 256) lw[s] = w[s];
  __syncthreads();
  const int ty = tid >> 4, tx = tid & 15;
  const int oh2 = ty0 + ty, ow2 = tx0 + tx;
  const int kh0 = (oh2 + 1) & 1, kw0 = (ow2 + 1) & 1;
  const int ih0 = (oh2 + 1 - kh0) >> 1, iw0 = (ow2 + 1 - kw0) >> 1;
  const int rl0 = ih0 - iy0, cl0 = iw0 - ix0;
  const int p00 = rl0 * 10 + cl0, p01 = p00 - 1, p10 = p00 - 10, p11 = p00 - 11;
  const int wi00 = kh0 * 4 + kw0, wi01 = wi00 + 2, wi10 = wi00 + 8, wi11 = wi00 + 10;
  float acc0 = 0.f, acc1 = 0.f, acc2 = 0.f;
  for (int ch = 0; ch < 16; ++ch) {
    const s16x8 v00 = *(const s16x8*)&li[p00 * 128 + (ch ^ (p00 & 15)) * 8];
    const s16x8 v01 = *(const s16x8*)&li[p01 * 128 + (ch ^ (p01 & 15)) * 8];
    const s16x8 v10 = *(const s16x8*)&li[p10 * 128 + (ch ^ (p10 & 15)) * 8];
    const s16x8 v11 = *(const s16x8*)&li[p11 * 128 + (ch ^ (p11 & 15)) * 8];
#pragma unroll
    for (int e = 0; e < 8; ++e) {
      const int ci = ch * 8 + e;
      const float* wr = &lw[ci * 48];
      const float f00 = bf2f(v00[e]), f01 = bf2f(v01[e]);
      const float f10 = bf2f(v10[e]), f11 = bf2f(v11[e]);
      acc0 = fmaf(wr[wi00], f00, fmaf(wr[wi01], f01, fmaf(wr[wi10], f10, fmaf(wr[wi11], f11, acc0))));
      acc1 = fmaf(wr[16 + wi00], f00, fmaf(wr[16 + wi01], f01, fmaf(wr[16 + wi10], f10, fmaf(wr[16 + wi11], f11, acc1))));
      acc2 = fmaf(wr[32 + wi00], f00, fmaf(wr[32 + wi01], f01, fmaf(wr[32 + wi10], f10, fmaf(wr[32 + wi11], f11, acc2))));
    }
  }
  const size_t ob = ((size_t)(b * 3) * 64 + oh2) * 64 + ow2;
  out[ob] = acc0 + bias[0];
  out[ob + 4096] = acc1 + bias[1];
  out[ob + 8192] = acc2 + bias[2];
}

// =====================================================================
extern "C" void kernel_launch(void* const* d_in, const int* in_sizes, int n_in,
                              void* d_out, int out_size, void* d_ws, size_t ws_size,
                              hipStream_t stream)
{
  const float* x     = (const float*)d_in[0];
  const float* ew1   = (const float*)d_in[1];
  const float* eb1   = (const float*)d_in[2];
  const float* ew2   = (const float*)d_in[3];
  const float* eb2   = (const float*)d_in[4];
  const float* ew3   = (const float*)d_in[5];
  const float* eb3   = (const float*)d_in[6];
  const float* er1aw = (const float*)d_in[7];
  const float* er1ab = (const float*)d_in[8];
  const float* er1bw = (const float*)d_in[9];
  const float* er1bb = (const float*)d_in[10];
  const float* er2aw = (const float*)d_in[11];
  const float* er2ab = (const float*)d_in[12];
  const float* er2bw = (const float*)d_in[13];
  const float* er2bb = (const float*)d_in[14];
  const float* cb    = (const float*)d_in[15];
  const float* pi    = (const float*)d_in[16];
  const float* dr1aw = (const float*)d_in[17];
  const float* dr1ab = (const float*)d_in[18];
  const float* dr1bw = (const float*)d_in[19];
  const float* dr1bb = (const float*)d_in[20];
  const float* dr2aw = (const float*)d_in[21];
  const float* dr2ab = (const float*)d_in[22];
  const float* dr2bw = (const float*)d_in[23];
  const float* dr2bb = (const float*)d_in[24];
  const float* dw1   = (const float*)d_in[25];
  const float* db1   = (const float*)d_in[26];
  const float* dwt2  = (const float*)d_in[27];
  const float* dbt2  = (const float*)d_in[28];
  const float* dwt3  = (const float*)d_in[29];
  const float* dbt3  = (const float*)d_in[30];

  float* outf = (float*)d_out;

  // workspace layout (bytes), ~182 MB of 256 MiB
  char* W = (char*)d_ws;
  short* BIGA  = (short*)W;                    // 33.5MB: conv1-out -> ZF32 -> convt2-out
  float* ZF32  = (float*)W;
  short* DV    = (short*)(W + 33554432);       // 67MB bf16 [32768][1024]: dv -> P
  short* X0    = (short*)(W + 100663296);      // 16.7MB each
  short* X1    = (short*)(W + 117440512);
  short* X2    = (short*)(W + 134217728);
  short* WT2   = (short*)(W + 152174592);      // 1,048,576 B
  short* WTT2  = (short*)(W + 153223168);      // 1,048,576 B
  short* CBB   = (short*)(W + 154271744);      //   524,288 B
  short* CBT   = (short*)(W + 154796032);      //   524,288 B
  float* cn    = (float*)(W + 155320320);      //     4,096 B
  float* qsum  = (float*)(W + 155324416);
  float* logq  = (float*)(W + 155328512);
  int*   idx   = (int*)(W + 155332608);        //   131,072 B
  float* Sacc  = (float*)(W + 155463680);
  short* zerob = (short*)(W + 155463696);      //        16 B
  unsigned* ticket = (unsigned*)(W + 155463712);
  float* PART  = (float*)(W + 160000000);      // 8,388,608 B [2048][1024]
  float* PART2 = (float*)(W + 168388608);      //   262,144 B [64][1024]
  short* WT3S  = (short*)(W + 168650752);      // 10 x 1,179,648 B

  const dim3 blk(256);
  #define WTSLAB(i) (WT3S + (size_t)(i) * 589824)
  #define IG3(A_, Wi_, B_, R_, O_, F_) \
    igemm_kernel<0,72,256,256,65536><<<dim3(256, 2), blk, 0, stream>>>( \
        A_, WTSLAB(Wi_), B_, R_, O_, F_, nullptr, zerob)

  init0_kernel<<<dim3(1), dim3(64), 0, stream>>>(zerob, ticket);
  w3t10_kernel<<<dim3(2304, 10), blk, 0, stream>>>(
      ew3, er1aw, er1bw, er2aw, er2bw, dr1aw, dr1bw, dr2aw, dr2bw, dw1, WT3S);

  // -------- encoder --------
  conv1_kernel<<<dim3(4, NB), blk, 0, stream>>>(x, ew1, eb1, BIGA);
  w2t_kernel<<<dim3(2048), blk, 0, stream>>>(ew2, WT2);
  igemm_kernel<2,64,128,128,32768><<<dim3(256, 2), blk, 0, stream>>>(
      BIGA, WT2, eb2, nullptr, X0, nullptr, nullptr, zerob);
  IG3(X0, 0, eb3, nullptr, X1, nullptr);                   // h3
  IG3(X1, 1, er1ab, nullptr, X2, nullptr);
  IG3(X2, 2, er1bb, X1, X0, nullptr);                      // h4
  IG3(X0, 3, er2ab, nullptr, X1, nullptr);
  IG3(X1, 4, er2bb, X0, X2, ZF32);                         // z (bf16 + fp32 dup)

  // -------- VQ / Blahut-Arimoto --------
  rownorm_kernel<<<dim3(KCB / 4), blk, 0, stream>>>(cb, cn, KCB);
  cbbf_kernel<<<dim3(1024), blk, 0, stream>>>(cb, CBB);
  cbt_kernel<<<dim3(1024), blk, 0, stream>>>(cb, CBT);
  initq_kernel<<<dim3(4), blk, 0, stream>>>(pi, logq, Sacc);
  igemm_kernel<4,8,256,256,0><<<dim3(256, 8), blk, 0, stream>>>(
      X2, CBB, cn, nullptr, DV, nullptr, nullptr, zerob);
  for (int i = 0; i < 5; ++i) {
    ba2_kernel<<<dim3(NROW / 16), blk, 0, stream>>>(
        (uint4*)DV, logq, PART, idx, (i == 4) ? 1 : 0);
    qredf_kernel<<<dim3(64), blk, 0, stream>>>(PART, PART2, qsum, logq, ticket);
  }
  igemm_kernel<5,32,1024,1024,0><<<dim3(256, 2), blk, 0, stream>>>(
      DV, CBT, nullptr, nullptr, nullptr, ZF32, Sacc, zerob);
  entsc_kernel<<<dim3(1), dim3(1024), 0, stream>>>(qsum, Sacc, outf + 1572864);
  gather16_kernel<<<dim3(8192), blk, 0, stream>>>(idx, CBB, X0);  // zq_hard NHWC bf16

  // -------- decoder --------
  IG3(X0, 5, dr1ab, nullptr, X1, nullptr);
  IG3(X1, 6, dr1bb, X0, X2, nullptr);                      // y1
  IG3(X2, 7, dr2ab, nullptr, X0, nullptr);
  IG3(X0, 8, dr2bb, X2, X1, nullptr);                      // y2
  IG3(X1, 9, db1, nullptr, X0, nullptr);                   // y3
  wtt2_kernel<<<dim3(2048), blk, 0, stream>>>(dwt2, WTT2);
  igemm_kernel<3,32,256,256,32768><<<dim3(256, 4), blk, 0, stream>>>(
      X0, WTT2, dbt2, nullptr, BIGA, nullptr, nullptr, zerob);
  convt3_kernel<<<dim3(16, NB), blk, 0, stream>>>(BIGA, dwt3, dbt3, outf);
  #undef IG3
  #undef WTSLAB
}